// Round 8
// baseline (6653.104 us; speedup 1.0000x reference)
//
#include <hip/hip_runtime.h>
#include <hip/hip_bf16.h>
#include <cstdint>

__device__ __forceinline__ float silu_f(float v) {
  return v / (1.0f + expf(-v));
}

// B-spline bases, exact Cox-de Boor recursion matching the reference.
// grid: G[j] = -2.2 + 0.4*j, j=0..11. Returns 8 cubic bases.
__device__ __forceinline__ void bspl(float x, float* b8) {
  float b[11];
#pragma unroll
  for (int j = 0; j < 11; ++j) {
    float g0 = -2.2f + 0.4f * j;
    float g1 = g0 + 0.4f;
    b[j] = (x >= g0 && x < g1) ? 1.0f : 0.0f;
  }
#pragma unroll
  for (int k = 1; k <= 3; ++k) {
    float inv = 1.0f / (0.4f * k);
#pragma unroll
    for (int j = 0; j + k < 11; ++j) {
      float gj = -2.2f + 0.4f * j;
      float l = (x - gj) * inv;
      float r = (gj + 0.4f * (k + 1) - x) * inv;
      b[j] = l * b[j] + r * b[j + 1];
    }
  }
#pragma unroll
  for (int g = 0; g < 8; ++g) b8[g] = b[g];
}

// ---------------- LayerNorm: one wave per row of 512 ----------------
__global__ __launch_bounds__(256) void ln_kernel(
    const float* __restrict__ z, const float* __restrict__ gamma,
    const float* __restrict__ beta, float* __restrict__ out) {
  const int row = blockIdx.x * 4 + (threadIdx.x >> 6);
  const int lane = threadIdx.x & 63;
  const float4* zr = (const float4*)(z + (size_t)row * 512);
  float4 v0 = zr[lane * 2], v1 = zr[lane * 2 + 1];
  float s = v0.x + v0.y + v0.z + v0.w + v1.x + v1.y + v1.z + v1.w;
  float q = v0.x * v0.x + v0.y * v0.y + v0.z * v0.z + v0.w * v0.w +
            v1.x * v1.x + v1.y * v1.y + v1.z * v1.z + v1.w * v1.w;
#pragma unroll
  for (int o = 32; o > 0; o >>= 1) {
    s += __shfl_down(s, o);
    q += __shfl_down(q, o);
  }
  float mu = __shfl(s, 0) * (1.0f / 512.0f);
  float ex2 = __shfl(q, 0) * (1.0f / 512.0f);
  float rs = rsqrtf(ex2 - mu * mu + 1e-5f);
  const float4* gp = (const float4*)gamma;
  const float4* bp = (const float4*)beta;
  float4 g0 = gp[lane * 2], g1 = gp[lane * 2 + 1];
  float4 b0 = bp[lane * 2], b1 = bp[lane * 2 + 1];
  float4 o0, o1;
  o0.x = (v0.x - mu) * rs * g0.x + b0.x;
  o0.y = (v0.y - mu) * rs * g0.y + b0.y;
  o0.z = (v0.z - mu) * rs * g0.z + b0.z;
  o0.w = (v0.w - mu) * rs * g0.w + b0.w;
  o1.x = (v1.x - mu) * rs * g1.x + b1.x;
  o1.y = (v1.y - mu) * rs * g1.y + b1.y;
  o1.z = (v1.z - mu) * rs * g1.z + b1.z;
  o1.w = (v1.w - mu) * rs * g1.w + b1.w;
  float4* op = (float4*)(out + (size_t)row * 512);
  op[lane * 2] = o0;
  op[lane * 2 + 1] = o1;
}

// ---------------- W_eff prep (f32): W[o][c*in + i] ------------------------
__global__ __launch_bounds__(256) void prep_w_f32(
    const float* __restrict__ bw, const float* __restrict__ sw,
    const float* __restrict__ sc, float* __restrict__ W,
    int in_shift, int total) {
  int idx = blockIdx.x * 256 + threadIdx.x;
  if (idx >= total) return;
  int in = 1 << in_shift;
  int i = idx & (in - 1);
  int o = idx >> in_shift;
  size_t wb = (size_t)o * ((size_t)9 << in_shift) + i;
  float s = sc[idx];
  const float4* swp = (const float4*)(sw + (size_t)idx * 8);
  float4 a = swp[0], b = swp[1];
  W[wb] = bw[idx];
  W[wb + ((size_t)1 << in_shift)] = a.x * s;
  W[wb + ((size_t)2 << in_shift)] = a.y * s;
  W[wb + ((size_t)3 << in_shift)] = a.z * s;
  W[wb + ((size_t)4 << in_shift)] = a.w * s;
  W[wb + ((size_t)5 << in_shift)] = b.x * s;
  W[wb + ((size_t)6 << in_shift)] = b.y * s;
  W[wb + ((size_t)7 << in_shift)] = b.z * s;
  W[wb + ((size_t)8 << in_shift)] = b.w * s;
}

// ---------------- expansion (f32): X[b][c*in + i] -------------------------
__global__ __launch_bounds__(256) void expand_f32(
    const float* __restrict__ x, float* __restrict__ X, int in_shift, int total) {
  int idx = blockIdx.x * 256 + threadIdx.x;
  if (idx >= total) return;
  int in = 1 << in_shift;
  int i = idx & (in - 1);
  int b = idx >> in_shift;
  float v = x[idx];
  size_t base = (size_t)b * ((size_t)9 << in_shift) + i;
  float bs[8];
  bspl(v, bs);
  X[base] = silu_f(v);
#pragma unroll
  for (int g = 0; g < 8; ++g)
    X[base + ((size_t)(g + 1) << in_shift)] = bs[g];
}

// ---------------- f32 tiled GEMM: C(M,N) = A(M,K) * B(N,K)^T --------------
// BM=BN=64, BK=16, 256 threads, 4x4 micro-tile per thread. All f32 VALU.
template <bool SILU>
__global__ __launch_bounds__(256) void gemm_f32(
    const float* __restrict__ A, const float* __restrict__ B,
    float* __restrict__ C, int M, int N, int K, int ldc) {
  __shared__ float As[64][17];
  __shared__ float Bs[64][17];
  const int tid = threadIdx.x;
  const int bm = blockIdx.y * 64, bn = blockIdx.x * 64;
  const int tx = tid & 15, ty = tid >> 4;      // 16x16 thread grid
  const int srow = tid >> 2;                   // 0..63
  const int scol = (tid & 3) * 4;              // 0,4,8,12
  const float* gA = A + (size_t)(bm + srow) * K + scol;
  const float* gB = B + (size_t)(bn + srow) * K + scol;
  float acc[4][4] = {};
  for (int k0 = 0; k0 < K; k0 += 16) {
    float4 av = *(const float4*)(gA + k0);
    float4 bv = *(const float4*)(gB + k0);
    __syncthreads();
    As[srow][scol] = av.x; As[srow][scol + 1] = av.y;
    As[srow][scol + 2] = av.z; As[srow][scol + 3] = av.w;
    Bs[srow][scol] = bv.x; Bs[srow][scol + 1] = bv.y;
    Bs[srow][scol + 2] = bv.z; Bs[srow][scol + 3] = bv.w;
    __syncthreads();
#pragma unroll
    for (int kk = 0; kk < 16; ++kk) {
      float a0 = As[ty * 4 + 0][kk], a1 = As[ty * 4 + 1][kk];
      float a2 = As[ty * 4 + 2][kk], a3 = As[ty * 4 + 3][kk];
      float b0 = Bs[tx * 4 + 0][kk], b1 = Bs[tx * 4 + 1][kk];
      float b2 = Bs[tx * 4 + 2][kk], b3 = Bs[tx * 4 + 3][kk];
      acc[0][0] += a0 * b0; acc[0][1] += a0 * b1; acc[0][2] += a0 * b2; acc[0][3] += a0 * b3;
      acc[1][0] += a1 * b0; acc[1][1] += a1 * b1; acc[1][2] += a1 * b2; acc[1][3] += a1 * b3;
      acc[2][0] += a2 * b0; acc[2][1] += a2 * b1; acc[2][2] += a2 * b2; acc[2][3] += a2 * b3;
      acc[3][0] += a3 * b0; acc[3][1] += a3 * b1; acc[3][2] += a3 * b2; acc[3][3] += a3 * b3;
    }
  }
#pragma unroll
  for (int j = 0; j < 4; ++j) {
#pragma unroll
    for (int l = 0; l < 4; ++l) {
      int r = bm + ty * 4 + j;
      int c = bn + tx * 4 + l;
      float val = acc[j][l];
      if (SILU) val = silu_f(val);
      C[(size_t)r * ldc + c] = val;
    }
  }
}

extern "C" void kernel_launch(void* const* d_in, const int* in_sizes, int n_in,
                              void* d_out, int out_size, void* d_ws, size_t ws_size,
                              hipStream_t stream) {
  const float* z   = (const float*)d_in[1];
  const float* lng = (const float*)d_in[2];
  const float* lnb = (const float*)d_in[3];
  const float* bw1 = (const float*)d_in[5];
  const float* sw1 = (const float*)d_in[6];
  const float* sc1 = (const float*)d_in[7];
  const float* bw2 = (const float*)d_in[9];
  const float* sw2 = (const float*)d_in[10];
  const float* sc2 = (const float*)d_in[11];
  const float* bw3 = (const float*)d_in[13];
  const float* sw3 = (const float*)d_in[14];
  const float* sc3 = (const float*)d_in[15];
  float* out = (float*)d_out;

  const int B = 8192, D = 512, H = 1024;
  char* ws = (char*)d_ws;
  size_t off = 0;
  float* ln_out = (float*)(ws + off); off += (size_t)B * D * 4;
  float* hbuf   = (float*)(ws + off); off += (size_t)B * H * 4;  // activated h
  float* Wbuf   = (float*)(ws + off); off += (size_t)H * 9216 * 4;
  size_t rem = ws_size > off ? ws_size - off : 0;
  int CB = 128;
  {
    const int cands[6] = {8192, 4096, 2048, 1024, 512, 256};
    for (int c = 0; c < 6; ++c) {
      if ((size_t)cands[c] * 9216 * 4 <= rem) { CB = cands[c]; break; }
    }
  }
  float* Xexp = (float*)(ws + off);

  ln_kernel<<<B / 4, 256, 0, stream>>>(z, lng, lnb, ln_out);

  // ---- layer 1: in=512, out=1024, silu epilogue (f32 throughout)
  {
    const int in_shift = 9, K = 9 * D, N = H;
    prep_w_f32<<<(H * D + 255) / 256, 256, 0, stream>>>(bw1, sw1, sc1, Wbuf, in_shift, H * D);
    for (int r0 = 0; r0 < B; r0 += CB) {
      int cb = (B - r0 < CB) ? (B - r0) : CB;
      expand_f32<<<(cb << in_shift) / 256, 256, 0, stream>>>(
          ln_out + (size_t)r0 * D, Xexp, in_shift, cb << in_shift);
      dim3 grid(N / 64, cb / 64);
      gemm_f32<true><<<grid, 256, 0, stream>>>(Xexp, Wbuf, hbuf + (size_t)r0 * H, cb, N, K, H);
    }
  }
  // ---- layer 2: in=1024, out=1024, silu epilogue
  {
    const int in_shift = 10, K = 9 * H, N = H;
    prep_w_f32<<<(H * H + 255) / 256, 256, 0, stream>>>(bw2, sw2, sc2, Wbuf, in_shift, H * H);
    for (int r0 = 0; r0 < B; r0 += CB) {
      int cb = (B - r0 < CB) ? (B - r0) : CB;
      expand_f32<<<(cb << in_shift) / 256, 256, 0, stream>>>(
          hbuf + (size_t)r0 * H, Xexp, in_shift, cb << in_shift);
      dim3 grid(N / 64, cb / 64);
      gemm_f32<true><<<grid, 256, 0, stream>>>(Xexp, Wbuf, hbuf + (size_t)r0 * H, cb, N, K, H);
    }
  }
  // ---- layer 3: in=1024, out=512, no silu, f32 out
  {
    const int in_shift = 10, K = 9 * H, N = D;
    prep_w_f32<<<(D * H + 255) / 256, 256, 0, stream>>>(bw3, sw3, sc3, Wbuf, in_shift, D * H);
    for (int r0 = 0; r0 < B; r0 += CB) {
      int cb = (B - r0 < CB) ? (B - r0) : CB;
      expand_f32<<<(cb << in_shift) / 256, 256, 0, stream>>>(
          hbuf + (size_t)r0 * H, Xexp, in_shift, cb << in_shift);
      dim3 grid(N / 64, cb / 64);
      gemm_f32<false><<<grid, 256, 0, stream>>>(Xexp, Wbuf, out + (size_t)r0 * D, cb, N, K, D);
    }
  }
}

// Round 9
// 6450.913 us; speedup vs baseline: 1.0313x; 1.0313x over previous
//
#include <hip/hip_runtime.h>
#include <hip/hip_bf16.h>
#include <cstdint>

__device__ __forceinline__ float silu_f(float v) {
  return v / (1.0f + expf(-v));
}

// B-spline bases, exact Cox-de Boor recursion matching the reference.
// grid: G[j] = -2.2 + 0.4*j, j=0..11. Returns 8 cubic bases.
__device__ __forceinline__ void bspl(float x, float* b8) {
  float b[11];
#pragma unroll
  for (int j = 0; j < 11; ++j) {
    float g0 = -2.2f + 0.4f * j;
    float g1 = g0 + 0.4f;
    b[j] = (x >= g0 && x < g1) ? 1.0f : 0.0f;
  }
#pragma unroll
  for (int k = 1; k <= 3; ++k) {
    float inv = 1.0f / (0.4f * k);
#pragma unroll
    for (int j = 0; j + k < 11; ++j) {
      float gj = -2.2f + 0.4f * j;
      float l = (x - gj) * inv;
      float r = (gj + 0.4f * (k + 1) - x) * inv;
      b[j] = l * b[j] + r * b[j + 1];
    }
  }
#pragma unroll
  for (int g = 0; g < 8; ++g) b8[g] = b[g];
}

// ---------------- LayerNorm: one wave per row of 512 (bitwise = r8) -------
__global__ __launch_bounds__(256) void ln_kernel(
    const float* __restrict__ z, const float* __restrict__ gamma,
    const float* __restrict__ beta, float* __restrict__ out) {
  const int row = blockIdx.x * 4 + (threadIdx.x >> 6);
  const int lane = threadIdx.x & 63;
  const float4* zr = (const float4*)(z + (size_t)row * 512);
  float4 v0 = zr[lane * 2], v1 = zr[lane * 2 + 1];
  float s = v0.x + v0.y + v0.z + v0.w + v1.x + v1.y + v1.z + v1.w;
  float q = v0.x * v0.x + v0.y * v0.y + v0.z * v0.z + v0.w * v0.w +
            v1.x * v1.x + v1.y * v1.y + v1.z * v1.z + v1.w * v1.w;
#pragma unroll
  for (int o = 32; o > 0; o >>= 1) {
    s += __shfl_down(s, o);
    q += __shfl_down(q, o);
  }
  float mu = __shfl(s, 0) * (1.0f / 512.0f);
  float ex2 = __shfl(q, 0) * (1.0f / 512.0f);
  float rs = rsqrtf(ex2 - mu * mu + 1e-5f);
  const float4* gp = (const float4*)gamma;
  const float4* bp = (const float4*)beta;
  float4 g0 = gp[lane * 2], g1 = gp[lane * 2 + 1];
  float4 b0 = bp[lane * 2], b1 = bp[lane * 2 + 1];
  float4 o0, o1;
  o0.x = (v0.x - mu) * rs * g0.x + b0.x;
  o0.y = (v0.y - mu) * rs * g0.y + b0.y;
  o0.z = (v0.z - mu) * rs * g0.z + b0.z;
  o0.w = (v0.w - mu) * rs * g0.w + b0.w;
  o1.x = (v1.x - mu) * rs * g1.x + b1.x;
  o1.y = (v1.y - mu) * rs * g1.y + b1.y;
  o1.z = (v1.z - mu) * rs * g1.z + b1.z;
  o1.w = (v1.w - mu) * rs * g1.w + b1.w;
  float4* op = (float4*)(out + (size_t)row * 512);
  op[lane * 2] = o0;
  op[lane * 2 + 1] = o1;
}

// ---------------- W_eff prep (f32, bitwise = r8) --------------------------
__global__ __launch_bounds__(256) void prep_w_f32(
    const float* __restrict__ bw, const float* __restrict__ sw,
    const float* __restrict__ sc, float* __restrict__ W,
    int in_shift, int total) {
  int idx = blockIdx.x * 256 + threadIdx.x;
  if (idx >= total) return;
  int in = 1 << in_shift;
  int i = idx & (in - 1);
  int o = idx >> in_shift;
  size_t wb = (size_t)o * ((size_t)9 << in_shift) + i;
  float s = sc[idx];
  const float4* swp = (const float4*)(sw + (size_t)idx * 8);
  float4 a = swp[0], b = swp[1];
  W[wb] = bw[idx];
  W[wb + ((size_t)1 << in_shift)] = a.x * s;
  W[wb + ((size_t)2 << in_shift)] = a.y * s;
  W[wb + ((size_t)3 << in_shift)] = a.z * s;
  W[wb + ((size_t)4 << in_shift)] = a.w * s;
  W[wb + ((size_t)5 << in_shift)] = b.x * s;
  W[wb + ((size_t)6 << in_shift)] = b.y * s;
  W[wb + ((size_t)7 << in_shift)] = b.z * s;
  W[wb + ((size_t)8 << in_shift)] = b.w * s;
}

// ---------------- expansion (f32, bitwise = r8) ---------------------------
__global__ __launch_bounds__(256) void expand_f32(
    const float* __restrict__ x, float* __restrict__ X, int in_shift, int total) {
  int idx = blockIdx.x * 256 + threadIdx.x;
  if (idx >= total) return;
  int in = 1 << in_shift;
  int i = idx & (in - 1);
  int b = idx >> in_shift;
  float v = x[idx];
  size_t base = (size_t)b * ((size_t)9 << in_shift) + i;
  float bs[8];
  bspl(v, bs);
  X[base] = silu_f(v);
#pragma unroll
  for (int g = 0; g < 8; ++g)
    X[base + ((size_t)(g + 1) << in_shift)] = bs[g];
}

// ---------------- f32 tiled GEMM v2: C(M,N) = A(M,K) * B(N,K)^T -----------
// BM=BN=128, BK=32, 256 threads, 8x8 micro-tile. Per-output accumulation is
// a strict k-ascending `acc += a*b` chain -> BITWISE-IDENTICAL to r8's GEMM.
// LDS stored k-major [32][132]: 132%4==0 keeps b128 alignment; A-frag reads
// are broadcast, staging writes 2-way (free). Global staging: 8 lanes x
// float4 = full 128B line per row.
template <bool SILU>
__global__ __launch_bounds__(256) void gemm_f32(
    const float* __restrict__ A, const float* __restrict__ B,
    float* __restrict__ C, int M, int N, int K, int ldc) {
  __shared__ float As[32][132];
  __shared__ float Bs[32][132];
  const int tid = threadIdx.x;
  const int bm = blockIdx.y * 128, bn = blockIdx.x * 128;
  const int tx = tid & 15, ty = tid >> 4;   // 16x16 thread grid, 8x8 each
  const int sr = tid >> 3;                  // staging row 0..31 (per pass)
  const int sk = (tid & 7) * 4;             // staging k-offset 0,4,...,28
  const float* gA = A + (size_t)(bm + sr) * K + sk;
  const float* gB = B + (size_t)(bn + sr) * K + sk;
  float acc[8][8] = {};
  for (int k0 = 0; k0 < K; k0 += 32) {
    // prefetch this tile's global data into registers before the barrier
    float4 av[4], bv[4];
#pragma unroll
    for (int p = 0; p < 4; ++p) {
      av[p] = *(const float4*)(gA + (size_t)p * 32 * K + k0);
      bv[p] = *(const float4*)(gB + (size_t)p * 32 * K + k0);
    }
    __syncthreads();
#pragma unroll
    for (int p = 0; p < 4; ++p) {
      int m = p * 32 + sr;
      As[sk + 0][m] = av[p].x; As[sk + 1][m] = av[p].y;
      As[sk + 2][m] = av[p].z; As[sk + 3][m] = av[p].w;
      Bs[sk + 0][m] = bv[p].x; Bs[sk + 1][m] = bv[p].y;
      Bs[sk + 2][m] = bv[p].z; Bs[sk + 3][m] = bv[p].w;
    }
    __syncthreads();
#pragma unroll 4
    for (int kk = 0; kk < 32; ++kk) {
      float4 a0 = *(const float4*)&As[kk][ty * 8];
      float4 a1 = *(const float4*)&As[kk][ty * 8 + 4];
      float4 b0 = *(const float4*)&Bs[kk][tx * 8];
      float4 b1 = *(const float4*)&Bs[kk][tx * 8 + 4];
      float a[8] = {a0.x, a0.y, a0.z, a0.w, a1.x, a1.y, a1.z, a1.w};
      float b[8] = {b0.x, b0.y, b0.z, b0.w, b1.x, b1.y, b1.z, b1.w};
#pragma unroll
      for (int j = 0; j < 8; ++j)
#pragma unroll
        for (int l = 0; l < 8; ++l)
          acc[j][l] += a[j] * b[l];
    }
  }
#pragma unroll
  for (int j = 0; j < 8; ++j) {
    int r = bm + ty * 8 + j;
    float4 o0, o1;
    o0.x = acc[j][0]; o0.y = acc[j][1]; o0.z = acc[j][2]; o0.w = acc[j][3];
    o1.x = acc[j][4]; o1.y = acc[j][5]; o1.z = acc[j][6]; o1.w = acc[j][7];
    if (SILU) {
      o0.x = silu_f(o0.x); o0.y = silu_f(o0.y);
      o0.z = silu_f(o0.z); o0.w = silu_f(o0.w);
      o1.x = silu_f(o1.x); o1.y = silu_f(o1.y);
      o1.z = silu_f(o1.z); o1.w = silu_f(o1.w);
    }
    float* cp = C + (size_t)r * ldc + bn + tx * 8;
    *(float4*)cp = o0;
    *(float4*)(cp + 4) = o1;
  }
}

extern "C" void kernel_launch(void* const* d_in, const int* in_sizes, int n_in,
                              void* d_out, int out_size, void* d_ws, size_t ws_size,
                              hipStream_t stream) {
  const float* z   = (const float*)d_in[1];
  const float* lng = (const float*)d_in[2];
  const float* lnb = (const float*)d_in[3];
  const float* bw1 = (const float*)d_in[5];
  const float* sw1 = (const float*)d_in[6];
  const float* sc1 = (const float*)d_in[7];
  const float* bw2 = (const float*)d_in[9];
  const float* sw2 = (const float*)d_in[10];
  const float* sc2 = (const float*)d_in[11];
  const float* bw3 = (const float*)d_in[13];
  const float* sw3 = (const float*)d_in[14];
  const float* sc3 = (const float*)d_in[15];
  float* out = (float*)d_out;

  const int B = 8192, D = 512, H = 1024;
  char* ws = (char*)d_ws;
  size_t off = 0;
  float* ln_out = (float*)(ws + off); off += (size_t)B * D * 4;
  float* hbuf   = (float*)(ws + off); off += (size_t)B * H * 4;  // activated h
  float* Wbuf   = (float*)(ws + off); off += (size_t)H * 9216 * 4;
  size_t rem = ws_size > off ? ws_size - off : 0;
  int CB = 128;
  {
    const int cands[6] = {8192, 4096, 2048, 1024, 512, 256};
    for (int c = 0; c < 6; ++c) {
      if ((size_t)cands[c] * 9216 * 4 <= rem) { CB = cands[c]; break; }
    }
  }
  float* Xexp = (float*)(ws + off);

  ln_kernel<<<B / 4, 256, 0, stream>>>(z, lng, lnb, ln_out);

  // ---- layer 1: in=512, out=1024, silu epilogue (f32 throughout)
  {
    const int in_shift = 9, K = 9 * D, N = H;
    prep_w_f32<<<(H * D + 255) / 256, 256, 0, stream>>>(bw1, sw1, sc1, Wbuf, in_shift, H * D);
    for (int r0 = 0; r0 < B; r0 += CB) {
      int cb = (B - r0 < CB) ? (B - r0) : CB;
      expand_f32<<<(cb << in_shift) / 256, 256, 0, stream>>>(
          ln_out + (size_t)r0 * D, Xexp, in_shift, cb << in_shift);
      dim3 grid(N / 128, cb / 128);
      gemm_f32<true><<<grid, 256, 0, stream>>>(Xexp, Wbuf, hbuf + (size_t)r0 * H, cb, N, K, H);
    }
  }
  // ---- layer 2: in=1024, out=1024, silu epilogue
  {
    const int in_shift = 10, K = 9 * H, N = H;
    prep_w_f32<<<(H * H + 255) / 256, 256, 0, stream>>>(bw2, sw2, sc2, Wbuf, in_shift, H * H);
    for (int r0 = 0; r0 < B; r0 += CB) {
      int cb = (B - r0 < CB) ? (B - r0) : CB;
      expand_f32<<<(cb << in_shift) / 256, 256, 0, stream>>>(
          hbuf + (size_t)r0 * H, Xexp, in_shift, cb << in_shift);
      dim3 grid(N / 128, cb / 128);
      gemm_f32<true><<<grid, 256, 0, stream>>>(Xexp, Wbuf, hbuf + (size_t)r0 * H, cb, N, K, H);
    }
  }
  // ---- layer 3: in=1024, out=512, no silu, f32 out
  {
    const int in_shift = 10, K = 9 * H, N = D;
    prep_w_f32<<<(D * H + 255) / 256, 256, 0, stream>>>(bw3, sw3, sc3, Wbuf, in_shift, D * H);
    for (int r0 = 0; r0 < B; r0 += CB) {
      int cb = (B - r0 < CB) ? (B - r0) : CB;
      expand_f32<<<(cb << in_shift) / 256, 256, 0, stream>>>(
          hbuf + (size_t)r0 * H, Xexp, in_shift, cb << in_shift);
      dim3 grid(N / 128, cb / 128);
      gemm_f32<false><<<grid, 256, 0, stream>>>(Xexp, Wbuf, out + (size_t)r0 * D, cb, N, K, D);
    }
  }
}

// Round 10
// 5090.903 us; speedup vs baseline: 1.3069x; 1.2671x over previous
//
#include <hip/hip_runtime.h>
#include <hip/hip_bf16.h>
#include <cstdint>

__device__ __forceinline__ float silu_f(float v) {
  return v / (1.0f + expf(-v));
}

// B-spline bases, exact Cox-de Boor recursion matching the reference.
// grid: G[j] = -2.2 + 0.4*j, j=0..11. Returns 8 cubic bases.
__device__ __forceinline__ void bspl(float x, float* b8) {
  float b[11];
#pragma unroll
  for (int j = 0; j < 11; ++j) {
    float g0 = -2.2f + 0.4f * j;
    float g1 = g0 + 0.4f;
    b[j] = (x >= g0 && x < g1) ? 1.0f : 0.0f;
  }
#pragma unroll
  for (int k = 1; k <= 3; ++k) {
    float inv = 1.0f / (0.4f * k);
#pragma unroll
    for (int j = 0; j + k < 11; ++j) {
      float gj = -2.2f + 0.4f * j;
      float l = (x - gj) * inv;
      float r = (gj + 0.4f * (k + 1) - x) * inv;
      b[j] = l * b[j] + r * b[j + 1];
    }
  }
#pragma unroll
  for (int g = 0; g < 8; ++g) b8[g] = b[g];
}

// ---------------- LayerNorm: one wave per row of 512 (bitwise = r8/r9) ----
__global__ __launch_bounds__(256) void ln_kernel(
    const float* __restrict__ z, const float* __restrict__ gamma,
    const float* __restrict__ beta, float* __restrict__ out) {
  const int row = blockIdx.x * 4 + (threadIdx.x >> 6);
  const int lane = threadIdx.x & 63;
  const float4* zr = (const float4*)(z + (size_t)row * 512);
  float4 v0 = zr[lane * 2], v1 = zr[lane * 2 + 1];
  float s = v0.x + v0.y + v0.z + v0.w + v1.x + v1.y + v1.z + v1.w;
  float q = v0.x * v0.x + v0.y * v0.y + v0.z * v0.z + v0.w * v0.w +
            v1.x * v1.x + v1.y * v1.y + v1.z * v1.z + v1.w * v1.w;
#pragma unroll
  for (int o = 32; o > 0; o >>= 1) {
    s += __shfl_down(s, o);
    q += __shfl_down(q, o);
  }
  float mu = __shfl(s, 0) * (1.0f / 512.0f);
  float ex2 = __shfl(q, 0) * (1.0f / 512.0f);
  float rs = rsqrtf(ex2 - mu * mu + 1e-5f);
  const float4* gp = (const float4*)gamma;
  const float4* bp = (const float4*)beta;
  float4 g0 = gp[lane * 2], g1 = gp[lane * 2 + 1];
  float4 b0 = bp[lane * 2], b1 = bp[lane * 2 + 1];
  float4 o0, o1;
  o0.x = (v0.x - mu) * rs * g0.x + b0.x;
  o0.y = (v0.y - mu) * rs * g0.y + b0.y;
  o0.z = (v0.z - mu) * rs * g0.z + b0.z;
  o0.w = (v0.w - mu) * rs * g0.w + b0.w;
  o1.x = (v1.x - mu) * rs * g1.x + b1.x;
  o1.y = (v1.y - mu) * rs * g1.y + b1.y;
  o1.z = (v1.z - mu) * rs * g1.z + b1.z;
  o1.w = (v1.w - mu) * rs * g1.w + b1.w;
  float4* op = (float4*)(out + (size_t)row * 512);
  op[lane * 2] = o0;
  op[lane * 2 + 1] = o1;
}

// ---------------- W_eff prep (f32, bitwise = r8/r9) -----------------------
__global__ __launch_bounds__(256) void prep_w_f32(
    const float* __restrict__ bw, const float* __restrict__ sw,
    const float* __restrict__ sc, float* __restrict__ W,
    int in_shift, int total) {
  int idx = blockIdx.x * 256 + threadIdx.x;
  if (idx >= total) return;
  int in = 1 << in_shift;
  int i = idx & (in - 1);
  int o = idx >> in_shift;
  size_t wb = (size_t)o * ((size_t)9 << in_shift) + i;
  float s = sc[idx];
  const float4* swp = (const float4*)(sw + (size_t)idx * 8);
  float4 a = swp[0], b = swp[1];
  W[wb] = bw[idx];
  W[wb + ((size_t)1 << in_shift)] = a.x * s;
  W[wb + ((size_t)2 << in_shift)] = a.y * s;
  W[wb + ((size_t)3 << in_shift)] = a.z * s;
  W[wb + ((size_t)4 << in_shift)] = a.w * s;
  W[wb + ((size_t)5 << in_shift)] = b.x * s;
  W[wb + ((size_t)6 << in_shift)] = b.y * s;
  W[wb + ((size_t)7 << in_shift)] = b.z * s;
  W[wb + ((size_t)8 << in_shift)] = b.w * s;
}

// ---------------- expansion (f32, bitwise = r8/r9) ------------------------
__global__ __launch_bounds__(256) void expand_f32(
    const float* __restrict__ x, float* __restrict__ X, int in_shift, int total) {
  int idx = blockIdx.x * 256 + threadIdx.x;
  if (idx >= total) return;
  int in = 1 << in_shift;
  int i = idx & (in - 1);
  int b = idx >> in_shift;
  float v = x[idx];
  size_t base = (size_t)b * ((size_t)9 << in_shift) + i;
  float bs[8];
  bspl(v, bs);
  X[base] = silu_f(v);
#pragma unroll
  for (int g = 0; g < 8; ++g)
    X[base + ((size_t)(g + 1) << in_shift)] = bs[g];
}

// ---------------- f32 tiled GEMM v3: double-buffered LDS ------------------
// BM=BN=128, BK=32, 256 threads, 8x8 micro-tile. Per-output accumulation is
// the same strict k-ascending `acc += a*b` chain -> BITWISE-IDENTICAL output.
// v3: prefetch tile t+1 (global->regs) before computing tile t; write to the
// alternate LDS buffer after compute; ONE barrier per k-iter. Removes the
// exposed global-load latency that capped v2 at ~71% of f32 peak.
template <bool SILU>
__global__ __launch_bounds__(256, 2) void gemm_f32(
    const float* __restrict__ A, const float* __restrict__ B,
    float* __restrict__ C, int M, int N, int K, int ldc) {
  __shared__ float As[2][32][132];
  __shared__ float Bs[2][32][132];
  const int tid = threadIdx.x;
  const int bm = blockIdx.y * 128, bn = blockIdx.x * 128;
  const int tx = tid & 15, ty = tid >> 4;   // 16x16 thread grid, 8x8 each
  const int sr = tid >> 3;                  // staging row 0..31 (per pass)
  const int sk = (tid & 7) * 4;             // staging k-offset 0,4,...,28
  const float* gA = A + (size_t)(bm + sr) * K + sk;
  const float* gB = B + (size_t)(bn + sr) * K + sk;
  float acc[8][8] = {};
  float4 av[4], bv[4];
  const int NT = K >> 5;
  // prologue: tile 0 -> regs -> LDS buf 0
#pragma unroll
  for (int p = 0; p < 4; ++p) {
    av[p] = *(const float4*)(gA + (size_t)p * 32 * K);
    bv[p] = *(const float4*)(gB + (size_t)p * 32 * K);
  }
#pragma unroll
  for (int p = 0; p < 4; ++p) {
    int m = p * 32 + sr;
    As[0][sk + 0][m] = av[p].x; As[0][sk + 1][m] = av[p].y;
    As[0][sk + 2][m] = av[p].z; As[0][sk + 3][m] = av[p].w;
    Bs[0][sk + 0][m] = bv[p].x; Bs[0][sk + 1][m] = bv[p].y;
    Bs[0][sk + 2][m] = bv[p].z; Bs[0][sk + 3][m] = bv[p].w;
  }
  __syncthreads();
  for (int t = 0; t < NT; ++t) {
    const int cur = t & 1;
    // issue next tile's global loads BEFORE compute (latency hides under it)
    if (t + 1 < NT) {
      const int k0 = (t + 1) << 5;
#pragma unroll
      for (int p = 0; p < 4; ++p) {
        av[p] = *(const float4*)(gA + (size_t)p * 32 * K + k0);
        bv[p] = *(const float4*)(gB + (size_t)p * 32 * K + k0);
      }
    }
#pragma unroll 4
    for (int kk = 0; kk < 32; ++kk) {
      float4 a0 = *(const float4*)&As[cur][kk][ty * 8];
      float4 a1 = *(const float4*)&As[cur][kk][ty * 8 + 4];
      float4 b0 = *(const float4*)&Bs[cur][kk][tx * 8];
      float4 b1 = *(const float4*)&Bs[cur][kk][tx * 8 + 4];
      float a[8] = {a0.x, a0.y, a0.z, a0.w, a1.x, a1.y, a1.z, a1.w};
      float b[8] = {b0.x, b0.y, b0.z, b0.w, b1.x, b1.y, b1.z, b1.w};
#pragma unroll
      for (int j = 0; j < 8; ++j)
#pragma unroll
        for (int l = 0; l < 8; ++l)
          acc[j][l] += a[j] * b[l];
    }
    if (t + 1 < NT) {
      const int nxt = cur ^ 1;
      // buf nxt was last READ in iter t-1; the barrier at end of t-1 proves
      // all waves are done with it -> safe to overwrite now.
#pragma unroll
      for (int p = 0; p < 4; ++p) {
        int m = p * 32 + sr;
        As[nxt][sk + 0][m] = av[p].x; As[nxt][sk + 1][m] = av[p].y;
        As[nxt][sk + 2][m] = av[p].z; As[nxt][sk + 3][m] = av[p].w;
        Bs[nxt][sk + 0][m] = bv[p].x; Bs[nxt][sk + 1][m] = bv[p].y;
        Bs[nxt][sk + 2][m] = bv[p].z; Bs[nxt][sk + 3][m] = bv[p].w;
      }
      __syncthreads();
    }
  }
#pragma unroll
  for (int j = 0; j < 8; ++j) {
    int r = bm + ty * 8 + j;
    float4 o0, o1;
    o0.x = acc[j][0]; o0.y = acc[j][1]; o0.z = acc[j][2]; o0.w = acc[j][3];
    o1.x = acc[j][4]; o1.y = acc[j][5]; o1.z = acc[j][6]; o1.w = acc[j][7];
    if (SILU) {
      o0.x = silu_f(o0.x); o0.y = silu_f(o0.y);
      o0.z = silu_f(o0.z); o0.w = silu_f(o0.w);
      o1.x = silu_f(o1.x); o1.y = silu_f(o1.y);
      o1.z = silu_f(o1.z); o1.w = silu_f(o1.w);
    }
    float* cp = C + (size_t)r * ldc + bn + tx * 8;
    *(float4*)cp = o0;
    *(float4*)(cp + 4) = o1;
  }
}

extern "C" void kernel_launch(void* const* d_in, const int* in_sizes, int n_in,
                              void* d_out, int out_size, void* d_ws, size_t ws_size,
                              hipStream_t stream) {
  const float* z   = (const float*)d_in[1];
  const float* lng = (const float*)d_in[2];
  const float* lnb = (const float*)d_in[3];
  const float* bw1 = (const float*)d_in[5];
  const float* sw1 = (const float*)d_in[6];
  const float* sc1 = (const float*)d_in[7];
  const float* bw2 = (const float*)d_in[9];
  const float* sw2 = (const float*)d_in[10];
  const float* sc2 = (const float*)d_in[11];
  const float* bw3 = (const float*)d_in[13];
  const float* sw3 = (const float*)d_in[14];
  const float* sc3 = (const float*)d_in[15];
  float* out = (float*)d_out;

  const int B = 8192, D = 512, H = 1024;
  char* ws = (char*)d_ws;
  size_t off = 0;
  float* ln_out = (float*)(ws + off); off += (size_t)B * D * 4;
  float* hbuf   = (float*)(ws + off); off += (size_t)B * H * 4;  // activated h
  float* Wbuf   = (float*)(ws + off); off += (size_t)H * 9216 * 4;
  size_t rem = ws_size > off ? ws_size - off : 0;
  int CB = 128;
  {
    const int cands[6] = {8192, 4096, 2048, 1024, 512, 256};
    for (int c = 0; c < 6; ++c) {
      if ((size_t)cands[c] * 9216 * 4 <= rem) { CB = cands[c]; break; }
    }
  }
  float* Xexp = (float*)(ws + off);

  ln_kernel<<<B / 4, 256, 0, stream>>>(z, lng, lnb, ln_out);

  // ---- layer 1: in=512, out=1024, silu epilogue (f32 throughout)
  {
    const int in_shift = 9, K = 9 * D, N = H;
    prep_w_f32<<<(H * D + 255) / 256, 256, 0, stream>>>(bw1, sw1, sc1, Wbuf, in_shift, H * D);
    for (int r0 = 0; r0 < B; r0 += CB) {
      int cb = (B - r0 < CB) ? (B - r0) : CB;
      expand_f32<<<(cb << in_shift) / 256, 256, 0, stream>>>(
          ln_out + (size_t)r0 * D, Xexp, in_shift, cb << in_shift);
      dim3 grid(N / 128, cb / 128);
      gemm_f32<true><<<grid, 256, 0, stream>>>(Xexp, Wbuf, hbuf + (size_t)r0 * H, cb, N, K, H);
    }
  }
  // ---- layer 2: in=1024, out=1024, silu epilogue
  {
    const int in_shift = 10, K = 9 * H, N = H;
    prep_w_f32<<<(H * H + 255) / 256, 256, 0, stream>>>(bw2, sw2, sc2, Wbuf, in_shift, H * H);
    for (int r0 = 0; r0 < B; r0 += CB) {
      int cb = (B - r0 < CB) ? (B - r0) : CB;
      expand_f32<<<(cb << in_shift) / 256, 256, 0, stream>>>(
          hbuf + (size_t)r0 * H, Xexp, in_shift, cb << in_shift);
      dim3 grid(N / 128, cb / 128);
      gemm_f32<true><<<grid, 256, 0, stream>>>(Xexp, Wbuf, hbuf + (size_t)r0 * H, cb, N, K, H);
    }
  }
  // ---- layer 3: in=1024, out=512, no silu, f32 out
  {
    const int in_shift = 10, K = 9 * H, N = D;
    prep_w_f32<<<(D * H + 255) / 256, 256, 0, stream>>>(bw3, sw3, sc3, Wbuf, in_shift, D * H);
    for (int r0 = 0; r0 < B; r0 += CB) {
      int cb = (B - r0 < CB) ? (B - r0) : CB;
      expand_f32<<<(cb << in_shift) / 256, 256, 0, stream>>>(
          hbuf + (size_t)r0 * H, Xexp, in_shift, cb << in_shift);
      dim3 grid(N / 128, cb / 128);
      gemm_f32<false><<<grid, 256, 0, stream>>>(Xexp, Wbuf, out + (size_t)r0 * D, cb, N, K, D);
    }
  }
}

// Round 11
// 4580.758 us; speedup vs baseline: 1.4524x; 1.1114x over previous
//
#include <hip/hip_runtime.h>
#include <hip/hip_bf16.h>
#include <cstdint>

__device__ __forceinline__ float silu_f(float v) {
  return v / (1.0f + expf(-v));
}

// B-spline bases, exact Cox-de Boor recursion matching the reference.
__device__ __forceinline__ void bspl(float x, float* b8) {
  float b[11];
#pragma unroll
  for (int j = 0; j < 11; ++j) {
    float g0 = -2.2f + 0.4f * j;
    float g1 = g0 + 0.4f;
    b[j] = (x >= g0 && x < g1) ? 1.0f : 0.0f;
  }
#pragma unroll
  for (int k = 1; k <= 3; ++k) {
    float inv = 1.0f / (0.4f * k);
#pragma unroll
    for (int j = 0; j + k < 11; ++j) {
      float gj = -2.2f + 0.4f * j;
      float l = (x - gj) * inv;
      float r = (gj + 0.4f * (k + 1) - x) * inv;
      b[j] = l * b[j] + r * b[j + 1];
    }
  }
#pragma unroll
  for (int g = 0; g < 8; ++g) b8[g] = b[g];
}

// ---------------- LayerNorm: one wave per row of 512 (bitwise = r8-r10) ---
__global__ __launch_bounds__(256) void ln_kernel(
    const float* __restrict__ z, const float* __restrict__ gamma,
    const float* __restrict__ beta, float* __restrict__ out) {
  const int row = blockIdx.x * 4 + (threadIdx.x >> 6);
  const int lane = threadIdx.x & 63;
  const float4* zr = (const float4*)(z + (size_t)row * 512);
  float4 v0 = zr[lane * 2], v1 = zr[lane * 2 + 1];
  float s = v0.x + v0.y + v0.z + v0.w + v1.x + v1.y + v1.z + v1.w;
  float q = v0.x * v0.x + v0.y * v0.y + v0.z * v0.z + v0.w * v0.w +
            v1.x * v1.x + v1.y * v1.y + v1.z * v1.z + v1.w * v1.w;
#pragma unroll
  for (int o = 32; o > 0; o >>= 1) {
    s += __shfl_down(s, o);
    q += __shfl_down(q, o);
  }
  float mu = __shfl(s, 0) * (1.0f / 512.0f);
  float ex2 = __shfl(q, 0) * (1.0f / 512.0f);
  float rs = rsqrtf(ex2 - mu * mu + 1e-5f);
  const float4* gp = (const float4*)gamma;
  const float4* bp = (const float4*)beta;
  float4 g0 = gp[lane * 2], g1 = gp[lane * 2 + 1];
  float4 b0 = bp[lane * 2], b1 = bp[lane * 2 + 1];
  float4 o0, o1;
  o0.x = (v0.x - mu) * rs * g0.x + b0.x;
  o0.y = (v0.y - mu) * rs * g0.y + b0.y;
  o0.z = (v0.z - mu) * rs * g0.z + b0.z;
  o0.w = (v0.w - mu) * rs * g0.w + b0.w;
  o1.x = (v1.x - mu) * rs * g1.x + b1.x;
  o1.y = (v1.y - mu) * rs * g1.y + b1.y;
  o1.z = (v1.z - mu) * rs * g1.z + b1.z;
  o1.w = (v1.w - mu) * rs * g1.w + b1.w;
  float4* op = (float4*)(out + (size_t)row * 512);
  op[lane * 2] = o0;
  op[lane * 2 + 1] = o1;
}

// ---------------- W_eff prep (f32, bitwise = r8-r10) ----------------------
__global__ __launch_bounds__(256) void prep_w_f32(
    const float* __restrict__ bw, const float* __restrict__ sw,
    const float* __restrict__ sc, float* __restrict__ W,
    int in_shift, int total) {
  int idx = blockIdx.x * 256 + threadIdx.x;
  if (idx >= total) return;
  int in = 1 << in_shift;
  int i = idx & (in - 1);
  int o = idx >> in_shift;
  size_t wb = (size_t)o * ((size_t)9 << in_shift) + i;
  float s = sc[idx];
  const float4* swp = (const float4*)(sw + (size_t)idx * 8);
  float4 a = swp[0], b = swp[1];
  W[wb] = bw[idx];
  W[wb + ((size_t)1 << in_shift)] = a.x * s;
  W[wb + ((size_t)2 << in_shift)] = a.y * s;
  W[wb + ((size_t)3 << in_shift)] = a.z * s;
  W[wb + ((size_t)4 << in_shift)] = a.w * s;
  W[wb + ((size_t)5 << in_shift)] = b.x * s;
  W[wb + ((size_t)6 << in_shift)] = b.y * s;
  W[wb + ((size_t)7 << in_shift)] = b.z * s;
  W[wb + ((size_t)8 << in_shift)] = b.w * s;
}

// ---------------- expansion (f32, bitwise = r8-r10) -----------------------
__global__ __launch_bounds__(256) void expand_f32(
    const float* __restrict__ x, float* __restrict__ X, int in_shift, int total) {
  int idx = blockIdx.x * 256 + threadIdx.x;
  if (idx >= total) return;
  int in = 1 << in_shift;
  int i = idx & (in - 1);
  int b = idx >> in_shift;
  float v = x[idx];
  size_t base = (size_t)b * ((size_t)9 << in_shift) + i;
  float bs[8];
  bspl(v, bs);
  X[base] = silu_f(v);
#pragma unroll
  for (int g = 0; g < 8; ++g)
    X[base + ((size_t)(g + 1) << in_shift)] = bs[g];
}

// ---------------- f32 tiled GEMM v4: dbuf + SEGMENTED ACCUMULATION --------
// BM=128, BN template (128 or 64), BK=32, 256 threads. v4 adds: (1) per-tile
// accumulator flush (acc_t += acc; acc = 0 every 32 k) -- segmented/pairwise
// summation, ~10x lower rounding error vs one serial K-chain, ~3% VALU cost.
// (2) BN=64 variant for the N=512 layer (grid 512 blocks = 2/CU, LDS 51KB).
template <bool SILU, int BN>
__global__ __launch_bounds__(256, BN == 64 ? 3 : 2) void gemm_f32(
    const float* __restrict__ A, const float* __restrict__ B,
    float* __restrict__ C, int M, int N, int K, int ldc) {
  constexpr int TN = BN / 16;          // per-thread output cols (8 or 4)
  constexpr int BP = BN / 32;          // B staging passes (4 or 2)
  __shared__ float As[2][32][132];
  __shared__ float Bs[2][32][BN + 4];
  const int tid = threadIdx.x;
  const int bm = blockIdx.y * 128, bn = blockIdx.x * BN;
  const int tx = tid & 15, ty = tid >> 4;   // 16x16 thread grid
  const int sr = tid >> 3;                  // staging row 0..31 (per pass)
  const int sk = (tid & 7) * 4;             // staging k-offset 0,4,...,28
  const float* gA = A + (size_t)(bm + sr) * K + sk;
  const float* gB = B + (size_t)(bn + sr) * K + sk;
  float acc[8][TN] = {};
  float acc_t[8][TN] = {};
  float4 av[4], bv[BP];
  const int NT = K >> 5;
  // prologue: tile 0 -> regs -> LDS buf 0
#pragma unroll
  for (int p = 0; p < 4; ++p)
    av[p] = *(const float4*)(gA + (size_t)p * 32 * K);
#pragma unroll
  for (int p = 0; p < BP; ++p)
    bv[p] = *(const float4*)(gB + (size_t)p * 32 * K);
#pragma unroll
  for (int p = 0; p < 4; ++p) {
    int m = p * 32 + sr;
    As[0][sk + 0][m] = av[p].x; As[0][sk + 1][m] = av[p].y;
    As[0][sk + 2][m] = av[p].z; As[0][sk + 3][m] = av[p].w;
  }
#pragma unroll
  for (int p = 0; p < BP; ++p) {
    int m = p * 32 + sr;
    Bs[0][sk + 0][m] = bv[p].x; Bs[0][sk + 1][m] = bv[p].y;
    Bs[0][sk + 2][m] = bv[p].z; Bs[0][sk + 3][m] = bv[p].w;
  }
  __syncthreads();
  for (int t = 0; t < NT; ++t) {
    const int cur = t & 1;
    if (t + 1 < NT) {
      const int k0 = (t + 1) << 5;
#pragma unroll
      for (int p = 0; p < 4; ++p)
        av[p] = *(const float4*)(gA + (size_t)p * 32 * K + k0);
#pragma unroll
      for (int p = 0; p < BP; ++p)
        bv[p] = *(const float4*)(gB + (size_t)p * 32 * K + k0);
    }
#pragma unroll 4
    for (int kk = 0; kk < 32; ++kk) {
      float4 a0 = *(const float4*)&As[cur][kk][ty * 8];
      float4 a1 = *(const float4*)&As[cur][kk][ty * 8 + 4];
      float a[8] = {a0.x, a0.y, a0.z, a0.w, a1.x, a1.y, a1.z, a1.w};
      float b[TN];
#pragma unroll
      for (int q = 0; q < TN; q += 4) {
        float4 bq = *(const float4*)&Bs[cur][kk][tx * TN + q];
        b[q] = bq.x; b[q + 1] = bq.y; b[q + 2] = bq.z; b[q + 3] = bq.w;
      }
#pragma unroll
      for (int j = 0; j < 8; ++j)
#pragma unroll
        for (int l = 0; l < TN; ++l)
          acc[j][l] += a[j] * b[l];
    }
    // segmented-sum flush: one 32-k segment into the running total
#pragma unroll
    for (int j = 0; j < 8; ++j)
#pragma unroll
      for (int l = 0; l < TN; ++l) {
        acc_t[j][l] += acc[j][l];
        acc[j][l] = 0.0f;
      }
    if (t + 1 < NT) {
      const int nxt = cur ^ 1;
#pragma unroll
      for (int p = 0; p < 4; ++p) {
        int m = p * 32 + sr;
        As[nxt][sk + 0][m] = av[p].x; As[nxt][sk + 1][m] = av[p].y;
        As[nxt][sk + 2][m] = av[p].z; As[nxt][sk + 3][m] = av[p].w;
      }
#pragma unroll
      for (int p = 0; p < BP; ++p) {
        int m = p * 32 + sr;
        Bs[nxt][sk + 0][m] = bv[p].x; Bs[nxt][sk + 1][m] = bv[p].y;
        Bs[nxt][sk + 2][m] = bv[p].z; Bs[nxt][sk + 3][m] = bv[p].w;
      }
      __syncthreads();
    }
  }
#pragma unroll
  for (int j = 0; j < 8; ++j) {
    int r = bm + ty * 8 + j;
    float* cp = C + (size_t)r * ldc + bn + tx * TN;
#pragma unroll
    for (int q = 0; q < TN; q += 4) {
      float4 o;
      o.x = acc_t[j][q]; o.y = acc_t[j][q + 1];
      o.z = acc_t[j][q + 2]; o.w = acc_t[j][q + 3];
      if (SILU) {
        o.x = silu_f(o.x); o.y = silu_f(o.y);
        o.z = silu_f(o.z); o.w = silu_f(o.w);
      }
      *(float4*)(cp + q) = o;
    }
  }
}

extern "C" void kernel_launch(void* const* d_in, const int* in_sizes, int n_in,
                              void* d_out, int out_size, void* d_ws, size_t ws_size,
                              hipStream_t stream) {
  const float* z   = (const float*)d_in[1];
  const float* lng = (const float*)d_in[2];
  const float* lnb = (const float*)d_in[3];
  const float* bw1 = (const float*)d_in[5];
  const float* sw1 = (const float*)d_in[6];
  const float* sc1 = (const float*)d_in[7];
  const float* bw2 = (const float*)d_in[9];
  const float* sw2 = (const float*)d_in[10];
  const float* sc2 = (const float*)d_in[11];
  const float* bw3 = (const float*)d_in[13];
  const float* sw3 = (const float*)d_in[14];
  const float* sc3 = (const float*)d_in[15];
  float* out = (float*)d_out;

  const int B = 8192, D = 512, H = 1024;
  char* ws = (char*)d_ws;
  size_t off = 0;
  float* ln_out = (float*)(ws + off); off += (size_t)B * D * 4;
  float* hbuf   = (float*)(ws + off); off += (size_t)B * H * 4;  // activated h
  float* Wbuf   = (float*)(ws + off); off += (size_t)H * 9216 * 4;
  size_t rem = ws_size > off ? ws_size - off : 0;
  int CB = 128;
  {
    const int cands[6] = {8192, 4096, 2048, 1024, 512, 256};
    for (int c = 0; c < 6; ++c) {
      if ((size_t)cands[c] * 9216 * 4 <= rem) { CB = cands[c]; break; }
    }
  }
  float* Xexp = (float*)(ws + off);

  ln_kernel<<<B / 4, 256, 0, stream>>>(z, lng, lnb, ln_out);

  // ---- layer 1: in=512, out=1024, silu epilogue
  {
    const int in_shift = 9, K = 9 * D, N = H;
    prep_w_f32<<<(H * D + 255) / 256, 256, 0, stream>>>(bw1, sw1, sc1, Wbuf, in_shift, H * D);
    for (int r0 = 0; r0 < B; r0 += CB) {
      int cb = (B - r0 < CB) ? (B - r0) : CB;
      expand_f32<<<(cb << in_shift) / 256, 256, 0, stream>>>(
          ln_out + (size_t)r0 * D, Xexp, in_shift, cb << in_shift);
      dim3 grid(N / 128, cb / 128);
      gemm_f32<true, 128><<<grid, 256, 0, stream>>>(Xexp, Wbuf, hbuf + (size_t)r0 * H, cb, N, K, H);
    }
  }
  // ---- layer 2: in=1024, out=1024, silu epilogue
  {
    const int in_shift = 10, K = 9 * H, N = H;
    prep_w_f32<<<(H * H + 255) / 256, 256, 0, stream>>>(bw2, sw2, sc2, Wbuf, in_shift, H * H);
    for (int r0 = 0; r0 < B; r0 += CB) {
      int cb = (B - r0 < CB) ? (B - r0) : CB;
      expand_f32<<<(cb << in_shift) / 256, 256, 0, stream>>>(
          hbuf + (size_t)r0 * H, Xexp, in_shift, cb << in_shift);
      dim3 grid(N / 128, cb / 128);
      gemm_f32<true, 128><<<grid, 256, 0, stream>>>(Xexp, Wbuf, hbuf + (size_t)r0 * H, cb, N, K, H);
    }
  }
  // ---- layer 3: in=1024, out=512, no silu, BN=64 (512 blocks = 2/CU)
  {
    const int in_shift = 10, K = 9 * H, N = D;
    prep_w_f32<<<(D * H + 255) / 256, 256, 0, stream>>>(bw3, sw3, sc3, Wbuf, in_shift, D * H);
    for (int r0 = 0; r0 < B; r0 += CB) {
      int cb = (B - r0 < CB) ? (B - r0) : CB;
      expand_f32<<<(cb << in_shift) / 256, 256, 0, stream>>>(
          hbuf + (size_t)r0 * H, Xexp, in_shift, cb << in_shift);
      dim3 grid(N / 64, cb / 128);
      gemm_f32<false, 64><<<grid, 256, 0, stream>>>(Xexp, Wbuf, out + (size_t)r0 * D, cb, N, K, D);
    }
  }
}

// Round 13
// 4364.684 us; speedup vs baseline: 1.5243x; 1.0495x over previous
//
#include <hip/hip_runtime.h>
#include <hip/hip_bf16.h>
#include <cstdint>

typedef unsigned short u16;
typedef short short8 __attribute__((ext_vector_type(8)));
typedef float f32x4 __attribute__((ext_vector_type(4)));

__device__ __forceinline__ float silu_f(float v) {
  return v / (1.0f + expf(-v));
}

// f32 -> bf16 round-to-nearest-even
__device__ __forceinline__ u16 f2bf(float f) {
  union { float f; uint32_t u; } v; v.f = f;
  uint32_t r = v.u + 0x7fffu + ((v.u >> 16) & 1u);
  return (u16)(r >> 16);
}
__device__ __forceinline__ float bf2f(u16 b) {
  union { uint32_t u; float f; } v; v.u = ((uint32_t)b) << 16;
  return v.f;
}
// bf16x2 split: hi = bf16(x), lo = bf16(x - hi). bf16 exponent range == f32,
// so the lo plane never denormal-flushes.
__device__ __forceinline__ void split_bf(float f, u16* hi, u16* lo) {
  u16 h = f2bf(f);
  *hi = h;
  *lo = f2bf(f - bf2f(h));
}

// B-spline bases, exact Cox-de Boor recursion matching the reference.
__device__ __forceinline__ void bspl(float x, float* b8) {
  float b[11];
#pragma unroll
  for (int j = 0; j < 11; ++j) {
    float g0 = -2.2f + 0.4f * j;
    float g1 = g0 + 0.4f;
    b[j] = (x >= g0 && x < g1) ? 1.0f : 0.0f;
  }
#pragma unroll
  for (int k = 1; k <= 3; ++k) {
    float inv = 1.0f / (0.4f * k);
#pragma unroll
    for (int j = 0; j + k < 11; ++j) {
      float gj = -2.2f + 0.4f * j;
      float l = (x - gj) * inv;
      float r = (gj + 0.4f * (k + 1) - x) * inv;
      b[j] = l * b[j] + r * b[j + 1];
    }
  }
#pragma unroll
  for (int g = 0; g < 8; ++g) b8[g] = b[g];
}

// ---------------- LayerNorm (bitwise = r8-r11) ----------------------------
__global__ __launch_bounds__(256) void ln_kernel(
    const float* __restrict__ z, const float* __restrict__ gamma,
    const float* __restrict__ beta, float* __restrict__ out) {
  const int row = blockIdx.x * 4 + (threadIdx.x >> 6);
  const int lane = threadIdx.x & 63;
  const float4* zr = (const float4*)(z + (size_t)row * 512);
  float4 v0 = zr[lane * 2], v1 = zr[lane * 2 + 1];
  float s = v0.x + v0.y + v0.z + v0.w + v1.x + v1.y + v1.z + v1.w;
  float q = v0.x * v0.x + v0.y * v0.y + v0.z * v0.z + v0.w * v0.w +
            v1.x * v1.x + v1.y * v1.y + v1.z * v1.z + v1.w * v1.w;
#pragma unroll
  for (int o = 32; o > 0; o >>= 1) {
    s += __shfl_down(s, o);
    q += __shfl_down(q, o);
  }
  float mu = __shfl(s, 0) * (1.0f / 512.0f);
  float ex2 = __shfl(q, 0) * (1.0f / 512.0f);
  float rs = rsqrtf(ex2 - mu * mu + 1e-5f);
  const float4* gp = (const float4*)gamma;
  const float4* bp = (const float4*)beta;
  float4 g0 = gp[lane * 2], g1 = gp[lane * 2 + 1];
  float4 b0 = bp[lane * 2], b1 = bp[lane * 2 + 1];
  float4 o0, o1;
  o0.x = (v0.x - mu) * rs * g0.x + b0.x;
  o0.y = (v0.y - mu) * rs * g0.y + b0.y;
  o0.z = (v0.z - mu) * rs * g0.z + b0.z;
  o0.w = (v0.w - mu) * rs * g0.w + b0.w;
  o1.x = (v1.x - mu) * rs * g1.x + b1.x;
  o1.y = (v1.y - mu) * rs * g1.y + b1.y;
  o1.z = (v1.z - mu) * rs * g1.z + b1.z;
  o1.w = (v1.w - mu) * rs * g1.w + b1.w;
  float4* op = (float4*)(out + (size_t)row * 512);
  op[lane * 2] = o0;
  op[lane * 2 + 1] = o1;
}

// ---------------- W_eff prep f32 (bitwise = r8-r11) -----------------------
__global__ __launch_bounds__(256) void prep_w_f32(
    const float* __restrict__ bw, const float* __restrict__ sw,
    const float* __restrict__ sc, float* __restrict__ W,
    int in_shift, int total) {
  int idx = blockIdx.x * 256 + threadIdx.x;
  if (idx >= total) return;
  int in = 1 << in_shift;
  int i = idx & (in - 1);
  int o = idx >> in_shift;
  size_t wb = (size_t)o * ((size_t)9 << in_shift) + i;
  float s = sc[idx];
  const float4* swp = (const float4*)(sw + (size_t)idx * 8);
  float4 a = swp[0], b = swp[1];
  W[wb] = bw[idx];
  W[wb + ((size_t)1 << in_shift)] = a.x * s;
  W[wb + ((size_t)2 << in_shift)] = a.y * s;
  W[wb + ((size_t)3 << in_shift)] = a.z * s;
  W[wb + ((size_t)4 << in_shift)] = a.w * s;
  W[wb + ((size_t)5 << in_shift)] = b.x * s;
  W[wb + ((size_t)6 << in_shift)] = b.y * s;
  W[wb + ((size_t)7 << in_shift)] = b.z * s;
  W[wb + ((size_t)8 << in_shift)] = b.w * s;
}

// ---------------- expansion f32 (bitwise = r8-r11) ------------------------
__global__ __launch_bounds__(256) void expand_f32(
    const float* __restrict__ x, float* __restrict__ X, int in_shift, int total) {
  int idx = blockIdx.x * 256 + threadIdx.x;
  if (idx >= total) return;
  int in = 1 << in_shift;
  int i = idx & (in - 1);
  int b = idx >> in_shift;
  float v = x[idx];
  size_t base = (size_t)b * ((size_t)9 << in_shift) + i;
  float bs[8];
  bspl(v, bs);
  X[base] = silu_f(v);
#pragma unroll
  for (int g = 0; g < 8; ++g)
    X[base + ((size_t)(g + 1) << in_shift)] = bs[g];
}

// ---------------- W_eff prep bf16 hi/lo (layer 3 only) --------------------
__global__ __launch_bounds__(256) void prep_w_bf(
    const float* __restrict__ bw, const float* __restrict__ sw,
    const float* __restrict__ sc, u16* __restrict__ Wh, u16* __restrict__ Wl,
    int in_shift, int total) {
  int idx = blockIdx.x * 256 + threadIdx.x;
  if (idx >= total) return;
  int in = 1 << in_shift;
  int i = idx & (in - 1);
  int o = idx >> in_shift;
  size_t wb = (size_t)o * ((size_t)9 << in_shift) + i;
  float s = sc[idx];
  const float4* swp = (const float4*)(sw + (size_t)idx * 8);
  float4 a = swp[0], b = swp[1];
  float vals[9] = {bw[idx], a.x * s, a.y * s, a.z * s, a.w * s,
                   b.x * s, b.y * s, b.z * s, b.w * s};
#pragma unroll
  for (int c = 0; c < 9; ++c) {
    u16 h, l;
    split_bf(vals[c], &h, &l);
    Wh[wb + ((size_t)c << in_shift)] = h;
    Wl[wb + ((size_t)c << in_shift)] = l;
  }
}

// ---------------- expansion bf16 hi/lo (layer 3 only) ---------------------
__global__ __launch_bounds__(256) void expand_bf(
    const float* __restrict__ x, u16* __restrict__ Xh, u16* __restrict__ Xl,
    int in_shift, int total) {
  int idx = blockIdx.x * 256 + threadIdx.x;
  if (idx >= total) return;
  int in = 1 << in_shift;
  int i = idx & (in - 1);
  int b = idx >> in_shift;
  float v = x[idx];
  size_t base = (size_t)b * ((size_t)9 << in_shift) + i;
  float bs[8];
  bspl(v, bs);
  float vals[9];
  vals[0] = silu_f(v);
#pragma unroll
  for (int g = 0; g < 8; ++g) vals[g + 1] = bs[g];
#pragma unroll
  for (int c = 0; c < 9; ++c) {
    u16 h, l;
    split_bf(vals[c], &h, &l);
    Xh[base + ((size_t)c << in_shift)] = h;
    Xl[base + ((size_t)c << in_shift)] = l;
  }
}

// ---------------- f32 tiled GEMM (bitwise = r11) --------------------------
template <bool SILU, int BN>
__global__ __launch_bounds__(256, BN == 64 ? 3 : 2) void gemm_f32(
    const float* __restrict__ A, const float* __restrict__ B,
    float* __restrict__ C, int M, int N, int K, int ldc) {
  constexpr int TN = BN / 16;
  constexpr int BP = BN / 32;
  __shared__ float As[2][32][132];
  __shared__ float Bs[2][32][BN + 4];
  const int tid = threadIdx.x;
  const int bm = blockIdx.y * 128, bn = blockIdx.x * BN;
  const int tx = tid & 15, ty = tid >> 4;
  const int sr = tid >> 3;
  const int sk = (tid & 7) * 4;
  const float* gA = A + (size_t)(bm + sr) * K + sk;
  const float* gB = B + (size_t)(bn + sr) * K + sk;
  float acc[8][TN] = {};
  float acc_t[8][TN] = {};
  float4 av[4], bv[BP];
  const int NT = K >> 5;
#pragma unroll
  for (int p = 0; p < 4; ++p)
    av[p] = *(const float4*)(gA + (size_t)p * 32 * K);
#pragma unroll
  for (int p = 0; p < BP; ++p)
    bv[p] = *(const float4*)(gB + (size_t)p * 32 * K);
#pragma unroll
  for (int p = 0; p < 4; ++p) {
    int m = p * 32 + sr;
    As[0][sk + 0][m] = av[p].x; As[0][sk + 1][m] = av[p].y;
    As[0][sk + 2][m] = av[p].z; As[0][sk + 3][m] = av[p].w;
  }
#pragma unroll
  for (int p = 0; p < BP; ++p) {
    int m = p * 32 + sr;
    Bs[0][sk + 0][m] = bv[p].x; Bs[0][sk + 1][m] = bv[p].y;
    Bs[0][sk + 2][m] = bv[p].z; Bs[0][sk + 3][m] = bv[p].w;
  }
  __syncthreads();
  for (int t = 0; t < NT; ++t) {
    const int cur = t & 1;
    if (t + 1 < NT) {
      const int k0 = (t + 1) << 5;
#pragma unroll
      for (int p = 0; p < 4; ++p)
        av[p] = *(const float4*)(gA + (size_t)p * 32 * K + k0);
#pragma unroll
      for (int p = 0; p < BP; ++p)
        bv[p] = *(const float4*)(gB + (size_t)p * 32 * K + k0);
    }
#pragma unroll 4
    for (int kk = 0; kk < 32; ++kk) {
      float4 a0 = *(const float4*)&As[cur][kk][ty * 8];
      float4 a1 = *(const float4*)&As[cur][kk][ty * 8 + 4];
      float a[8] = {a0.x, a0.y, a0.z, a0.w, a1.x, a1.y, a1.z, a1.w};
      float b[TN];
#pragma unroll
      for (int q = 0; q < TN; q += 4) {
        float4 bq = *(const float4*)&Bs[cur][kk][tx * TN + q];
        b[q] = bq.x; b[q + 1] = bq.y; b[q + 2] = bq.z; b[q + 3] = bq.w;
      }
#pragma unroll
      for (int j = 0; j < 8; ++j)
#pragma unroll
        for (int l = 0; l < TN; ++l)
          acc[j][l] += a[j] * b[l];
    }
#pragma unroll
    for (int j = 0; j < 8; ++j)
#pragma unroll
      for (int l = 0; l < TN; ++l) {
        acc_t[j][l] += acc[j][l];
        acc[j][l] = 0.0f;
      }
    if (t + 1 < NT) {
      const int nxt = cur ^ 1;
#pragma unroll
      for (int p = 0; p < 4; ++p) {
        int m = p * 32 + sr;
        As[nxt][sk + 0][m] = av[p].x; As[nxt][sk + 1][m] = av[p].y;
        As[nxt][sk + 2][m] = av[p].z; As[nxt][sk + 3][m] = av[p].w;
      }
#pragma unroll
      for (int p = 0; p < BP; ++p) {
        int m = p * 32 + sr;
        Bs[nxt][sk + 0][m] = bv[p].x; Bs[nxt][sk + 1][m] = bv[p].y;
        Bs[nxt][sk + 2][m] = bv[p].z; Bs[nxt][sk + 3][m] = bv[p].w;
      }
      __syncthreads();
    }
  }
#pragma unroll
  for (int j = 0; j < 8; ++j) {
    int r = bm + ty * 8 + j;
    float* cp = C + (size_t)r * ldc + bn + tx * TN;
#pragma unroll
    for (int q = 0; q < TN; q += 4) {
      float4 o;
      o.x = acc_t[j][q]; o.y = acc_t[j][q + 1];
      o.z = acc_t[j][q + 2]; o.w = acc_t[j][q + 3];
      if (SILU) {
        o.x = silu_f(o.x); o.y = silu_f(o.y);
        o.z = silu_f(o.z); o.w = silu_f(o.w);
      }
      *(float4*)(cp + q) = o;
    }
  }
}

// ---------------- MFMA GEMM bf16x2 3-pass (layer 3 only this round) -------
__device__ __forceinline__ void gload_lds16(const u16* g, u16* l) {
  __builtin_amdgcn_global_load_lds(
      (const __attribute__((address_space(1))) void*)g,
      (__attribute__((address_space(3))) void*)l, 16, 0, 0);
}

template <bool SILU>
__global__ __launch_bounds__(256) void gemm_mfma(
    const u16* __restrict__ Ah, const u16* __restrict__ Al,
    const u16* __restrict__ Wh, const u16* __restrict__ Wl,
    float* __restrict__ C, int M, int N, int K, int ldc) {
  __shared__ __align__(16) u16 lsA[128 * 64];
  __shared__ __align__(16) u16 lsB[128 * 64];
  const int tid = threadIdx.x;
  const int wave = tid >> 6, lane = tid & 63;
  const int bm = blockIdx.y * 128, bn = blockIdx.x * 128;
  const int srow = wave * 8 + (lane >> 3);
  const int scol = (lane & 7) * 8;
  u16* lA = &lsA[wave * 512 + lane * 8];
  u16* lB = &lsB[wave * 512 + lane * 8];
  const int wm = wave >> 1, wn = wave & 1;
  const int fr = lane & 15, kg = lane >> 4;
  const u16* rA = &lsA[(wm * 64 + fr) * 64 + kg * 8];
  const u16* rB = &lsB[(wn * 64 + fr) * 64 + kg * 8];
  f32x4 acc[4][4] = {};
#pragma unroll
  for (int ph = 0; ph < 3; ++ph) {
    const u16* Ap = (ph == 1) ? Al : Ah;
    const u16* Bp = (ph == 2) ? Wl : Wh;
    const u16* gA = Ap + (size_t)(bm + srow) * K + scol;
    const u16* gB = Bp + (size_t)(bn + srow) * K + scol;
    for (int k0 = 0; k0 < K; k0 += 64) {
#pragma unroll
      for (int s = 0; s < 4; ++s) {
        gload_lds16(gA + (size_t)s * 32 * K + k0, lA + s * 2048);
        gload_lds16(gB + (size_t)s * 32 * K + k0, lB + s * 2048);
      }
      __syncthreads();
#pragma unroll
      for (int kc = 0; kc < 2; ++kc) {
        short8 af[4], bv[4];
#pragma unroll
        for (int m = 0; m < 4; ++m)
          af[m] = *(const short8*)(rA + m * 16 * 64 + kc * 32);
#pragma unroll
        for (int n = 0; n < 4; ++n)
          bv[n] = *(const short8*)(rB + n * 16 * 64 + kc * 32);
#pragma unroll
        for (int m = 0; m < 4; ++m)
#pragma unroll
          for (int n = 0; n < 4; ++n)
            acc[m][n] = __builtin_amdgcn_mfma_f32_16x16x32_bf16(
                af[m], bv[n], acc[m][n], 0, 0, 0);
      }
      __syncthreads();
    }
  }
#pragma unroll
  for (int m = 0; m < 4; ++m) {
#pragma unroll
    for (int n = 0; n < 4; ++n) {
#pragma unroll
      for (int v = 0; v < 4; ++v) {
        int r = bm + wm * 64 + m * 16 + kg * 4 + v;
        int c = bn + wn * 64 + n * 16 + fr;
        float val = acc[m][n][v];
        if (SILU) val = silu_f(val);
        C[(size_t)r * ldc + c] = val;
      }
    }
  }
}

extern "C" void kernel_launch(void* const* d_in, const int* in_sizes, int n_in,
                              void* d_out, int out_size, void* d_ws, size_t ws_size,
                              hipStream_t stream) {
  const float* z   = (const float*)d_in[1];
  const float* lng = (const float*)d_in[2];
  const float* lnb = (const float*)d_in[3];
  const float* bw1 = (const float*)d_in[5];
  const float* sw1 = (const float*)d_in[6];
  const float* sc1 = (const float*)d_in[7];
  const float* bw2 = (const float*)d_in[9];
  const float* sw2 = (const float*)d_in[10];
  const float* sc2 = (const float*)d_in[11];
  const float* bw3 = (const float*)d_in[13];
  const float* sw3 = (const float*)d_in[14];
  const float* sc3 = (const float*)d_in[15];
  float* out = (float*)d_out;

  const int B = 8192, D = 512, H = 1024;
  char* ws = (char*)d_ws;
  size_t off = 0;
  float* ln_out = (float*)(ws + off); off += (size_t)B * D * 4;
  float* hbuf   = (float*)(ws + off); off += (size_t)B * H * 4;  // activated h
  float* Wbuf   = (float*)(ws + off); off += (size_t)H * 9216 * 4;
  size_t rem = ws_size > off ? ws_size - off : 0;
  int CB = 128;
  {
    const int cands[6] = {8192, 4096, 2048, 1024, 512, 256};
    for (int c = 0; c < 6; ++c) {
      if ((size_t)cands[c] * 9216 * 4 <= rem) { CB = cands[c]; break; }
    }
  }
  float* Xexp = (float*)(ws + off);
  // layer-3 bf16 overlays (safe: stream-ordered after all f32 uses)
  u16* Wh3 = (u16*)Wbuf;                      // 512*9216*2 = 9.4MB of 37.7MB
  u16* Wl3 = Wh3 + (size_t)D * 9216;
  u16* Xh3 = (u16*)Xexp;                      // CB*9216*2 each, == f32 footprint
  u16* Xl3 = Xh3 + (size_t)CB * 9216;

  ln_kernel<<<B / 4, 256, 0, stream>>>(z, lng, lnb, ln_out);

  // ---- layer 1: f32 (bitwise = r11)
  {
    const int in_shift = 9, K = 9 * D, N = H;
    prep_w_f32<<<(H * D + 255) / 256, 256, 0, stream>>>(bw1, sw1, sc1, Wbuf, in_shift, H * D);
    for (int r0 = 0; r0 < B; r0 += CB) {
      int cb = (B - r0 < CB) ? (B - r0) : CB;
      expand_f32<<<(cb << in_shift) / 256, 256, 0, stream>>>(
          ln_out + (size_t)r0 * D, Xexp, in_shift, cb << in_shift);
      dim3 grid(N / 128, cb / 128);
      gemm_f32<true, 128><<<grid, 256, 0, stream>>>(Xexp, Wbuf, hbuf + (size_t)r0 * H, cb, N, K, H);
    }
  }
  // ---- layer 2: f32 (bitwise = r11)
  {
    const int in_shift = 10, K = 9 * H, N = H;
    prep_w_f32<<<(H * H + 255) / 256, 256, 0, stream>>>(bw2, sw2, sc2, Wbuf, in_shift, H * H);
    for (int r0 = 0; r0 < B; r0 += CB) {
      int cb = (B - r0 < CB) ? (B - r0) : CB;
      expand_f32<<<(cb << in_shift) / 256, 256, 0, stream>>>(
          hbuf + (size_t)r0 * H, Xexp, in_shift, cb << in_shift);
      dim3 grid(N / 128, cb / 128);
      gemm_f32<true, 128><<<grid, 256, 0, stream>>>(Xexp, Wbuf, hbuf + (size_t)r0 * H, cb, N, K, H);
    }
  }
  // ---- layer 3: bf16x2 3-pass MFMA (THE experiment; unamplified layer)
  {
    const int in_shift = 10, K = 9 * H, N = D;
    prep_w_bf<<<(D * H + 255) / 256, 256, 0, stream>>>(bw3, sw3, sc3, Wh3, Wl3, in_shift, D * H);
    for (int r0 = 0; r0 < B; r0 += CB) {
      int cb = (B - r0 < CB) ? (B - r0) : CB;
      expand_bf<<<(cb << in_shift) / 256, 256, 0, stream>>>(
          hbuf + (size_t)r0 * H, Xh3, Xl3, in_shift, cb << in_shift);
      dim3 grid(N / 128, cb / 128);
      gemm_mfma<false><<<grid, 256, 0, stream>>>(
          Xh3, Xl3, Wh3, Wl3, out + (size_t)r0 * D, cb, N, K, D);
    }
  }
}

// Round 14
// 3396.293 us; speedup vs baseline: 1.9589x; 1.2851x over previous
//
#include <hip/hip_runtime.h>
#include <hip/hip_bf16.h>
#include <cstdint>

typedef unsigned short u16;
typedef short short8 __attribute__((ext_vector_type(8)));
typedef float f32x4 __attribute__((ext_vector_type(4)));

__device__ __forceinline__ float silu_f(float v) {
  return v / (1.0f + expf(-v));
}

// f32 -> bf16 round-to-nearest-even
__device__ __forceinline__ u16 f2bf(float f) {
  union { float f; uint32_t u; } v; v.f = f;
  uint32_t r = v.u + 0x7fffu + ((v.u >> 16) & 1u);
  return (u16)(r >> 16);
}
__device__ __forceinline__ float bf2f(u16 b) {
  union { uint32_t u; float f; } v; v.u = ((uint32_t)b) << 16;
  return v.f;
}
// bf16x2 split: hi = bf16(x), lo = bf16(x - hi). bf16 exponent range == f32,
// so the lo plane never denormal-flushes.
__device__ __forceinline__ void split_bf(float f, u16* hi, u16* lo) {
  u16 h = f2bf(f);
  *hi = h;
  *lo = f2bf(f - bf2f(h));
}

// B-spline bases, exact Cox-de Boor recursion matching the reference.
__device__ __forceinline__ void bspl(float x, float* b8) {
  float b[11];
#pragma unroll
  for (int j = 0; j < 11; ++j) {
    float g0 = -2.2f + 0.4f * j;
    float g1 = g0 + 0.4f;
    b[j] = (x >= g0 && x < g1) ? 1.0f : 0.0f;
  }
#pragma unroll
  for (int k = 1; k <= 3; ++k) {
    float inv = 1.0f / (0.4f * k);
#pragma unroll
    for (int j = 0; j + k < 11; ++j) {
      float gj = -2.2f + 0.4f * j;
      float l = (x - gj) * inv;
      float r = (gj + 0.4f * (k + 1) - x) * inv;
      b[j] = l * b[j] + r * b[j + 1];
    }
  }
#pragma unroll
  for (int g = 0; g < 8; ++g) b8[g] = b[g];
}

// ---------------- LayerNorm (bitwise = r8-r13) ----------------------------
__global__ __launch_bounds__(256) void ln_kernel(
    const float* __restrict__ z, const float* __restrict__ gamma,
    const float* __restrict__ beta, float* __restrict__ out) {
  const int row = blockIdx.x * 4 + (threadIdx.x >> 6);
  const int lane = threadIdx.x & 63;
  const float4* zr = (const float4*)(z + (size_t)row * 512);
  float4 v0 = zr[lane * 2], v1 = zr[lane * 2 + 1];
  float s = v0.x + v0.y + v0.z + v0.w + v1.x + v1.y + v1.z + v1.w;
  float q = v0.x * v0.x + v0.y * v0.y + v0.z * v0.z + v0.w * v0.w +
            v1.x * v1.x + v1.y * v1.y + v1.z * v1.z + v1.w * v1.w;
#pragma unroll
  for (int o = 32; o > 0; o >>= 1) {
    s += __shfl_down(s, o);
    q += __shfl_down(q, o);
  }
  float mu = __shfl(s, 0) * (1.0f / 512.0f);
  float ex2 = __shfl(q, 0) * (1.0f / 512.0f);
  float rs = rsqrtf(ex2 - mu * mu + 1e-5f);
  const float4* gp = (const float4*)gamma;
  const float4* bp = (const float4*)beta;
  float4 g0 = gp[lane * 2], g1 = gp[lane * 2 + 1];
  float4 b0 = bp[lane * 2], b1 = bp[lane * 2 + 1];
  float4 o0, o1;
  o0.x = (v0.x - mu) * rs * g0.x + b0.x;
  o0.y = (v0.y - mu) * rs * g0.y + b0.y;
  o0.z = (v0.z - mu) * rs * g0.z + b0.z;
  o0.w = (v0.w - mu) * rs * g0.w + b0.w;
  o1.x = (v1.x - mu) * rs * g1.x + b1.x;
  o1.y = (v1.y - mu) * rs * g1.y + b1.y;
  o1.z = (v1.z - mu) * rs * g1.z + b1.z;
  o1.w = (v1.w - mu) * rs * g1.w + b1.w;
  float4* op = (float4*)(out + (size_t)row * 512);
  op[lane * 2] = o0;
  op[lane * 2 + 1] = o1;
}

// ---------------- W_eff prep f32 (bitwise = r8-r13, L1 only now) ----------
__global__ __launch_bounds__(256) void prep_w_f32(
    const float* __restrict__ bw, const float* __restrict__ sw,
    const float* __restrict__ sc, float* __restrict__ W,
    int in_shift, int total) {
  int idx = blockIdx.x * 256 + threadIdx.x;
  if (idx >= total) return;
  int in = 1 << in_shift;
  int i = idx & (in - 1);
  int o = idx >> in_shift;
  size_t wb = (size_t)o * ((size_t)9 << in_shift) + i;
  float s = sc[idx];
  const float4* swp = (const float4*)(sw + (size_t)idx * 8);
  float4 a = swp[0], b = swp[1];
  W[wb] = bw[idx];
  W[wb + ((size_t)1 << in_shift)] = a.x * s;
  W[wb + ((size_t)2 << in_shift)] = a.y * s;
  W[wb + ((size_t)3 << in_shift)] = a.z * s;
  W[wb + ((size_t)4 << in_shift)] = a.w * s;
  W[wb + ((size_t)5 << in_shift)] = b.x * s;
  W[wb + ((size_t)6 << in_shift)] = b.y * s;
  W[wb + ((size_t)7 << in_shift)] = b.z * s;
  W[wb + ((size_t)8 << in_shift)] = b.w * s;
}

// ---------------- expansion f32 (bitwise = r8-r13, L1 only now) -----------
__global__ __launch_bounds__(256) void expand_f32(
    const float* __restrict__ x, float* __restrict__ X, int in_shift, int total) {
  int idx = blockIdx.x * 256 + threadIdx.x;
  if (idx >= total) return;
  int in = 1 << in_shift;
  int i = idx & (in - 1);
  int b = idx >> in_shift;
  float v = x[idx];
  size_t base = (size_t)b * ((size_t)9 << in_shift) + i;
  float bs[8];
  bspl(v, bs);
  X[base] = silu_f(v);
#pragma unroll
  for (int g = 0; g < 8; ++g)
    X[base + ((size_t)(g + 1) << in_shift)] = bs[g];
}

// ---------------- W_eff prep bf16 hi/lo (L2 + L3) -------------------------
__global__ __launch_bounds__(256) void prep_w_bf(
    const float* __restrict__ bw, const float* __restrict__ sw,
    const float* __restrict__ sc, u16* __restrict__ Wh, u16* __restrict__ Wl,
    int in_shift, int total) {
  int idx = blockIdx.x * 256 + threadIdx.x;
  if (idx >= total) return;
  int in = 1 << in_shift;
  int i = idx & (in - 1);
  int o = idx >> in_shift;
  size_t wb = (size_t)o * ((size_t)9 << in_shift) + i;
  float s = sc[idx];
  const float4* swp = (const float4*)(sw + (size_t)idx * 8);
  float4 a = swp[0], b = swp[1];
  float vals[9] = {bw[idx], a.x * s, a.y * s, a.z * s, a.w * s,
                   b.x * s, b.y * s, b.z * s, b.w * s};
#pragma unroll
  for (int c = 0; c < 9; ++c) {
    u16 h, l;
    split_bf(vals[c], &h, &l);
    Wh[wb + ((size_t)c << in_shift)] = h;
    Wl[wb + ((size_t)c << in_shift)] = l;
  }
}

// ---------------- expansion bf16 hi/lo (L2 + L3) --------------------------
__global__ __launch_bounds__(256) void expand_bf(
    const float* __restrict__ x, u16* __restrict__ Xh, u16* __restrict__ Xl,
    int in_shift, int total) {
  int idx = blockIdx.x * 256 + threadIdx.x;
  if (idx >= total) return;
  int in = 1 << in_shift;
  int i = idx & (in - 1);
  int b = idx >> in_shift;
  float v = x[idx];
  size_t base = (size_t)b * ((size_t)9 << in_shift) + i;
  float bs[8];
  bspl(v, bs);
  float vals[9];
  vals[0] = silu_f(v);
#pragma unroll
  for (int g = 0; g < 8; ++g) vals[g + 1] = bs[g];
#pragma unroll
  for (int c = 0; c < 9; ++c) {
    u16 h, l;
    split_bf(vals[c], &h, &l);
    Xh[base + ((size_t)c << in_shift)] = h;
    Xl[base + ((size_t)c << in_shift)] = l;
  }
}

// ---------------- f32 tiled GEMM (bitwise = r11, L1 only now) -------------
template <bool SILU, int BN>
__global__ __launch_bounds__(256, BN == 64 ? 3 : 2) void gemm_f32(
    const float* __restrict__ A, const float* __restrict__ B,
    float* __restrict__ C, int M, int N, int K, int ldc) {
  constexpr int TN = BN / 16;
  constexpr int BP = BN / 32;
  __shared__ float As[2][32][132];
  __shared__ float Bs[2][32][BN + 4];
  const int tid = threadIdx.x;
  const int bm = blockIdx.y * 128, bn = blockIdx.x * BN;
  const int tx = tid & 15, ty = tid >> 4;
  const int sr = tid >> 3;
  const int sk = (tid & 7) * 4;
  const float* gA = A + (size_t)(bm + sr) * K + sk;
  const float* gB = B + (size_t)(bn + sr) * K + sk;
  float acc[8][TN] = {};
  float acc_t[8][TN] = {};
  float4 av[4], bv[BP];
  const int NT = K >> 5;
#pragma unroll
  for (int p = 0; p < 4; ++p)
    av[p] = *(const float4*)(gA + (size_t)p * 32 * K);
#pragma unroll
  for (int p = 0; p < BP; ++p)
    bv[p] = *(const float4*)(gB + (size_t)p * 32 * K);
#pragma unroll
  for (int p = 0; p < 4; ++p) {
    int m = p * 32 + sr;
    As[0][sk + 0][m] = av[p].x; As[0][sk + 1][m] = av[p].y;
    As[0][sk + 2][m] = av[p].z; As[0][sk + 3][m] = av[p].w;
  }
#pragma unroll
  for (int p = 0; p < BP; ++p) {
    int m = p * 32 + sr;
    Bs[0][sk + 0][m] = bv[p].x; Bs[0][sk + 1][m] = bv[p].y;
    Bs[0][sk + 2][m] = bv[p].z; Bs[0][sk + 3][m] = bv[p].w;
  }
  __syncthreads();
  for (int t = 0; t < NT; ++t) {
    const int cur = t & 1;
    if (t + 1 < NT) {
      const int k0 = (t + 1) << 5;
#pragma unroll
      for (int p = 0; p < 4; ++p)
        av[p] = *(const float4*)(gA + (size_t)p * 32 * K + k0);
#pragma unroll
      for (int p = 0; p < BP; ++p)
        bv[p] = *(const float4*)(gB + (size_t)p * 32 * K + k0);
    }
#pragma unroll 4
    for (int kk = 0; kk < 32; ++kk) {
      float4 a0 = *(const float4*)&As[cur][kk][ty * 8];
      float4 a1 = *(const float4*)&As[cur][kk][ty * 8 + 4];
      float a[8] = {a0.x, a0.y, a0.z, a0.w, a1.x, a1.y, a1.z, a1.w};
      float b[TN];
#pragma unroll
      for (int q = 0; q < TN; q += 4) {
        float4 bq = *(const float4*)&Bs[cur][kk][tx * TN + q];
        b[q] = bq.x; b[q + 1] = bq.y; b[q + 2] = bq.z; b[q + 3] = bq.w;
      }
#pragma unroll
      for (int j = 0; j < 8; ++j)
#pragma unroll
        for (int l = 0; l < TN; ++l)
          acc[j][l] += a[j] * b[l];
    }
#pragma unroll
    for (int j = 0; j < 8; ++j)
#pragma unroll
      for (int l = 0; l < TN; ++l) {
        acc_t[j][l] += acc[j][l];
        acc[j][l] = 0.0f;
      }
    if (t + 1 < NT) {
      const int nxt = cur ^ 1;
#pragma unroll
      for (int p = 0; p < 4; ++p) {
        int m = p * 32 + sr;
        As[nxt][sk + 0][m] = av[p].x; As[nxt][sk + 1][m] = av[p].y;
        As[nxt][sk + 2][m] = av[p].z; As[nxt][sk + 3][m] = av[p].w;
      }
#pragma unroll
      for (int p = 0; p < BP; ++p) {
        int m = p * 32 + sr;
        Bs[nxt][sk + 0][m] = bv[p].x; Bs[nxt][sk + 1][m] = bv[p].y;
        Bs[nxt][sk + 2][m] = bv[p].z; Bs[nxt][sk + 3][m] = bv[p].w;
      }
      __syncthreads();
    }
  }
#pragma unroll
  for (int j = 0; j < 8; ++j) {
    int r = bm + ty * 8 + j;
    float* cp = C + (size_t)r * ldc + bn + tx * TN;
#pragma unroll
    for (int q = 0; q < TN; q += 4) {
      float4 o;
      o.x = acc_t[j][q]; o.y = acc_t[j][q + 1];
      o.z = acc_t[j][q + 2]; o.w = acc_t[j][q + 3];
      if (SILU) {
        o.x = silu_f(o.x); o.y = silu_f(o.y);
        o.z = silu_f(o.z); o.w = silu_f(o.w);
      }
      *(float4*)(cp + q) = o;
    }
  }
}

// ---------------- MFMA GEMM bf16x2 3-pass (L2 + L3) -----------------------
__device__ __forceinline__ void gload_lds16(const u16* g, u16* l) {
  __builtin_amdgcn_global_load_lds(
      (const __attribute__((address_space(1))) void*)g,
      (__attribute__((address_space(3))) void*)l, 16, 0, 0);
}

template <bool SILU>
__global__ __launch_bounds__(256) void gemm_mfma(
    const u16* __restrict__ Ah, const u16* __restrict__ Al,
    const u16* __restrict__ Wh, const u16* __restrict__ Wl,
    float* __restrict__ C, int M, int N, int K, int ldc) {
  __shared__ __align__(16) u16 lsA[128 * 64];
  __shared__ __align__(16) u16 lsB[128 * 64];
  const int tid = threadIdx.x;
  const int wave = tid >> 6, lane = tid & 63;
  const int bm = blockIdx.y * 128, bn = blockIdx.x * 128;
  const int srow = wave * 8 + (lane >> 3);
  const int scol = (lane & 7) * 8;
  u16* lA = &lsA[wave * 512 + lane * 8];
  u16* lB = &lsB[wave * 512 + lane * 8];
  const int wm = wave >> 1, wn = wave & 1;
  const int fr = lane & 15, kg = lane >> 4;
  const u16* rA = &lsA[(wm * 64 + fr) * 64 + kg * 8];
  const u16* rB = &lsB[(wn * 64 + fr) * 64 + kg * 8];
  f32x4 acc[4][4] = {};
#pragma unroll
  for (int ph = 0; ph < 3; ++ph) {
    const u16* Ap = (ph == 1) ? Al : Ah;
    const u16* Bp = (ph == 2) ? Wl : Wh;
    const u16* gA = Ap + (size_t)(bm + srow) * K + scol;
    const u16* gB = Bp + (size_t)(bn + srow) * K + scol;
    for (int k0 = 0; k0 < K; k0 += 64) {
#pragma unroll
      for (int s = 0; s < 4; ++s) {
        gload_lds16(gA + (size_t)s * 32 * K + k0, lA + s * 2048);
        gload_lds16(gB + (size_t)s * 32 * K + k0, lB + s * 2048);
      }
      __syncthreads();
#pragma unroll
      for (int kc = 0; kc < 2; ++kc) {
        short8 af[4], bv[4];
#pragma unroll
        for (int m = 0; m < 4; ++m)
          af[m] = *(const short8*)(rA + m * 16 * 64 + kc * 32);
#pragma unroll
        for (int n = 0; n < 4; ++n)
          bv[n] = *(const short8*)(rB + n * 16 * 64 + kc * 32);
#pragma unroll
        for (int m = 0; m < 4; ++m)
#pragma unroll
          for (int n = 0; n < 4; ++n)
            acc[m][n] = __builtin_amdgcn_mfma_f32_16x16x32_bf16(
                af[m], bv[n], acc[m][n], 0, 0, 0);
      }
      __syncthreads();
    }
  }
#pragma unroll
  for (int m = 0; m < 4; ++m) {
#pragma unroll
    for (int n = 0; n < 4; ++n) {
#pragma unroll
      for (int v = 0; v < 4; ++v) {
        int r = bm + wm * 64 + m * 16 + kg * 4 + v;
        int c = bn + wn * 64 + n * 16 + fr;
        float val = acc[m][n][v];
        if (SILU) val = silu_f(val);
        C[(size_t)r * ldc + c] = val;
      }
    }
  }
}

extern "C" void kernel_launch(void* const* d_in, const int* in_sizes, int n_in,
                              void* d_out, int out_size, void* d_ws, size_t ws_size,
                              hipStream_t stream) {
  const float* z   = (const float*)d_in[1];
  const float* lng = (const float*)d_in[2];
  const float* lnb = (const float*)d_in[3];
  const float* bw1 = (const float*)d_in[5];
  const float* sw1 = (const float*)d_in[6];
  const float* sc1 = (const float*)d_in[7];
  const float* bw2 = (const float*)d_in[9];
  const float* sw2 = (const float*)d_in[10];
  const float* sc2 = (const float*)d_in[11];
  const float* bw3 = (const float*)d_in[13];
  const float* sw3 = (const float*)d_in[14];
  const float* sc3 = (const float*)d_in[15];
  float* out = (float*)d_out;

  const int B = 8192, D = 512, H = 1024;
  char* ws = (char*)d_ws;
  size_t off = 0;
  float* ln_out = (float*)(ws + off); off += (size_t)B * D * 4;
  float* hbuf   = (float*)(ws + off); off += (size_t)B * H * 4;  // activated h
  float* Wbuf   = (float*)(ws + off); off += (size_t)H * 9216 * 4;
  size_t rem = ws_size > off ? ws_size - off : 0;
  int CB = 128;
  {
    const int cands[6] = {8192, 4096, 2048, 1024, 512, 256};
    for (int c = 0; c < 6; ++c) {
      if ((size_t)cands[c] * 9216 * 4 <= rem) { CB = cands[c]; break; }
    }
  }
  float* Xexp = (float*)(ws + off);
  // bf16 overlays for L2/L3 (stream-ordered after all f32 uses of the region)
  u16* WhB = (u16*)Wbuf;                    // up to H*9216 entries each
  u16* WlB = WhB + (size_t)H * 9216;
  u16* XhB = (u16*)Xexp;                    // CB*9216 entries each
  u16* XlB = XhB + (size_t)CB * 9216;

  ln_kernel<<<B / 4, 256, 0, stream>>>(z, lng, lnb, ln_out);

  // ---- layer 1: f32 (bitwise = r11/r13)
  {
    const int in_shift = 9, K = 9 * D, N = H;
    prep_w_f32<<<(H * D + 255) / 256, 256, 0, stream>>>(bw1, sw1, sc1, Wbuf, in_shift, H * D);
    for (int r0 = 0; r0 < B; r0 += CB) {
      int cb = (B - r0 < CB) ? (B - r0) : CB;
      expand_f32<<<(cb << in_shift) / 256, 256, 0, stream>>>(
          ln_out + (size_t)r0 * D, Xexp, in_shift, cb << in_shift);
      dim3 grid(N / 128, cb / 128);
      gemm_f32<true, 128><<<grid, 256, 0, stream>>>(Xexp, Wbuf, hbuf + (size_t)r0 * H, cb, N, K, H);
    }
  }
  // ---- layer 2: bf16x2 3-pass MFMA with silu epilogue (THIS round's change)
  {
    const int in_shift = 10, K = 9 * H, N = H;
    prep_w_bf<<<(H * H + 255) / 256, 256, 0, stream>>>(bw2, sw2, sc2, WhB, WlB, in_shift, H * H);
    for (int r0 = 0; r0 < B; r0 += CB) {
      int cb = (B - r0 < CB) ? (B - r0) : CB;
      expand_bf<<<(cb << in_shift) / 256, 256, 0, stream>>>(
          hbuf + (size_t)r0 * H, XhB, XlB, in_shift, cb << in_shift);
      dim3 grid(N / 128, cb / 128);
      gemm_mfma<true><<<grid, 256, 0, stream>>>(
          XhB, XlB, WhB, WlB, hbuf + (size_t)r0 * H, cb, N, K, H);
    }
  }
  // ---- layer 3: bf16x2 3-pass MFMA, no silu (proven in r13)
  {
    const int in_shift = 10, K = 9 * H, N = D;
    prep_w_bf<<<(D * H + 255) / 256, 256, 0, stream>>>(bw3, sw3, sc3, WhB, WlB, in_shift, D * H);
    for (int r0 = 0; r0 < B; r0 += CB) {
      int cb = (B - r0 < CB) ? (B - r0) : CB;
      expand_bf<<<(cb << in_shift) / 256, 256, 0, stream>>>(
          hbuf + (size_t)r0 * H, XhB, XlB, in_shift, cb << in_shift);
      dim3 grid(N / 128, cb / 128);
      gemm_mfma<false><<<grid, 256, 0, stream>>>(
          XhB, XlB, WhB, WlB, out + (size_t)r0 * D, cb, N, K, D);
    }
  }
}

// Round 16
// 3391.282 us; speedup vs baseline: 1.9618x; 1.0015x over previous
//
#include <hip/hip_runtime.h>
#include <hip/hip_bf16.h>
#include <cstdint>

typedef unsigned short u16;
typedef _Float16 f16;
typedef _Float16 f16x8 __attribute__((ext_vector_type(8)));
typedef short short8 __attribute__((ext_vector_type(8)));
typedef float f32x4 __attribute__((ext_vector_type(4)));

__device__ __forceinline__ float silu_f(float v) {
  return v / (1.0f + expf(-v));
}

// f32 -> bf16 round-to-nearest-even
__device__ __forceinline__ u16 f2bf(float f) {
  union { float f; uint32_t u; } v; v.f = f;
  uint32_t r = v.u + 0x7fffu + ((v.u >> 16) & 1u);
  return (u16)(r >> 16);
}
__device__ __forceinline__ float bf2f(u16 b) {
  union { uint32_t u; float f; } v; v.u = ((uint32_t)b) << 16;
  return v.f;
}
__device__ __forceinline__ void split_bf(float f, u16* hi, u16* lo) {
  u16 h = f2bf(f);
  *hi = h;
  *lo = f2bf(f - bf2f(h));
}
// f16x2 split: hi = f16(x), lo = f16(x - hi).
__device__ __forceinline__ void split_f16(float f, f16* hi, f16* lo) {
  f16 h = (f16)f;
  *hi = h;
  *lo = (f16)(f - (float)h);
}

// B-spline bases, exact Cox-de Boor recursion matching the reference.
__device__ __forceinline__ void bspl(float x, float* b8) {
  float b[11];
#pragma unroll
  for (int j = 0; j < 11; ++j) {
    float g0 = -2.2f + 0.4f * j;
    float g1 = g0 + 0.4f;
    b[j] = (x >= g0 && x < g1) ? 1.0f : 0.0f;
  }
#pragma unroll
  for (int k = 1; k <= 3; ++k) {
    float inv = 1.0f / (0.4f * k);
#pragma unroll
    for (int j = 0; j + k < 11; ++j) {
      float gj = -2.2f + 0.4f * j;
      float l = (x - gj) * inv;
      float r = (gj + 0.4f * (k + 1) - x) * inv;
      b[j] = l * b[j] + r * b[j + 1];
    }
  }
#pragma unroll
  for (int g = 0; g < 8; ++g) b8[g] = b[g];
}

// ---------------- LayerNorm (bitwise = r8-r14) ----------------------------
__global__ __launch_bounds__(256) void ln_kernel(
    const float* __restrict__ z, const float* __restrict__ gamma,
    const float* __restrict__ beta, float* __restrict__ out) {
  const int row = blockIdx.x * 4 + (threadIdx.x >> 6);
  const int lane = threadIdx.x & 63;
  const float4* zr = (const float4*)(z + (size_t)row * 512);
  float4 v0 = zr[lane * 2], v1 = zr[lane * 2 + 1];
  float s = v0.x + v0.y + v0.z + v0.w + v1.x + v1.y + v1.z + v1.w;
  float q = v0.x * v0.x + v0.y * v0.y + v0.z * v0.z + v0.w * v0.w +
            v1.x * v1.x + v1.y * v1.y + v1.z * v1.z + v1.w * v1.w;
#pragma unroll
  for (int o = 32; o > 0; o >>= 1) {
    s += __shfl_down(s, o);
    q += __shfl_down(q, o);
  }
  float mu = __shfl(s, 0) * (1.0f / 512.0f);
  float ex2 = __shfl(q, 0) * (1.0f / 512.0f);
  float rs = rsqrtf(ex2 - mu * mu + 1e-5f);
  const float4* gp = (const float4*)gamma;
  const float4* bp = (const float4*)beta;
  float4 g0 = gp[lane * 2], g1 = gp[lane * 2 + 1];
  float4 b0 = bp[lane * 2], b1 = bp[lane * 2 + 1];
  float4 o0, o1;
  o0.x = (v0.x - mu) * rs * g0.x + b0.x;
  o0.y = (v0.y - mu) * rs * g0.y + b0.y;
  o0.z = (v0.z - mu) * rs * g0.z + b0.z;
  o0.w = (v0.w - mu) * rs * g0.w + b0.w;
  o1.x = (v1.x - mu) * rs * g1.x + b1.x;
  o1.y = (v1.y - mu) * rs * g1.y + b1.y;
  o1.z = (v1.z - mu) * rs * g1.z + b1.z;
  o1.w = (v1.w - mu) * rs * g1.w + b1.w;
  float4* op = (float4*)(out + (size_t)row * 512);
  op[lane * 2] = o0;
  op[lane * 2 + 1] = o1;
}

// ---------------- W_eff prep f32 (L1, bitwise = r11-r14) ------------------
__global__ __launch_bounds__(256) void prep_w_f32(
    const float* __restrict__ bw, const float* __restrict__ sw,
    const float* __restrict__ sc, float* __restrict__ W,
    int in_shift, int total) {
  int idx = blockIdx.x * 256 + threadIdx.x;
  if (idx >= total) return;
  int in = 1 << in_shift;
  int i = idx & (in - 1);
  int o = idx >> in_shift;
  size_t wb = (size_t)o * ((size_t)9 << in_shift) + i;
  float s = sc[idx];
  const float4* swp = (const float4*)(sw + (size_t)idx * 8);
  float4 a = swp[0], b = swp[1];
  W[wb] = bw[idx];
  W[wb + ((size_t)1 << in_shift)] = a.x * s;
  W[wb + ((size_t)2 << in_shift)] = a.y * s;
  W[wb + ((size_t)3 << in_shift)] = a.z * s;
  W[wb + ((size_t)4 << in_shift)] = a.w * s;
  W[wb + ((size_t)5 << in_shift)] = b.x * s;
  W[wb + ((size_t)6 << in_shift)] = b.y * s;
  W[wb + ((size_t)7 << in_shift)] = b.z * s;
  W[wb + ((size_t)8 << in_shift)] = b.w * s;
}

// ---------------- expansion f32 (L1, bitwise = r11-r14) -------------------
__global__ __launch_bounds__(256) void expand_f32(
    const float* __restrict__ x, float* __restrict__ X, int in_shift, int total) {
  int idx = blockIdx.x * 256 + threadIdx.x;
  if (idx >= total) return;
  int in = 1 << in_shift;
  int i = idx & (in - 1);
  int b = idx >> in_shift;
  float v = x[idx];
  size_t base = (size_t)b * ((size_t)9 << in_shift) + i;
  float bs[8];
  bspl(v, bs);
  X[base] = silu_f(v);
#pragma unroll
  for (int g = 0; g < 8; ++g)
    X[base + ((size_t)(g + 1) << in_shift)] = bs[g];
}

// ---------------- W_eff prep f16 hi/lo (L2) -------------------------------
__global__ __launch_bounds__(256) void prep_w_f16(
    const float* __restrict__ bw, const float* __restrict__ sw,
    const float* __restrict__ sc, f16* __restrict__ Wh, f16* __restrict__ Wl,
    int in_shift, int total) {
  int idx = blockIdx.x * 256 + threadIdx.x;
  if (idx >= total) return;
  int in = 1 << in_shift;
  int i = idx & (in - 1);
  int o = idx >> in_shift;
  size_t wb = (size_t)o * ((size_t)9 << in_shift) + i;
  float s = sc[idx];
  const float4* swp = (const float4*)(sw + (size_t)idx * 8);
  float4 a = swp[0], b = swp[1];
  float vals[9] = {bw[idx], a.x * s, a.y * s, a.z * s, a.w * s,
                   b.x * s, b.y * s, b.z * s, b.w * s};
#pragma unroll
  for (int c = 0; c < 9; ++c) {
    f16 h, l;
    split_f16(vals[c], &h, &l);
    Wh[wb + ((size_t)c << in_shift)] = h;
    Wl[wb + ((size_t)c << in_shift)] = l;
  }
}

// ---------------- expansion f16 hi/lo (L2) --------------------------------
__global__ __launch_bounds__(256) void expand_f16(
    const float* __restrict__ x, f16* __restrict__ Xh, f16* __restrict__ Xl,
    int in_shift, int total) {
  int idx = blockIdx.x * 256 + threadIdx.x;
  if (idx >= total) return;
  int in = 1 << in_shift;
  int i = idx & (in - 1);
  int b = idx >> in_shift;
  float v = x[idx];
  size_t base = (size_t)b * ((size_t)9 << in_shift) + i;
  float bs[8];
  bspl(v, bs);
  float vals[9];
  vals[0] = silu_f(v);
#pragma unroll
  for (int g = 0; g < 8; ++g) vals[g + 1] = bs[g];
#pragma unroll
  for (int c = 0; c < 9; ++c) {
    f16 h, l;
    split_f16(vals[c], &h, &l);
    Xh[base + ((size_t)c << in_shift)] = h;
    Xl[base + ((size_t)c << in_shift)] = l;
  }
}

// ---------------- W_eff prep bf16 hi/lo (L3) ------------------------------
__global__ __launch_bounds__(256) void prep_w_bf(
    const float* __restrict__ bw, const float* __restrict__ sw,
    const float* __restrict__ sc, u16* __restrict__ Wh, u16* __restrict__ Wl,
    int in_shift, int total) {
  int idx = blockIdx.x * 256 + threadIdx.x;
  if (idx >= total) return;
  int in = 1 << in_shift;
  int i = idx & (in - 1);
  int o = idx >> in_shift;
  size_t wb = (size_t)o * ((size_t)9 << in_shift) + i;
  float s = sc[idx];
  const float4* swp = (const float4*)(sw + (size_t)idx * 8);
  float4 a = swp[0], b = swp[1];
  float vals[9] = {bw[idx], a.x * s, a.y * s, a.z * s, a.w * s,
                   b.x * s, b.y * s, b.z * s, b.w * s};
#pragma unroll
  for (int c = 0; c < 9; ++c) {
    u16 h, l;
    split_bf(vals[c], &h, &l);
    Wh[wb + ((size_t)c << in_shift)] = h;
    Wl[wb + ((size_t)c << in_shift)] = l;
  }
}

// ---------------- expansion bf16 hi/lo (L3) -------------------------------
__global__ __launch_bounds__(256) void expand_bf(
    const float* __restrict__ x, u16* __restrict__ Xh, u16* __restrict__ Xl,
    int in_shift, int total) {
  int idx = blockIdx.x * 256 + threadIdx.x;
  if (idx >= total) return;
  int in = 1 << in_shift;
  int i = idx & (in - 1);
  int b = idx >> in_shift;
  float v = x[idx];
  size_t base = (size_t)b * ((size_t)9 << in_shift) + i;
  float bs[8];
  bspl(v, bs);
  float vals[9];
  vals[0] = silu_f(v);
#pragma unroll
  for (int g = 0; g < 8; ++g) vals[g + 1] = bs[g];
#pragma unroll
  for (int c = 0; c < 9; ++c) {
    u16 h, l;
    split_bf(vals[c], &h, &l);
    Xh[base + ((size_t)c << in_shift)] = h;
    Xl[base + ((size_t)c << in_shift)] = l;
  }
}

// ---------------- f32 tiled GEMM (L1, bitwise = r11-r14) ------------------
template <bool SILU, int BN>
__global__ __launch_bounds__(256, BN == 64 ? 3 : 2) void gemm_f32(
    const float* __restrict__ A, const float* __restrict__ B,
    float* __restrict__ C, int M, int N, int K, int ldc) {
  constexpr int TN = BN / 16;
  constexpr int BP = BN / 32;
  __shared__ float As[2][32][132];
  __shared__ float Bs[2][32][BN + 4];
  const int tid = threadIdx.x;
  const int bm = blockIdx.y * 128, bn = blockIdx.x * BN;
  const int tx = tid & 15, ty = tid >> 4;
  const int sr = tid >> 3;
  const int sk = (tid & 7) * 4;
  const float* gA = A + (size_t)(bm + sr) * K + sk;
  const float* gB = B + (size_t)(bn + sr) * K + sk;
  float acc[8][TN] = {};
  float acc_t[8][TN] = {};
  float4 av[4], bv[BP];
  const int NT = K >> 5;
#pragma unroll
  for (int p = 0; p < 4; ++p)
    av[p] = *(const float4*)(gA + (size_t)p * 32 * K);
#pragma unroll
  for (int p = 0; p < BP; ++p)
    bv[p] = *(const float4*)(gB + (size_t)p * 32 * K);
#pragma unroll
  for (int p = 0; p < 4; ++p) {
    int m = p * 32 + sr;
    As[0][sk + 0][m] = av[p].x; As[0][sk + 1][m] = av[p].y;
    As[0][sk + 2][m] = av[p].z; As[0][sk + 3][m] = av[p].w;
  }
#pragma unroll
  for (int p = 0; p < BP; ++p) {
    int m = p * 32 + sr;
    Bs[0][sk + 0][m] = bv[p].x; Bs[0][sk + 1][m] = bv[p].y;
    Bs[0][sk + 2][m] = bv[p].z; Bs[0][sk + 3][m] = bv[p].w;
  }
  __syncthreads();
  for (int t = 0; t < NT; ++t) {
    const int cur = t & 1;
    if (t + 1 < NT) {
      const int k0 = (t + 1) << 5;
#pragma unroll
      for (int p = 0; p < 4; ++p)
        av[p] = *(const float4*)(gA + (size_t)p * 32 * K + k0);
#pragma unroll
      for (int p = 0; p < BP; ++p)
        bv[p] = *(const float4*)(gB + (size_t)p * 32 * K + k0);
    }
#pragma unroll 4
    for (int kk = 0; kk < 32; ++kk) {
      float4 a0 = *(const float4*)&As[cur][kk][ty * 8];
      float4 a1 = *(const float4*)&As[cur][kk][ty * 8 + 4];
      float a[8] = {a0.x, a0.y, a0.z, a0.w, a1.x, a1.y, a1.z, a1.w};
      float b[TN];
#pragma unroll
      for (int q = 0; q < TN; q += 4) {
        float4 bq = *(const float4*)&Bs[cur][kk][tx * TN + q];
        b[q] = bq.x; b[q + 1] = bq.y; b[q + 2] = bq.z; b[q + 3] = bq.w;
      }
#pragma unroll
      for (int j = 0; j < 8; ++j)
#pragma unroll
        for (int l = 0; l < TN; ++l)
          acc[j][l] += a[j] * b[l];
    }
#pragma unroll
    for (int j = 0; j < 8; ++j)
#pragma unroll
      for (int l = 0; l < TN; ++l) {
        acc_t[j][l] += acc[j][l];
        acc[j][l] = 0.0f;
      }
    if (t + 1 < NT) {
      const int nxt = cur ^ 1;
#pragma unroll
      for (int p = 0; p < 4; ++p) {
        int m = p * 32 + sr;
        As[nxt][sk + 0][m] = av[p].x; As[nxt][sk + 1][m] = av[p].y;
        As[nxt][sk + 2][m] = av[p].z; As[nxt][sk + 3][m] = av[p].w;
      }
#pragma unroll
      for (int p = 0; p < BP; ++p) {
        int m = p * 32 + sr;
        Bs[nxt][sk + 0][m] = bv[p].x; Bs[nxt][sk + 1][m] = bv[p].y;
        Bs[nxt][sk + 2][m] = bv[p].z; Bs[nxt][sk + 3][m] = bv[p].w;
      }
      __syncthreads();
    }
  }
#pragma unroll
  for (int j = 0; j < 8; ++j) {
    int r = bm + ty * 8 + j;
    float* cp = C + (size_t)r * ldc + bn + tx * TN;
#pragma unroll
    for (int q = 0; q < TN; q += 4) {
      float4 o;
      o.x = acc_t[j][q]; o.y = acc_t[j][q + 1];
      o.z = acc_t[j][q + 2]; o.w = acc_t[j][q + 3];
      if (SILU) {
        o.x = silu_f(o.x); o.y = silu_f(o.y);
        o.z = silu_f(o.z); o.w = silu_f(o.w);
      }
      *(float4*)(cp + q) = o;
    }
  }
}

// ---------------- MFMA GEMM skeletons (m97 structure) ---------------------
__device__ __forceinline__ void gload_lds16(const void* g, void* l) {
  __builtin_amdgcn_global_load_lds(
      (const __attribute__((address_space(1))) void*)g,
      (__attribute__((address_space(3))) void*)l, 16, 0, 0);
}

// bf16 variant (L3) — bitwise = r13/r14
template <bool SILU>
__global__ __launch_bounds__(256) void gemm_mfma_bf(
    const u16* __restrict__ Ah, const u16* __restrict__ Al,
    const u16* __restrict__ Wh, const u16* __restrict__ Wl,
    float* __restrict__ C, int M, int N, int K, int ldc) {
  __shared__ __align__(16) u16 lsA[128 * 64];
  __shared__ __align__(16) u16 lsB[128 * 64];
  const int tid = threadIdx.x;
  const int wave = tid >> 6, lane = tid & 63;
  const int bm = blockIdx.y * 128, bn = blockIdx.x * 128;
  const int srow = wave * 8 + (lane >> 3);
  const int scol = (lane & 7) * 8;
  u16* lA = &lsA[wave * 512 + lane * 8];
  u16* lB = &lsB[wave * 512 + lane * 8];
  const int wm = wave >> 1, wn = wave & 1;
  const int fr = lane & 15, kg = lane >> 4;
  const u16* rA = &lsA[(wm * 64 + fr) * 64 + kg * 8];
  const u16* rB = &lsB[(wn * 64 + fr) * 64 + kg * 8];
  f32x4 acc[4][4] = {};
#pragma unroll
  for (int ph = 0; ph < 3; ++ph) {
    const u16* Ap = (ph == 1) ? Al : Ah;
    const u16* Bp = (ph == 2) ? Wl : Wh;
    const u16* gA = Ap + (size_t)(bm + srow) * K + scol;
    const u16* gB = Bp + (size_t)(bn + srow) * K + scol;
    for (int k0 = 0; k0 < K; k0 += 64) {
#pragma unroll
      for (int s = 0; s < 4; ++s) {
        gload_lds16(gA + (size_t)s * 32 * K + k0, lA + s * 2048);
        gload_lds16(gB + (size_t)s * 32 * K + k0, lB + s * 2048);
      }
      __syncthreads();
#pragma unroll
      for (int kc = 0; kc < 2; ++kc) {
        short8 af[4], bv[4];
#pragma unroll
        for (int m = 0; m < 4; ++m)
          af[m] = *(const short8*)(rA + m * 16 * 64 + kc * 32);
#pragma unroll
        for (int n = 0; n < 4; ++n)
          bv[n] = *(const short8*)(rB + n * 16 * 64 + kc * 32);
#pragma unroll
        for (int m = 0; m < 4; ++m)
#pragma unroll
          for (int n = 0; n < 4; ++n)
            acc[m][n] = __builtin_amdgcn_mfma_f32_16x16x32_bf16(
                af[m], bv[n], acc[m][n], 0, 0, 0);
      }
      __syncthreads();
    }
  }
#pragma unroll
  for (int m = 0; m < 4; ++m) {
#pragma unroll
    for (int n = 0; n < 4; ++n) {
#pragma unroll
      for (int v = 0; v < 4; ++v) {
        int r = bm + wm * 64 + m * 16 + kg * 4 + v;
        int c = bn + wn * 64 + n * 16 + fr;
        float val = acc[m][n][v];
        if (SILU) val = silu_f(val);
        C[(size_t)r * ldc + c] = val;
      }
    }
  }
}

// f16 variant (L2) — same skeleton, f16 frags + f16 MFMA (ran in r15)
template <bool SILU>
__global__ __launch_bounds__(256) void gemm_mfma_f16(
    const f16* __restrict__ Ah, const f16* __restrict__ Al,
    const f16* __restrict__ Wh, const f16* __restrict__ Wl,
    float* __restrict__ C, int M, int N, int K, int ldc) {
  __shared__ __align__(16) f16 lsA[128 * 64];
  __shared__ __align__(16) f16 lsB[128 * 64];
  const int tid = threadIdx.x;
  const int wave = tid >> 6, lane = tid & 63;
  const int bm = blockIdx.y * 128, bn = blockIdx.x * 128;
  const int srow = wave * 8 + (lane >> 3);
  const int scol = (lane & 7) * 8;
  f16* lA = &lsA[wave * 512 + lane * 8];
  f16* lB = &lsB[wave * 512 + lane * 8];
  const int wm = wave >> 1, wn = wave & 1;
  const int fr = lane & 15, kg = lane >> 4;
  const f16* rA = &lsA[(wm * 64 + fr) * 64 + kg * 8];
  const f16* rB = &lsB[(wn * 64 + fr) * 64 + kg * 8];
  f32x4 acc[4][4] = {};
#pragma unroll
  for (int ph = 0; ph < 3; ++ph) {
    const f16* Ap = (ph == 1) ? Al : Ah;
    const f16* Bp = (ph == 2) ? Wl : Wh;
    const f16* gA = Ap + (size_t)(bm + srow) * K + scol;
    const f16* gB = Bp + (size_t)(bn + srow) * K + scol;
    for (int k0 = 0; k0 < K; k0 += 64) {
#pragma unroll
      for (int s = 0; s < 4; ++s) {
        gload_lds16(gA + (size_t)s * 32 * K + k0, lA + s * 2048);
        gload_lds16(gB + (size_t)s * 32 * K + k0, lB + s * 2048);
      }
      __syncthreads();
#pragma unroll
      for (int kc = 0; kc < 2; ++kc) {
        f16x8 af[4], bv[4];
#pragma unroll
        for (int m = 0; m < 4; ++m)
          af[m] = *(const f16x8*)(rA + m * 16 * 64 + kc * 32);
#pragma unroll
        for (int n = 0; n < 4; ++n)
          bv[n] = *(const f16x8*)(rB + n * 16 * 64 + kc * 32);
#pragma unroll
        for (int m = 0; m < 4; ++m)
#pragma unroll
          for (int n = 0; n < 4; ++n)
            acc[m][n] = __builtin_amdgcn_mfma_f32_16x16x32_f16(
                af[m], bv[n], acc[m][n], 0, 0, 0);
      }
      __syncthreads();
    }
  }
#pragma unroll
  for (int m = 0; m < 4; ++m) {
#pragma unroll
    for (int n = 0; n < 4; ++n) {
#pragma unroll
      for (int v = 0; v < 4; ++v) {
        int r = bm + wm * 64 + m * 16 + kg * 4 + v;
        int c = bn + wn * 64 + n * 16 + fr;
        float val = acc[m][n][v];
        if (SILU) val = silu_f(val);
        C[(size_t)r * ldc + c] = val;
      }
    }
  }
}

extern "C" void kernel_launch(void* const* d_in, const int* in_sizes, int n_in,
                              void* d_out, int out_size, void* d_ws, size_t ws_size,
                              hipStream_t stream) {
  const float* z   = (const float*)d_in[1];
  const float* lng = (const float*)d_in[2];
  const float* lnb = (const float*)d_in[3];
  const float* bw1 = (const float*)d_in[5];
  const float* sw1 = (const float*)d_in[6];
  const float* sc1 = (const float*)d_in[7];
  const float* bw2 = (const float*)d_in[9];
  const float* sw2 = (const float*)d_in[10];
  const float* sc2 = (const float*)d_in[11];
  const float* bw3 = (const float*)d_in[13];
  const float* sw3 = (const float*)d_in[14];
  const float* sc3 = (const float*)d_in[15];
  float* out = (float*)d_out;

  const int B = 8192, D = 512, H = 1024;
  char* ws = (char*)d_ws;
  size_t off = 0;
  float* ln_out = (float*)(ws + off); off += (size_t)B * D * 4;
  float* hbuf   = (float*)(ws + off); off += (size_t)B * H * 4;  // activated h
  char* Wregion = ws + off;           off += (size_t)H * 9216 * 4;
  size_t rem = ws_size > off ? ws_size - off : 0;
  int CB = 128;
  {
    const int cands[6] = {8192, 4096, 2048, 1024, 512, 256};
    for (int c = 0; c < 6; ++c) {
      if ((size_t)cands[c] * 9216 * 4 <= rem) { CB = cands[c]; break; }
    }
  }
  char* Xregion = ws + off;
  // typed overlays (stream-ordered reuse across layers)
  float* WF = (float*)Wregion;
  float* XF = (float*)Xregion;
  f16* WhF = (f16*)Wregion;
  f16* WlF = WhF + (size_t)H * 9216;
  f16* XhF = (f16*)Xregion;
  f16* XlF = XhF + (size_t)CB * 9216;
  u16* WhB = (u16*)Wregion;
  u16* WlB = WhB + (size_t)H * 9216;
  u16* XhB = (u16*)Xregion;
  u16* XlB = XhB + (size_t)CB * 9216;

  ln_kernel<<<B / 4, 256, 0, stream>>>(z, lng, lnb, ln_out);

  // ---- layer 1: f32 VALU GEMM (bitwise = r11-r14; 82% of f32 peak)
  {
    const int in_shift = 9, K = 9 * D, N = H;
    prep_w_f32<<<(H * D + 255) / 256, 256, 0, stream>>>(bw1, sw1, sc1, WF, in_shift, H * D);
    for (int r0 = 0; r0 < B; r0 += CB) {
      int cb = (B - r0 < CB) ? (B - r0) : CB;
      expand_f32<<<(cb << in_shift) / 256, 256, 0, stream>>>(
          ln_out + (size_t)r0 * D, XF, in_shift, cb << in_shift);
      dim3 grid(N / 128, cb / 128);
      gemm_f32<true, 128><<<grid, 256, 0, stream>>>(XF, WF, hbuf + (size_t)r0 * H, cb, N, K, H);
    }
  }
  // ---- layer 2: f16x2 3-pass MFMA, silu epilogue (THIS round's change)
  {
    const int in_shift = 10, K = 9 * H, N = H;
    prep_w_f16<<<(H * H + 255) / 256, 256, 0, stream>>>(bw2, sw2, sc2, WhF, WlF, in_shift, H * H);
    for (int r0 = 0; r0 < B; r0 += CB) {
      int cb = (B - r0 < CB) ? (B - r0) : CB;
      expand_f16<<<(cb << in_shift) / 256, 256, 0, stream>>>(
          hbuf + (size_t)r0 * H, XhF, XlF, in_shift, cb << in_shift);
      dim3 grid(N / 128, cb / 128);
      gemm_mfma_f16<true><<<grid, 256, 0, stream>>>(
          XhF, XlF, WhF, WlF, hbuf + (size_t)r0 * H, cb, N, K, H);
    }
  }
  // ---- layer 3: bf16x2 3-pass MFMA, no silu (bitwise = r13/r14)
  {
    const int in_shift = 10, K = 9 * H, N = D;
    prep_w_bf<<<(D * H + 255) / 256, 256, 0, stream>>>(bw3, sw3, sc3, WhB, WlB, in_shift, D * H);
    for (int r0 = 0; r0 < B; r0 += CB) {
      int cb = (B - r0 < CB) ? (B - r0) : CB;
      expand_bf<<<(cb << in_shift) / 256, 256, 0, stream>>>(
          hbuf + (size_t)r0 * H, XhB, XlB, in_shift, cb << in_shift);
      dim3 grid(N / 128, cb / 128);
      gemm_mfma_bf<false><<<grid, 256, 0, stream>>>(
          XhB, XlB, WhB, WlB, out + (size_t)r0 * D, cb, N, K, D);
    }
  }
}

// Round 17
// 2419.133 us; speedup vs baseline: 2.7502x; 1.4019x over previous
//
#include <hip/hip_runtime.h>
#include <hip/hip_bf16.h>
#include <cstdint>

typedef unsigned short u16;
typedef _Float16 f16;
typedef _Float16 f16x8 __attribute__((ext_vector_type(8)));
typedef short short8 __attribute__((ext_vector_type(8)));
typedef float f32x4 __attribute__((ext_vector_type(4)));

__device__ __forceinline__ float silu_f(float v) {
  return v / (1.0f + expf(-v));
}

// f32 -> bf16 round-to-nearest-even
__device__ __forceinline__ u16 f2bf(float f) {
  union { float f; uint32_t u; } v; v.f = f;
  uint32_t r = v.u + 0x7fffu + ((v.u >> 16) & 1u);
  return (u16)(r >> 16);
}
__device__ __forceinline__ float bf2f(u16 b) {
  union { uint32_t u; float f; } v; v.u = ((uint32_t)b) << 16;
  return v.f;
}
__device__ __forceinline__ void split_bf(float f, u16* hi, u16* lo) {
  u16 h = f2bf(f);
  *hi = h;
  *lo = f2bf(f - bf2f(h));
}
// f16x2 split: hi = f16(x), lo = f16(x - hi).
__device__ __forceinline__ void split_f16(float f, f16* hi, f16* lo) {
  f16 h = (f16)f;
  *hi = h;
  *lo = (f16)(f - (float)h);
}

// B-spline bases, exact Cox-de Boor recursion matching the reference.
__device__ __forceinline__ void bspl(float x, float* b8) {
  float b[11];
#pragma unroll
  for (int j = 0; j < 11; ++j) {
    float g0 = -2.2f + 0.4f * j;
    float g1 = g0 + 0.4f;
    b[j] = (x >= g0 && x < g1) ? 1.0f : 0.0f;
  }
#pragma unroll
  for (int k = 1; k <= 3; ++k) {
    float inv = 1.0f / (0.4f * k);
#pragma unroll
    for (int j = 0; j + k < 11; ++j) {
      float gj = -2.2f + 0.4f * j;
      float l = (x - gj) * inv;
      float r = (gj + 0.4f * (k + 1) - x) * inv;
      b[j] = l * b[j] + r * b[j + 1];
    }
  }
#pragma unroll
  for (int g = 0; g < 8; ++g) b8[g] = b[g];
}

// ---------------- LayerNorm (bitwise = r8-r16) ----------------------------
__global__ __launch_bounds__(256) void ln_kernel(
    const float* __restrict__ z, const float* __restrict__ gamma,
    const float* __restrict__ beta, float* __restrict__ out) {
  const int row = blockIdx.x * 4 + (threadIdx.x >> 6);
  const int lane = threadIdx.x & 63;
  const float4* zr = (const float4*)(z + (size_t)row * 512);
  float4 v0 = zr[lane * 2], v1 = zr[lane * 2 + 1];
  float s = v0.x + v0.y + v0.z + v0.w + v1.x + v1.y + v1.z + v1.w;
  float q = v0.x * v0.x + v0.y * v0.y + v0.z * v0.z + v0.w * v0.w +
            v1.x * v1.x + v1.y * v1.y + v1.z * v1.z + v1.w * v1.w;
#pragma unroll
  for (int o = 32; o > 0; o >>= 1) {
    s += __shfl_down(s, o);
    q += __shfl_down(q, o);
  }
  float mu = __shfl(s, 0) * (1.0f / 512.0f);
  float ex2 = __shfl(q, 0) * (1.0f / 512.0f);
  float rs = rsqrtf(ex2 - mu * mu + 1e-5f);
  const float4* gp = (const float4*)gamma;
  const float4* bp = (const float4*)beta;
  float4 g0 = gp[lane * 2], g1 = gp[lane * 2 + 1];
  float4 b0 = bp[lane * 2], b1 = bp[lane * 2 + 1];
  float4 o0, o1;
  o0.x = (v0.x - mu) * rs * g0.x + b0.x;
  o0.y = (v0.y - mu) * rs * g0.y + b0.y;
  o0.z = (v0.z - mu) * rs * g0.z + b0.z;
  o0.w = (v0.w - mu) * rs * g0.w + b0.w;
  o1.x = (v1.x - mu) * rs * g1.x + b1.x;
  o1.y = (v1.y - mu) * rs * g1.y + b1.y;
  o1.z = (v1.z - mu) * rs * g1.z + b1.z;
  o1.w = (v1.w - mu) * rs * g1.w + b1.w;
  float4* op = (float4*)(out + (size_t)row * 512);
  op[lane * 2] = o0;
  op[lane * 2 + 1] = o1;
}

// ---------------- W_eff prep f32 (L1, bitwise) -----------------------------
__global__ __launch_bounds__(256) void prep_w_f32(
    const float* __restrict__ bw, const float* __restrict__ sw,
    const float* __restrict__ sc, float* __restrict__ W,
    int in_shift, int total) {
  int idx = blockIdx.x * 256 + threadIdx.x;
  if (idx >= total) return;
  int in = 1 << in_shift;
  int i = idx & (in - 1);
  int o = idx >> in_shift;
  size_t wb = (size_t)o * ((size_t)9 << in_shift) + i;
  float s = sc[idx];
  const float4* swp = (const float4*)(sw + (size_t)idx * 8);
  float4 a = swp[0], b = swp[1];
  W[wb] = bw[idx];
  W[wb + ((size_t)1 << in_shift)] = a.x * s;
  W[wb + ((size_t)2 << in_shift)] = a.y * s;
  W[wb + ((size_t)3 << in_shift)] = a.z * s;
  W[wb + ((size_t)4 << in_shift)] = a.w * s;
  W[wb + ((size_t)5 << in_shift)] = b.x * s;
  W[wb + ((size_t)6 << in_shift)] = b.y * s;
  W[wb + ((size_t)7 << in_shift)] = b.z * s;
  W[wb + ((size_t)8 << in_shift)] = b.w * s;
}

// ---------------- expansion f32 (L1, bitwise) ------------------------------
__global__ __launch_bounds__(256) void expand_f32(
    const float* __restrict__ x, float* __restrict__ X, int in_shift, int total) {
  int idx = blockIdx.x * 256 + threadIdx.x;
  if (idx >= total) return;
  int in = 1 << in_shift;
  int i = idx & (in - 1);
  int b = idx >> in_shift;
  float v = x[idx];
  size_t base = (size_t)b * ((size_t)9 << in_shift) + i;
  float bs[8];
  bspl(v, bs);
  X[base] = silu_f(v);
#pragma unroll
  for (int g = 0; g < 8; ++g)
    X[base + ((size_t)(g + 1) << in_shift)] = bs[g];
}

// ---------------- W_eff prep f16 hi/lo (L2) -------------------------------
__global__ __launch_bounds__(256) void prep_w_f16(
    const float* __restrict__ bw, const float* __restrict__ sw,
    const float* __restrict__ sc, f16* __restrict__ Wh, f16* __restrict__ Wl,
    int in_shift, int total) {
  int idx = blockIdx.x * 256 + threadIdx.x;
  if (idx >= total) return;
  int in = 1 << in_shift;
  int i = idx & (in - 1);
  int o = idx >> in_shift;
  size_t wb = (size_t)o * ((size_t)9 << in_shift) + i;
  float s = sc[idx];
  const float4* swp = (const float4*)(sw + (size_t)idx * 8);
  float4 a = swp[0], b = swp[1];
  float vals[9] = {bw[idx], a.x * s, a.y * s, a.z * s, a.w * s,
                   b.x * s, b.y * s, b.z * s, b.w * s};
#pragma unroll
  for (int c = 0; c < 9; ++c) {
    f16 h, l;
    split_f16(vals[c], &h, &l);
    Wh[wb + ((size_t)c << in_shift)] = h;
    Wl[wb + ((size_t)c << in_shift)] = l;
  }
}

// ---------------- expansion f16 hi/lo (L2) --------------------------------
__global__ __launch_bounds__(256) void expand_f16(
    const float* __restrict__ x, f16* __restrict__ Xh, f16* __restrict__ Xl,
    int in_shift, int total) {
  int idx = blockIdx.x * 256 + threadIdx.x;
  if (idx >= total) return;
  int in = 1 << in_shift;
  int i = idx & (in - 1);
  int b = idx >> in_shift;
  float v = x[idx];
  size_t base = (size_t)b * ((size_t)9 << in_shift) + i;
  float bs[8];
  bspl(v, bs);
  float vals[9];
  vals[0] = silu_f(v);
#pragma unroll
  for (int g = 0; g < 8; ++g) vals[g + 1] = bs[g];
#pragma unroll
  for (int c = 0; c < 9; ++c) {
    f16 h, l;
    split_f16(vals[c], &h, &l);
    Xh[base + ((size_t)c << in_shift)] = h;
    Xl[base + ((size_t)c << in_shift)] = l;
  }
}

// ---------------- W_eff prep bf16 hi/lo (L3) ------------------------------
__global__ __launch_bounds__(256) void prep_w_bf(
    const float* __restrict__ bw, const float* __restrict__ sw,
    const float* __restrict__ sc, u16* __restrict__ Wh, u16* __restrict__ Wl,
    int in_shift, int total) {
  int idx = blockIdx.x * 256 + threadIdx.x;
  if (idx >= total) return;
  int in = 1 << in_shift;
  int i = idx & (in - 1);
  int o = idx >> in_shift;
  size_t wb = (size_t)o * ((size_t)9 << in_shift) + i;
  float s = sc[idx];
  const float4* swp = (const float4*)(sw + (size_t)idx * 8);
  float4 a = swp[0], b = swp[1];
  float vals[9] = {bw[idx], a.x * s, a.y * s, a.z * s, a.w * s,
                   b.x * s, b.y * s, b.z * s, b.w * s};
#pragma unroll
  for (int c = 0; c < 9; ++c) {
    u16 h, l;
    split_bf(vals[c], &h, &l);
    Wh[wb + ((size_t)c << in_shift)] = h;
    Wl[wb + ((size_t)c << in_shift)] = l;
  }
}

// ---------------- expansion bf16 hi/lo (L3) -------------------------------
__global__ __launch_bounds__(256) void expand_bf(
    const float* __restrict__ x, u16* __restrict__ Xh, u16* __restrict__ Xl,
    int in_shift, int total) {
  int idx = blockIdx.x * 256 + threadIdx.x;
  if (idx >= total) return;
  int in = 1 << in_shift;
  int i = idx & (in - 1);
  int b = idx >> in_shift;
  float v = x[idx];
  size_t base = (size_t)b * ((size_t)9 << in_shift) + i;
  float bs[8];
  bspl(v, bs);
  float vals[9];
  vals[0] = silu_f(v);
#pragma unroll
  for (int g = 0; g < 8; ++g) vals[g + 1] = bs[g];
#pragma unroll
  for (int c = 0; c < 9; ++c) {
    u16 h, l;
    split_bf(vals[c], &h, &l);
    Xh[base + ((size_t)c << in_shift)] = h;
    Xl[base + ((size_t)c << in_shift)] = l;
  }
}

// ---------------- f32 tiled GEMM (L1, bitwise = r11-r16) ------------------
template <bool SILU, int BN>
__global__ __launch_bounds__(256, BN == 64 ? 3 : 2) void gemm_f32(
    const float* __restrict__ A, const float* __restrict__ B,
    float* __restrict__ C, int M, int N, int K, int ldc) {
  constexpr int TN = BN / 16;
  constexpr int BP = BN / 32;
  __shared__ float As[2][32][132];
  __shared__ float Bs[2][32][BN + 4];
  const int tid = threadIdx.x;
  const int bm = blockIdx.y * 128, bn = blockIdx.x * BN;
  const int tx = tid & 15, ty = tid >> 4;
  const int sr = tid >> 3;
  const int sk = (tid & 7) * 4;
  const float* gA = A + (size_t)(bm + sr) * K + sk;
  const float* gB = B + (size_t)(bn + sr) * K + sk;
  float acc[8][TN] = {};
  float acc_t[8][TN] = {};
  float4 av[4], bv[BP];
  const int NT = K >> 5;
#pragma unroll
  for (int p = 0; p < 4; ++p)
    av[p] = *(const float4*)(gA + (size_t)p * 32 * K);
#pragma unroll
  for (int p = 0; p < BP; ++p)
    bv[p] = *(const float4*)(gB + (size_t)p * 32 * K);
#pragma unroll
  for (int p = 0; p < 4; ++p) {
    int m = p * 32 + sr;
    As[0][sk + 0][m] = av[p].x; As[0][sk + 1][m] = av[p].y;
    As[0][sk + 2][m] = av[p].z; As[0][sk + 3][m] = av[p].w;
  }
#pragma unroll
  for (int p = 0; p < BP; ++p) {
    int m = p * 32 + sr;
    Bs[0][sk + 0][m] = bv[p].x; Bs[0][sk + 1][m] = bv[p].y;
    Bs[0][sk + 2][m] = bv[p].z; Bs[0][sk + 3][m] = bv[p].w;
  }
  __syncthreads();
  for (int t = 0; t < NT; ++t) {
    const int cur = t & 1;
    if (t + 1 < NT) {
      const int k0 = (t + 1) << 5;
#pragma unroll
      for (int p = 0; p < 4; ++p)
        av[p] = *(const float4*)(gA + (size_t)p * 32 * K + k0);
#pragma unroll
      for (int p = 0; p < BP; ++p)
        bv[p] = *(const float4*)(gB + (size_t)p * 32 * K + k0);
    }
#pragma unroll 4
    for (int kk = 0; kk < 32; ++kk) {
      float4 a0 = *(const float4*)&As[cur][kk][ty * 8];
      float4 a1 = *(const float4*)&As[cur][kk][ty * 8 + 4];
      float a[8] = {a0.x, a0.y, a0.z, a0.w, a1.x, a1.y, a1.z, a1.w};
      float b[TN];
#pragma unroll
      for (int q = 0; q < TN; q += 4) {
        float4 bq = *(const float4*)&Bs[cur][kk][tx * TN + q];
        b[q] = bq.x; b[q + 1] = bq.y; b[q + 2] = bq.z; b[q + 3] = bq.w;
      }
#pragma unroll
      for (int j = 0; j < 8; ++j)
#pragma unroll
        for (int l = 0; l < TN; ++l)
          acc[j][l] += a[j] * b[l];
    }
#pragma unroll
    for (int j = 0; j < 8; ++j)
#pragma unroll
      for (int l = 0; l < TN; ++l) {
        acc_t[j][l] += acc[j][l];
        acc[j][l] = 0.0f;
      }
    if (t + 1 < NT) {
      const int nxt = cur ^ 1;
#pragma unroll
      for (int p = 0; p < 4; ++p) {
        int m = p * 32 + sr;
        As[nxt][sk + 0][m] = av[p].x; As[nxt][sk + 1][m] = av[p].y;
        As[nxt][sk + 2][m] = av[p].z; As[nxt][sk + 3][m] = av[p].w;
      }
#pragma unroll
      for (int p = 0; p < BP; ++p) {
        int m = p * 32 + sr;
        Bs[nxt][sk + 0][m] = bv[p].x; Bs[nxt][sk + 1][m] = bv[p].y;
        Bs[nxt][sk + 2][m] = bv[p].z; Bs[nxt][sk + 3][m] = bv[p].w;
      }
      __syncthreads();
    }
  }
#pragma unroll
  for (int j = 0; j < 8; ++j) {
    int r = bm + ty * 8 + j;
    float* cp = C + (size_t)r * ldc + bn + tx * TN;
#pragma unroll
    for (int q = 0; q < TN; q += 4) {
      float4 o;
      o.x = acc_t[j][q]; o.y = acc_t[j][q + 1];
      o.z = acc_t[j][q + 2]; o.w = acc_t[j][q + 3];
      if (SILU) {
        o.x = silu_f(o.x); o.y = silu_f(o.y);
        o.z = silu_f(o.z); o.w = silu_f(o.w);
      }
      *(float4*)(cp + q) = o;
    }
  }
}

// ---------------- FUSED 3-product dbuf MFMA GEMM (this round) -------------
// BK=32; per k-step stage Ah,Al,Wh,Wl (next tile) BEFORE computing current,
// then 3 MFMA products per fragment pair: AhWh + AlWh + AhWl. One barrier
// per k-step (was 2 per step x 3 passes). Same product terms, reordered.
__device__ __forceinline__ void gload_lds16(const void* g, void* l) {
  __builtin_amdgcn_global_load_lds(
      (const __attribute__((address_space(1))) void*)g,
      (__attribute__((address_space(3))) void*)l, 16, 0, 0);
}

// f16 variant, BN=128 (L2)
template <bool SILU>
__global__ __launch_bounds__(256) void gemm_fused_f16(
    const f16* __restrict__ Ah, const f16* __restrict__ Al,
    const f16* __restrict__ Wh, const f16* __restrict__ Wl,
    float* __restrict__ C, int M, int N, int K, int ldc) {
  __shared__ __align__(16) f16 sAh[2][128 * 32];
  __shared__ __align__(16) f16 sAl[2][128 * 32];
  __shared__ __align__(16) f16 sWh[2][128 * 32];
  __shared__ __align__(16) f16 sWl[2][128 * 32];
  const int tid = threadIdx.x, wave = tid >> 6, lane = tid & 63;
  const int bm = blockIdx.y * 128, bn = blockIdx.x * 128;
  const int rsub = lane >> 2;          // 0..15
  const int csub = (lane & 3) * 8;     // 0,8,16,24
  const int wm = wave >> 1, wn = wave & 1;
  const int fr = lane & 15, kg = lane >> 4;
  f32x4 acc[4][4] = {};
  const int NT = K >> 5;

  auto stage = [&](int buf, int k0) {
#pragma unroll
    for (int s = 0; s < 2; ++s) {
      const int rb = (s * 4 + wave) * 16;       // row base (16 rows/instr)
      const int doff = rb * 32 + lane * 8;      // contiguous 1024B per wave
      gload_lds16(Ah + (size_t)(bm + rb + rsub) * K + k0 + csub, &sAh[buf][doff]);
      gload_lds16(Al + (size_t)(bm + rb + rsub) * K + k0 + csub, &sAl[buf][doff]);
      gload_lds16(Wh + (size_t)(bn + rb + rsub) * K + k0 + csub, &sWh[buf][doff]);
      gload_lds16(Wl + (size_t)(bn + rb + rsub) * K + k0 + csub, &sWl[buf][doff]);
    }
  };

  stage(0, 0);
  __syncthreads();
  int cur = 0;
  for (int t = 0; t < NT; ++t) {
    if (t + 1 < NT) stage(cur ^ 1, (t + 1) << 5);
    f16x8 ah[4], al[4], wh[4], wl[4];
#pragma unroll
    for (int m = 0; m < 4; ++m) {
      int off = (wm * 64 + m * 16 + fr) * 32 + kg * 8;
      ah[m] = *(const f16x8*)&sAh[cur][off];
      al[m] = *(const f16x8*)&sAl[cur][off];
    }
#pragma unroll
    for (int n = 0; n < 4; ++n) {
      int off = (wn * 64 + n * 16 + fr) * 32 + kg * 8;
      wh[n] = *(const f16x8*)&sWh[cur][off];
      wl[n] = *(const f16x8*)&sWl[cur][off];
    }
#pragma unroll
    for (int m = 0; m < 4; ++m)
#pragma unroll
      for (int n = 0; n < 4; ++n) {
        acc[m][n] = __builtin_amdgcn_mfma_f32_16x16x32_f16(ah[m], wh[n], acc[m][n], 0, 0, 0);
        acc[m][n] = __builtin_amdgcn_mfma_f32_16x16x32_f16(al[m], wh[n], acc[m][n], 0, 0, 0);
        acc[m][n] = __builtin_amdgcn_mfma_f32_16x16x32_f16(ah[m], wl[n], acc[m][n], 0, 0, 0);
      }
    __syncthreads();
    cur ^= 1;
  }
#pragma unroll
  for (int m = 0; m < 4; ++m) {
#pragma unroll
    for (int n = 0; n < 4; ++n) {
#pragma unroll
      for (int v = 0; v < 4; ++v) {
        int r = bm + wm * 64 + m * 16 + kg * 4 + v;
        int c = bn + wn * 64 + n * 16 + fr;
        float val = acc[m][n][v];
        if (SILU) val = silu_f(val);
        C[(size_t)r * ldc + c] = val;
      }
    }
  }
}

// bf16 variant, BN=64 (L3; grid 512 blocks for occupancy)
template <bool SILU>
__global__ __launch_bounds__(256) void gemm_fused_bf64(
    const u16* __restrict__ Ah, const u16* __restrict__ Al,
    const u16* __restrict__ Wh, const u16* __restrict__ Wl,
    float* __restrict__ C, int M, int N, int K, int ldc) {
  __shared__ __align__(16) u16 sAh[2][128 * 32];
  __shared__ __align__(16) u16 sAl[2][128 * 32];
  __shared__ __align__(16) u16 sWh[2][64 * 32];
  __shared__ __align__(16) u16 sWl[2][64 * 32];
  const int tid = threadIdx.x, wave = tid >> 6, lane = tid & 63;
  const int bm = blockIdx.y * 128, bn = blockIdx.x * 64;
  const int rsub = lane >> 2;
  const int csub = (lane & 3) * 8;
  const int wm = wave >> 1, wn = wave & 1;
  const int fr = lane & 15, kg = lane >> 4;
  f32x4 acc[4][2] = {};
  const int NT = K >> 5;

  auto stage = [&](int buf, int k0) {
#pragma unroll
    for (int s = 0; s < 2; ++s) {
      const int rb = (s * 4 + wave) * 16;
      const int doff = rb * 32 + lane * 8;
      gload_lds16(Ah + (size_t)(bm + rb + rsub) * K + k0 + csub, &sAh[buf][doff]);
      gload_lds16(Al + (size_t)(bm + rb + rsub) * K + k0 + csub, &sAl[buf][doff]);
    }
    {
      const int rb = wave * 16;                 // 64 rows total
      const int doff = rb * 32 + lane * 8;
      gload_lds16(Wh + (size_t)(bn + rb + rsub) * K + k0 + csub, &sWh[buf][doff]);
      gload_lds16(Wl + (size_t)(bn + rb + rsub) * K + k0 + csub, &sWl[buf][doff]);
    }
  };

  stage(0, 0);
  __syncthreads();
  int cur = 0;
  for (int t = 0; t < NT; ++t) {
    if (t + 1 < NT) stage(cur ^ 1, (t + 1) << 5);
    short8 ah[4], al[4], wh[2], wl[2];
#pragma unroll
    for (int m = 0; m < 4; ++m) {
      int off = (wm * 64 + m * 16 + fr) * 32 + kg * 8;
      ah[m] = *(const short8*)&sAh[cur][off];
      al[m] = *(const short8*)&sAl[cur][off];
    }
#pragma unroll
    for (int n = 0; n < 2; ++n) {
      int off = (wn * 32 + n * 16 + fr) * 32 + kg * 8;
      wh[n] = *(const short8*)&sWh[cur][off];
      wl[n] = *(const short8*)&sWl[cur][off];
    }
#pragma unroll
    for (int m = 0; m < 4; ++m)
#pragma unroll
      for (int n = 0; n < 2; ++n) {
        acc[m][n] = __builtin_amdgcn_mfma_f32_16x16x32_bf16(ah[m], wh[n], acc[m][n], 0, 0, 0);
        acc[m][n] = __builtin_amdgcn_mfma_f32_16x16x32_bf16(al[m], wh[n], acc[m][n], 0, 0, 0);
        acc[m][n] = __builtin_amdgcn_mfma_f32_16x16x32_bf16(ah[m], wl[n], acc[m][n], 0, 0, 0);
      }
    __syncthreads();
    cur ^= 1;
  }
#pragma unroll
  for (int m = 0; m < 4; ++m) {
#pragma unroll
    for (int n = 0; n < 2; ++n) {
#pragma unroll
      for (int v = 0; v < 4; ++v) {
        int r = bm + wm * 64 + m * 16 + kg * 4 + v;
        int c = bn + wn * 32 + n * 16 + fr;
        float val = acc[m][n][v];
        if (SILU) val = silu_f(val);
        C[(size_t)r * ldc + c] = val;
      }
    }
  }
}

extern "C" void kernel_launch(void* const* d_in, const int* in_sizes, int n_in,
                              void* d_out, int out_size, void* d_ws, size_t ws_size,
                              hipStream_t stream) {
  const float* z   = (const float*)d_in[1];
  const float* lng = (const float*)d_in[2];
  const float* lnb = (const float*)d_in[3];
  const float* bw1 = (const float*)d_in[5];
  const float* sw1 = (const float*)d_in[6];
  const float* sc1 = (const float*)d_in[7];
  const float* bw2 = (const float*)d_in[9];
  const float* sw2 = (const float*)d_in[10];
  const float* sc2 = (const float*)d_in[11];
  const float* bw3 = (const float*)d_in[13];
  const float* sw3 = (const float*)d_in[14];
  const float* sc3 = (const float*)d_in[15];
  float* out = (float*)d_out;

  const int B = 8192, D = 512, H = 1024;
  char* ws = (char*)d_ws;
  size_t off = 0;
  float* ln_out = (float*)(ws + off); off += (size_t)B * D * 4;
  float* hbuf   = (float*)(ws + off); off += (size_t)B * H * 4;  // activated h
  char* Wregion = ws + off;           off += (size_t)H * 9216 * 4;
  size_t rem = ws_size > off ? ws_size - off : 0;
  int CB = 128;
  {
    const int cands[6] = {8192, 4096, 2048, 1024, 512, 256};
    for (int c = 0; c < 6; ++c) {
      if ((size_t)cands[c] * 9216 * 4 <= rem) { CB = cands[c]; break; }
    }
  }
  char* Xregion = ws + off;
  // typed overlays (stream-ordered reuse across layers)
  float* WF = (float*)Wregion;
  float* XF = (float*)Xregion;
  f16* WhF = (f16*)Wregion;
  f16* WlF = WhF + (size_t)H * 9216;
  f16* XhF = (f16*)Xregion;
  f16* XlF = XhF + (size_t)CB * 9216;
  u16* WhB = (u16*)Wregion;
  u16* WlB = WhB + (size_t)H * 9216;
  u16* XhB = (u16*)Xregion;
  u16* XlB = XhB + (size_t)CB * 9216;

  ln_kernel<<<B / 4, 256, 0, stream>>>(z, lng, lnb, ln_out);

  // ---- layer 1: f32 VALU GEMM (bitwise = r11-r16)
  {
    const int in_shift = 9, K = 9 * D, N = H;
    prep_w_f32<<<(H * D + 255) / 256, 256, 0, stream>>>(bw1, sw1, sc1, WF, in_shift, H * D);
    for (int r0 = 0; r0 < B; r0 += CB) {
      int cb = (B - r0 < CB) ? (B - r0) : CB;
      expand_f32<<<(cb << in_shift) / 256, 256, 0, stream>>>(
          ln_out + (size_t)r0 * D, XF, in_shift, cb << in_shift);
      dim3 grid(N / 128, cb / 128);
      gemm_f32<true, 128><<<grid, 256, 0, stream>>>(XF, WF, hbuf + (size_t)r0 * H, cb, N, K, H);
    }
  }
  // ---- layer 2: f16x2 FUSED 3-product MFMA, silu epilogue (this round)
  {
    const int in_shift = 10, K = 9 * H, N = H;
    prep_w_f16<<<(H * H + 255) / 256, 256, 0, stream>>>(bw2, sw2, sc2, WhF, WlF, in_shift, H * H);
    for (int r0 = 0; r0 < B; r0 += CB) {
      int cb = (B - r0 < CB) ? (B - r0) : CB;
      expand_f16<<<(cb << in_shift) / 256, 256, 0, stream>>>(
          hbuf + (size_t)r0 * H, XhF, XlF, in_shift, cb << in_shift);
      dim3 grid(N / 128, cb / 128);
      gemm_fused_f16<true><<<grid, 256, 0, stream>>>(
          XhF, XlF, WhF, WlF, hbuf + (size_t)r0 * H, cb, N, K, H);
    }
  }
  // ---- layer 3: bf16x2 FUSED 3-product MFMA, BN=64, no silu (this round)
  {
    const int in_shift = 10, K = 9 * H, N = D;
    prep_w_bf<<<(D * H + 255) / 256, 256, 0, stream>>>(bw3, sw3, sc3, WhB, WlB, in_shift, D * H);
    for (int r0 = 0; r0 < B; r0 += CB) {
      int cb = (B - r0 < CB) ? (B - r0) : CB;
      expand_bf<<<(cb << in_shift) / 256, 256, 0, stream>>>(
          hbuf + (size_t)r0 * H, XhB, XlB, in_shift, cb << in_shift);
      dim3 grid(N / 64, cb / 128);
      gemm_fused_bf64<false><<<grid, 256, 0, stream>>>(
          XhB, XlB, WhB, WlB, out + (size_t)r0 * D, cb, N, K, D);
    }
  }
}

// Round 20
// 2414.641 us; speedup vs baseline: 2.7553x; 1.0019x over previous
//
#include <hip/hip_runtime.h>
#include <hip/hip_bf16.h>
#include <cstdint>

typedef unsigned short u16;
typedef _Float16 f16;
typedef _Float16 f16x8 __attribute__((ext_vector_type(8)));
typedef short short8 __attribute__((ext_vector_type(8)));
typedef float f32x4 __attribute__((ext_vector_type(4)));

__device__ __forceinline__ float silu_f(float v) {
  return v / (1.0f + expf(-v));
}

// f32 -> bf16 round-to-nearest-even
__device__ __forceinline__ u16 f2bf(float f) {
  union { float f; uint32_t u; } v; v.f = f;
  uint32_t r = v.u + 0x7fffu + ((v.u >> 16) & 1u);
  return (u16)(r >> 16);
}
__device__ __forceinline__ float bf2f(u16 b) {
  union { uint32_t u; float f; } v; v.u = ((uint32_t)b) << 16;
  return v.f;
}
__device__ __forceinline__ void split_bf(float f, u16* hi, u16* lo) {
  u16 h = f2bf(f);
  *hi = h;
  *lo = f2bf(f - bf2f(h));
}
// f16x2 split (unscaled, proven r16/r17 on L2)
__device__ __forceinline__ void split_f16(float f, f16* hi, f16* lo) {
  f16 h = (f16)f;
  *hi = h;
  *lo = (f16)(f - (float)h);
}

// B-spline bases, exact Cox-de Boor recursion matching the reference.
__device__ __forceinline__ void bspl(float x, float* b8) {
  float b[11];
#pragma unroll
  for (int j = 0; j < 11; ++j) {
    float g0 = -2.2f + 0.4f * j;
    float g1 = g0 + 0.4f;
    b[j] = (x >= g0 && x < g1) ? 1.0f : 0.0f;
  }
#pragma unroll
  for (int k = 1; k <= 3; ++k) {
    float inv = 1.0f / (0.4f * k);
#pragma unroll
    for (int j = 0; j + k < 11; ++j) {
      float gj = -2.2f + 0.4f * j;
      float l = (x - gj) * inv;
      float r = (gj + 0.4f * (k + 1) - x) * inv;
      b[j] = l * b[j] + r * b[j + 1];
    }
  }
#pragma unroll
  for (int g = 0; g < 8; ++g) b8[g] = b[g];
}

// ---------------- LayerNorm (bitwise = r8-r17) ----------------------------
__global__ __launch_bounds__(256) void ln_kernel(
    const float* __restrict__ z, const float* __restrict__ gamma,
    const float* __restrict__ beta, float* __restrict__ out) {
  const int row = blockIdx.x * 4 + (threadIdx.x >> 6);
  const int lane = threadIdx.x & 63;
  const float4* zr = (const float4*)(z + (size_t)row * 512);
  float4 v0 = zr[lane * 2], v1 = zr[lane * 2 + 1];
  float s = v0.x + v0.y + v0.z + v0.w + v1.x + v1.y + v1.z + v1.w;
  float q = v0.x * v0.x + v0.y * v0.y + v0.z * v0.z + v0.w * v0.w +
            v1.x * v1.x + v1.y * v1.y + v1.z * v1.z + v1.w * v1.w;
#pragma unroll
  for (int o = 32; o > 0; o >>= 1) {
    s += __shfl_down(s, o);
    q += __shfl_down(q, o);
  }
  float mu = __shfl(s, 0) * (1.0f / 512.0f);
  float ex2 = __shfl(q, 0) * (1.0f / 512.0f);
  float rs = rsqrtf(ex2 - mu * mu + 1e-5f);
  const float4* gp = (const float4*)gamma;
  const float4* bp = (const float4*)beta;
  float4 g0 = gp[lane * 2], g1 = gp[lane * 2 + 1];
  float4 b0 = bp[lane * 2], b1 = bp[lane * 2 + 1];
  float4 o0, o1;
  o0.x = (v0.x - mu) * rs * g0.x + b0.x;
  o0.y = (v0.y - mu) * rs * g0.y + b0.y;
  o0.z = (v0.z - mu) * rs * g0.z + b0.z;
  o0.w = (v0.w - mu) * rs * g0.w + b0.w;
  o1.x = (v1.x - mu) * rs * g1.x + b1.x;
  o1.y = (v1.y - mu) * rs * g1.y + b1.y;
  o1.z = (v1.z - mu) * rs * g1.z + b1.z;
  o1.w = (v1.w - mu) * rs * g1.w + b1.w;
  float4* op = (float4*)(out + (size_t)row * 512);
  op[lane * 2] = o0;
  op[lane * 2 + 1] = o1;
}

// ---------------- W_eff prep f32 (L1, bitwise) -----------------------------
__global__ __launch_bounds__(256) void prep_w_f32(
    const float* __restrict__ bw, const float* __restrict__ sw,
    const float* __restrict__ sc, float* __restrict__ W,
    int in_shift, int total) {
  int idx = blockIdx.x * 256 + threadIdx.x;
  if (idx >= total) return;
  int in = 1 << in_shift;
  int i = idx & (in - 1);
  int o = idx >> in_shift;
  size_t wb = (size_t)o * ((size_t)9 << in_shift) + i;
  float s = sc[idx];
  const float4* swp = (const float4*)(sw + (size_t)idx * 8);
  float4 a = swp[0], b = swp[1];
  W[wb] = bw[idx];
  W[wb + ((size_t)1 << in_shift)] = a.x * s;
  W[wb + ((size_t)2 << in_shift)] = a.y * s;
  W[wb + ((size_t)3 << in_shift)] = a.z * s;
  W[wb + ((size_t)4 << in_shift)] = a.w * s;
  W[wb + ((size_t)5 << in_shift)] = b.x * s;
  W[wb + ((size_t)6 << in_shift)] = b.y * s;
  W[wb + ((size_t)7 << in_shift)] = b.z * s;
  W[wb + ((size_t)8 << in_shift)] = b.w * s;
}

// ---------------- expansion f32 (L1, bitwise) ------------------------------
__global__ __launch_bounds__(256) void expand_f32(
    const float* __restrict__ x, float* __restrict__ X, int in_shift, int total) {
  int idx = blockIdx.x * 256 + threadIdx.x;
  if (idx >= total) return;
  int in = 1 << in_shift;
  int i = idx & (in - 1);
  int b = idx >> in_shift;
  float v = x[idx];
  size_t base = (size_t)b * ((size_t)9 << in_shift) + i;
  float bs[8];
  bspl(v, bs);
  X[base] = silu_f(v);
#pragma unroll
  for (int g = 0; g < 8; ++g)
    X[base + ((size_t)(g + 1) << in_shift)] = bs[g];
}

// ---------------- W_eff prep f16 hi/lo (L2, bitwise = r17) ----------------
__global__ __launch_bounds__(256) void prep_w_f16(
    const float* __restrict__ bw, const float* __restrict__ sw,
    const float* __restrict__ sc, f16* __restrict__ Wh, f16* __restrict__ Wl,
    int in_shift, int total) {
  int idx = blockIdx.x * 256 + threadIdx.x;
  if (idx >= total) return;
  int in = 1 << in_shift;
  int i = idx & (in - 1);
  int o = idx >> in_shift;
  size_t wb = (size_t)o * ((size_t)9 << in_shift) + i;
  float s = sc[idx];
  const float4* swp = (const float4*)(sw + (size_t)idx * 8);
  float4 a = swp[0], b = swp[1];
  float vals[9] = {bw[idx], a.x * s, a.y * s, a.z * s, a.w * s,
                   b.x * s, b.y * s, b.z * s, b.w * s};
#pragma unroll
  for (int c = 0; c < 9; ++c) {
    f16 h, l;
    split_f16(vals[c], &h, &l);
    Wh[wb + ((size_t)c << in_shift)] = h;
    Wl[wb + ((size_t)c << in_shift)] = l;
  }
}

// ---------------- expansion f16 hi/lo (L2, bitwise = r17) -----------------
__global__ __launch_bounds__(256) void expand_f16(
    const float* __restrict__ x, f16* __restrict__ Xh, f16* __restrict__ Xl,
    int in_shift, int total) {
  int idx = blockIdx.x * 256 + threadIdx.x;
  if (idx >= total) return;
  int in = 1 << in_shift;
  int i = idx & (in - 1);
  int b = idx >> in_shift;
  float v = x[idx];
  size_t base = (size_t)b * ((size_t)9 << in_shift) + i;
  float bs[8];
  bspl(v, bs);
  float vals[9];
  vals[0] = silu_f(v);
#pragma unroll
  for (int g = 0; g < 8; ++g) vals[g + 1] = bs[g];
#pragma unroll
  for (int c = 0; c < 9; ++c) {
    f16 h, l;
    split_f16(vals[c], &h, &l);
    Xh[base + ((size_t)c << in_shift)] = h;
    Xl[base + ((size_t)c << in_shift)] = l;
  }
}

// ---------------- W_eff prep bf16 hi/lo (L3, bitwise = r17) ---------------
__global__ __launch_bounds__(256) void prep_w_bf(
    const float* __restrict__ bw, const float* __restrict__ sw,
    const float* __restrict__ sc, u16* __restrict__ Wh, u16* __restrict__ Wl,
    int in_shift, int total) {
  int idx = blockIdx.x * 256 + threadIdx.x;
  if (idx >= total) return;
  int in = 1 << in_shift;
  int i = idx & (in - 1);
  int o = idx >> in_shift;
  size_t wb = (size_t)o * ((size_t)9 << in_shift) + i;
  float s = sc[idx];
  const float4* swp = (const float4*)(sw + (size_t)idx * 8);
  float4 a = swp[0], b = swp[1];
  float vals[9] = {bw[idx], a.x * s, a.y * s, a.z * s, a.w * s,
                   b.x * s, b.y * s, b.z * s, b.w * s};
#pragma unroll
  for (int c = 0; c < 9; ++c) {
    u16 h, l;
    split_bf(vals[c], &h, &l);
    Wh[wb + ((size_t)c << in_shift)] = h;
    Wl[wb + ((size_t)c << in_shift)] = l;
  }
}

// ---------------- expansion bf16 hi/lo (L3, bitwise = r17) ----------------
__global__ __launch_bounds__(256) void expand_bf(
    const float* __restrict__ x, u16* __restrict__ Xh, u16* __restrict__ Xl,
    int in_shift, int total) {
  int idx = blockIdx.x * 256 + threadIdx.x;
  if (idx >= total) return;
  int in = 1 << in_shift;
  int i = idx & (in - 1);
  int b = idx >> in_shift;
  float v = x[idx];
  size_t base = (size_t)b * ((size_t)9 << in_shift) + i;
  float bs[8];
  bspl(v, bs);
  float vals[9];
  vals[0] = silu_f(v);
#pragma unroll
  for (int g = 0; g < 8; ++g) vals[g + 1] = bs[g];
#pragma unroll
  for (int c = 0; c < 9; ++c) {
    u16 h, l;
    split_bf(vals[c], &h, &l);
    Xh[base + ((size_t)c << in_shift)] = h;
    Xl[base + ((size_t)c << in_shift)] = l;
  }
}

// ---------------- f32 tiled GEMM (L1; BN=64 this round for occupancy) -----
template <bool SILU, int BN>
__global__ __launch_bounds__(256, BN == 64 ? 3 : 2) void gemm_f32(
    const float* __restrict__ A, const float* __restrict__ B,
    float* __restrict__ C, int M, int N, int K, int ldc) {
  constexpr int TN = BN / 16;
  constexpr int BP = BN / 32;
  __shared__ float As[2][32][132];
  __shared__ float Bs[2][32][BN + 4];
  const int tid = threadIdx.x;
  const int bm = blockIdx.y * 128, bn = blockIdx.x * BN;
  const int tx = tid & 15, ty = tid >> 4;
  const int sr = tid >> 3;
  const int sk = (tid & 7) * 4;
  const float* gA = A + (size_t)(bm + sr) * K + sk;
  const float* gB = B + (size_t)(bn + sr) * K + sk;
  float acc[8][TN] = {};
  float acc_t[8][TN] = {};
  float4 av[4], bv[BP];
  const int NT = K >> 5;
#pragma unroll
  for (int p = 0; p < 4; ++p)
    av[p] = *(const float4*)(gA + (size_t)p * 32 * K);
#pragma unroll
  for (int p = 0; p < BP; ++p)
    bv[p] = *(const float4*)(gB + (size_t)p * 32 * K);
#pragma unroll
  for (int p = 0; p < 4; ++p) {
    int m = p * 32 + sr;
    As[0][sk + 0][m] = av[p].x; As[0][sk + 1][m] = av[p].y;
    As[0][sk + 2][m] = av[p].z; As[0][sk + 3][m] = av[p].w;
  }
#pragma unroll
  for (int p = 0; p < BP; ++p) {
    int m = p * 32 + sr;
    Bs[0][sk + 0][m] = bv[p].x; Bs[0][sk + 1][m] = bv[p].y;
    Bs[0][sk + 2][m] = bv[p].z; Bs[0][sk + 3][m] = bv[p].w;
  }
  __syncthreads();
  for (int t = 0; t < NT; ++t) {
    const int cur = t & 1;
    if (t + 1 < NT) {
      const int k0 = (t + 1) << 5;
#pragma unroll
      for (int p = 0; p < 4; ++p)
        av[p] = *(const float4*)(gA + (size_t)p * 32 * K + k0);
#pragma unroll
      for (int p = 0; p < BP; ++p)
        bv[p] = *(const float4*)(gB + (size_t)p * 32 * K + k0);
    }
#pragma unroll 4
    for (int kk = 0; kk < 32; ++kk) {
      float4 a0 = *(const float4*)&As[cur][kk][ty * 8];
      float4 a1 = *(const float4*)&As[cur][kk][ty * 8 + 4];
      float a[8] = {a0.x, a0.y, a0.z, a0.w, a1.x, a1.y, a1.z, a1.w};
      float b[TN];
#pragma unroll
      for (int q = 0; q < TN; q += 4) {
        float4 bq = *(const float4*)&Bs[cur][kk][tx * TN + q];
        b[q] = bq.x; b[q + 1] = bq.y; b[q + 2] = bq.z; b[q + 3] = bq.w;
      }
#pragma unroll
      for (int j = 0; j < 8; ++j)
#pragma unroll
        for (int l = 0; l < TN; ++l)
          acc[j][l] += a[j] * b[l];
    }
#pragma unroll
    for (int j = 0; j < 8; ++j)
#pragma unroll
      for (int l = 0; l < TN; ++l) {
        acc_t[j][l] += acc[j][l];
        acc[j][l] = 0.0f;
      }
    if (t + 1 < NT) {
      const int nxt = cur ^ 1;
#pragma unroll
      for (int p = 0; p < 4; ++p) {
        int m = p * 32 + sr;
        As[nxt][sk + 0][m] = av[p].x; As[nxt][sk + 1][m] = av[p].y;
        As[nxt][sk + 2][m] = av[p].z; As[nxt][sk + 3][m] = av[p].w;
      }
#pragma unroll
      for (int p = 0; p < BP; ++p) {
        int m = p * 32 + sr;
        Bs[nxt][sk + 0][m] = bv[p].x; Bs[nxt][sk + 1][m] = bv[p].y;
        Bs[nxt][sk + 2][m] = bv[p].z; Bs[nxt][sk + 3][m] = bv[p].w;
      }
      __syncthreads();
    }
  }
#pragma unroll
  for (int j = 0; j < 8; ++j) {
    int r = bm + ty * 8 + j;
    float* cp = C + (size_t)r * ldc + bn + tx * TN;
#pragma unroll
    for (int q = 0; q < TN; q += 4) {
      float4 o;
      o.x = acc_t[j][q]; o.y = acc_t[j][q + 1];
      o.z = acc_t[j][q + 2]; o.w = acc_t[j][q + 3];
      if (SILU) {
        o.x = silu_f(o.x); o.y = silu_f(o.y);
        o.z = silu_f(o.z); o.w = silu_f(o.w);
      }
      *(float4*)(cp + q) = o;
    }
  }
}

// ---------------- FUSED 3-product dbuf MFMA GEMMs (bitwise = r17) ---------
__device__ __forceinline__ void gload_lds16(const void* g, void* l) {
  __builtin_amdgcn_global_load_lds(
      (const __attribute__((address_space(1))) void*)g,
      (__attribute__((address_space(3))) void*)l, 16, 0, 0);
}

// f16 unscaled 3-product variant, BN=128 (L2)
template <bool SILU>
__global__ __launch_bounds__(256) void gemm_fused_f16(
    const f16* __restrict__ Ah, const f16* __restrict__ Al,
    const f16* __restrict__ Wh, const f16* __restrict__ Wl,
    float* __restrict__ C, int M, int N, int K, int ldc) {
  __shared__ __align__(16) f16 sAh[2][128 * 32];
  __shared__ __align__(16) f16 sAl[2][128 * 32];
  __shared__ __align__(16) f16 sWh[2][128 * 32];
  __shared__ __align__(16) f16 sWl[2][128 * 32];
  const int tid = threadIdx.x, wave = tid >> 6, lane = tid & 63;
  const int bm = blockIdx.y * 128, bn = blockIdx.x * 128;
  const int rsub = lane >> 2;
  const int csub = (lane & 3) * 8;
  const int wm = wave >> 1, wn = wave & 1;
  const int fr = lane & 15, kg = lane >> 4;
  f32x4 acc[4][4] = {};
  const int NT = K >> 5;

  auto stage = [&](int buf, int k0) {
#pragma unroll
    for (int s = 0; s < 2; ++s) {
      const int rb = (s * 4 + wave) * 16;
      const int doff = rb * 32 + lane * 8;
      gload_lds16(Ah + (size_t)(bm + rb + rsub) * K + k0 + csub, &sAh[buf][doff]);
      gload_lds16(Al + (size_t)(bm + rb + rsub) * K + k0 + csub, &sAl[buf][doff]);
      gload_lds16(Wh + (size_t)(bn + rb + rsub) * K + k0 + csub, &sWh[buf][doff]);
      gload_lds16(Wl + (size_t)(bn + rb + rsub) * K + k0 + csub, &sWl[buf][doff]);
    }
  };

  stage(0, 0);
  __syncthreads();
  int cur = 0;
  for (int t = 0; t < NT; ++t) {
    if (t + 1 < NT) stage(cur ^ 1, (t + 1) << 5);
    f16x8 ah[4], al[4], wh[4], wl[4];
#pragma unroll
    for (int m = 0; m < 4; ++m) {
      int off = (wm * 64 + m * 16 + fr) * 32 + kg * 8;
      ah[m] = *(const f16x8*)&sAh[cur][off];
      al[m] = *(const f16x8*)&sAl[cur][off];
    }
#pragma unroll
    for (int n = 0; n < 4; ++n) {
      int off = (wn * 64 + n * 16 + fr) * 32 + kg * 8;
      wh[n] = *(const f16x8*)&sWh[cur][off];
      wl[n] = *(const f16x8*)&sWl[cur][off];
    }
#pragma unroll
    for (int m = 0; m < 4; ++m)
#pragma unroll
      for (int n = 0; n < 4; ++n) {
        acc[m][n] = __builtin_amdgcn_mfma_f32_16x16x32_f16(ah[m], wh[n], acc[m][n], 0, 0, 0);
        acc[m][n] = __builtin_amdgcn_mfma_f32_16x16x32_f16(al[m], wh[n], acc[m][n], 0, 0, 0);
        acc[m][n] = __builtin_amdgcn_mfma_f32_16x16x32_f16(ah[m], wl[n], acc[m][n], 0, 0, 0);
      }
    __syncthreads();
    cur ^= 1;
  }
#pragma unroll
  for (int m = 0; m < 4; ++m) {
#pragma unroll
    for (int n = 0; n < 4; ++n) {
#pragma unroll
      for (int v = 0; v < 4; ++v) {
        int r = bm + wm * 64 + m * 16 + kg * 4 + v;
        int c = bn + wn * 64 + n * 16 + fr;
        float val = acc[m][n][v];
        if (SILU) val = silu_f(val);
        C[(size_t)r * ldc + c] = val;
      }
    }
  }
}

// bf16 variant, BN=64 (L3)
template <bool SILU>
__global__ __launch_bounds__(256) void gemm_fused_bf64(
    const u16* __restrict__ Ah, const u16* __restrict__ Al,
    const u16* __restrict__ Wh, const u16* __restrict__ Wl,
    float* __restrict__ C, int M, int N, int K, int ldc) {
  __shared__ __align__(16) u16 sAh[2][128 * 32];
  __shared__ __align__(16) u16 sAl[2][128 * 32];
  __shared__ __align__(16) u16 sWh[2][64 * 32];
  __shared__ __align__(16) u16 sWl[2][64 * 32];
  const int tid = threadIdx.x, wave = tid >> 6, lane = tid & 63;
  const int bm = blockIdx.y * 128, bn = blockIdx.x * 64;
  const int rsub = lane >> 2;
  const int csub = (lane & 3) * 8;
  const int wm = wave >> 1, wn = wave & 1;
  const int fr = lane & 15, kg = lane >> 4;
  f32x4 acc[4][2] = {};
  const int NT = K >> 5;

  auto stage = [&](int buf, int k0) {
#pragma unroll
    for (int s = 0; s < 2; ++s) {
      const int rb = (s * 4 + wave) * 16;
      const int doff = rb * 32 + lane * 8;
      gload_lds16(Ah + (size_t)(bm + rb + rsub) * K + k0 + csub, &sAh[buf][doff]);
      gload_lds16(Al + (size_t)(bm + rb + rsub) * K + k0 + csub, &sAl[buf][doff]);
    }
    {
      const int rb = wave * 16;
      const int doff = rb * 32 + lane * 8;
      gload_lds16(Wh + (size_t)(bn + rb + rsub) * K + k0 + csub, &sWh[buf][doff]);
      gload_lds16(Wl + (size_t)(bn + rb + rsub) * K + k0 + csub, &sWl[buf][doff]);
    }
  };

  stage(0, 0);
  __syncthreads();
  int cur = 0;
  for (int t = 0; t < NT; ++t) {
    if (t + 1 < NT) stage(cur ^ 1, (t + 1) << 5);
    short8 ah[4], al[4], wh[2], wl[2];
#pragma unroll
    for (int m = 0; m < 4; ++m) {
      int off = (wm * 64 + m * 16 + fr) * 32 + kg * 8;
      ah[m] = *(const short8*)&sAh[cur][off];
      al[m] = *(const short8*)&sAl[cur][off];
    }
#pragma unroll
    for (int n = 0; n < 2; ++n) {
      int off = (wn * 32 + n * 16 + fr) * 32 + kg * 8;
      wh[n] = *(const short8*)&sWh[cur][off];
      wl[n] = *(const short8*)&sWl[cur][off];
    }
#pragma unroll
    for (int m = 0; m < 4; ++m)
#pragma unroll
      for (int n = 0; n < 2; ++n) {
        acc[m][n] = __builtin_amdgcn_mfma_f32_16x16x32_bf16(ah[m], wh[n], acc[m][n], 0, 0, 0);
        acc[m][n] = __builtin_amdgcn_mfma_f32_16x16x32_bf16(al[m], wh[n], acc[m][n], 0, 0, 0);
        acc[m][n] = __builtin_amdgcn_mfma_f32_16x16x32_bf16(ah[m], wl[n], acc[m][n], 0, 0, 0);
      }
    __syncthreads();
    cur ^= 1;
  }
#pragma unroll
  for (int m = 0; m < 4; ++m) {
#pragma unroll
    for (int n = 0; n < 2; ++n) {
#pragma unroll
      for (int v = 0; v < 4; ++v) {
        int r = bm + wm * 64 + m * 16 + kg * 4 + v;
        int c = bn + wn * 32 + n * 16 + fr;
        float val = acc[m][n][v];
        if (SILU) val = silu_f(val);
        C[(size_t)r * ldc + c] = val;
      }
    }
  }
}

extern "C" void kernel_launch(void* const* d_in, const int* in_sizes, int n_in,
                              void* d_out, int out_size, void* d_ws, size_t ws_size,
                              hipStream_t stream) {
  const float* z   = (const float*)d_in[1];
  const float* lng = (const float*)d_in[2];
  const float* lnb = (const float*)d_in[3];
  const float* bw1 = (const float*)d_in[5];
  const float* sw1 = (const float*)d_in[6];
  const float* sc1 = (const float*)d_in[7];
  const float* bw2 = (const float*)d_in[9];
  const float* sw2 = (const float*)d_in[10];
  const float* sc2 = (const float*)d_in[11];
  const float* bw3 = (const float*)d_in[13];
  const float* sw3 = (const float*)d_in[14];
  const float* sc3 = (const float*)d_in[15];
  float* out = (float*)d_out;

  const int B = 8192, D = 512, H = 1024;
  char* ws = (char*)d_ws;
  size_t off = 0;
  float* ln_out = (float*)(ws + off); off += (size_t)B * D * 4;
  float* hbuf   = (float*)(ws + off); off += (size_t)B * H * 4;  // activated h
  char* Wregion = ws + off;           off += (size_t)H * 9216 * 4;
  size_t rem = ws_size > off ? ws_size - off : 0;
  int CB = 128;
  {
    const int cands[6] = {8192, 4096, 2048, 1024, 512, 256};
    for (int c = 0; c < 6; ++c) {
      if ((size_t)cands[c] * 9216 * 4 <= rem) { CB = cands[c]; break; }
    }
  }
  char* Xregion = ws + off;
  // typed overlays (stream-ordered reuse across layers)
  float* WF = (float*)Wregion;
  float* XF = (float*)Xregion;
  f16* WhF = (f16*)Wregion;
  f16* WlF = WhF + (size_t)H * 9216;
  f16* XhF = (f16*)Xregion;
  f16* XlF = XhF + (size_t)CB * 9216;
  u16* WhB = (u16*)Wregion;
  u16* WlB = WhB + (size_t)H * 9216;
  u16* XhB = (u16*)Xregion;
  u16* XlB = XhB + (size_t)CB * 9216;

  ln_kernel<<<B / 4, 256, 0, stream>>>(z, lng, lnb, ln_out);

  // ---- layer 1: f32 VALU GEMM, BN=64 (bitwise output = r17; 3 blocks/CU)
  {
    const int in_shift = 9, K = 9 * D, N = H;
    prep_w_f32<<<(H * D + 255) / 256, 256, 0, stream>>>(bw1, sw1, sc1, WF, in_shift, H * D);
    for (int r0 = 0; r0 < B; r0 += CB) {
      int cb = (B - r0 < CB) ? (B - r0) : CB;
      expand_f32<<<(cb << in_shift) / 256, 256, 0, stream>>>(
          ln_out + (size_t)r0 * D, XF, in_shift, cb << in_shift);
      dim3 grid(N / 64, cb / 128);
      gemm_f32<true, 64><<<grid, 256, 0, stream>>>(XF, WF, hbuf + (size_t)r0 * H, cb, N, K, H);
    }
  }
  // ---- layer 2: f16x2 fused MFMA, silu epilogue (bitwise = r17)
  {
    const int in_shift = 10, K = 9 * H, N = H;
    prep_w_f16<<<(H * H + 255) / 256, 256, 0, stream>>>(
        bw2, sw2, sc2, WhF, WlF, in_shift, H * H);
    for (int r0 = 0; r0 < B; r0 += CB) {
      int cb = (B - r0 < CB) ? (B - r0) : CB;
      expand_f16<<<(cb << in_shift) / 256, 256, 0, stream>>>(
          hbuf + (size_t)r0 * H, XhF, XlF, in_shift, cb << in_shift);
      dim3 grid(N / 128, cb / 128);
      gemm_fused_f16<true><<<grid, 256, 0, stream>>>(
          XhF, XlF, WhF, WlF, hbuf + (size_t)r0 * H, cb, N, K, H);
    }
  }
  // ---- layer 3: bf16x2 fused MFMA, BN=64, no silu (bitwise = r17)
  {
    const int in_shift = 10, K = 9 * H, N = D;
    prep_w_bf<<<(D * H + 255) / 256, 256, 0, stream>>>(bw3, sw3, sc3, WhB, WlB, in_shift, D * H);
    for (int r0 = 0; r0 < B; r0 += CB) {
      int cb = (B - r0 < CB) ? (B - r0) : CB;
      expand_bf<<<(cb << in_shift) / 256, 256, 0, stream>>>(
          hbuf + (size_t)r0 * H, XhB, XlB, in_shift, cb << in_shift);
      dim3 grid(N / 64, cb / 128);
      gemm_fused_bf64<false><<<grid, 256, 0, stream>>>(
          XhB, XlB, WhB, WlB, out + (size_t)r0 * D, cb, N, K, D);
    }
  }
}

// Round 22
// 2406.791 us; speedup vs baseline: 2.7643x; 1.0033x over previous
//
#include <hip/hip_runtime.h>
#include <hip/hip_bf16.h>
#include <cstdint>

typedef unsigned short u16;
typedef _Float16 f16;
typedef _Float16 f16x8 __attribute__((ext_vector_type(8)));
typedef short short8 __attribute__((ext_vector_type(8)));
typedef float f32x4 __attribute__((ext_vector_type(4)));

__device__ __forceinline__ float silu_f(float v) {
  return v / (1.0f + expf(-v));
}

// f32 -> bf16 round-to-nearest-even
__device__ __forceinline__ u16 f2bf(float f) {
  union { float f; uint32_t u; } v; v.f = f;
  uint32_t r = v.u + 0x7fffu + ((v.u >> 16) & 1u);
  return (u16)(r >> 16);
}
__device__ __forceinline__ float bf2f(u16 b) {
  union { uint32_t u; float f; } v; v.u = ((uint32_t)b) << 16;
  return v.f;
}
__device__ __forceinline__ void split_bf(float f, u16* hi, u16* lo) {
  u16 h = f2bf(f);
  *hi = h;
  *lo = f2bf(f - bf2f(h));
}
// f16x2 split (unscaled, proven r16/r17 on L2)
__device__ __forceinline__ void split_f16(float f, f16* hi, f16* lo) {
  f16 h = (f16)f;
  *hi = h;
  *lo = (f16)(f - (float)h);
}

// B-spline bases, exact Cox-de Boor recursion matching the reference.
__device__ __forceinline__ void bspl(float x, float* b8) {
  float b[11];
#pragma unroll
  for (int j = 0; j < 11; ++j) {
    float g0 = -2.2f + 0.4f * j;
    float g1 = g0 + 0.4f;
    b[j] = (x >= g0 && x < g1) ? 1.0f : 0.0f;
  }
#pragma unroll
  for (int k = 1; k <= 3; ++k) {
    float inv = 1.0f / (0.4f * k);
#pragma unroll
    for (int j = 0; j + k < 11; ++j) {
      float gj = -2.2f + 0.4f * j;
      float l = (x - gj) * inv;
      float r = (gj + 0.4f * (k + 1) - x) * inv;
      b[j] = l * b[j] + r * b[j + 1];
    }
  }
#pragma unroll
  for (int g = 0; g < 8; ++g) b8[g] = b[g];
}

// ---------------- LayerNorm (bitwise = r8-r20) ----------------------------
__global__ __launch_bounds__(256) void ln_kernel(
    const float* __restrict__ z, const float* __restrict__ gamma,
    const float* __restrict__ beta, float* __restrict__ out) {
  const int row = blockIdx.x * 4 + (threadIdx.x >> 6);
  const int lane = threadIdx.x & 63;
  const float4* zr = (const float4*)(z + (size_t)row * 512);
  float4 v0 = zr[lane * 2], v1 = zr[lane * 2 + 1];
  float s = v0.x + v0.y + v0.z + v0.w + v1.x + v1.y + v1.z + v1.w;
  float q = v0.x * v0.x + v0.y * v0.y + v0.z * v0.z + v0.w * v0.w +
            v1.x * v1.x + v1.y * v1.y + v1.z * v1.z + v1.w * v1.w;
#pragma unroll
  for (int o = 32; o > 0; o >>= 1) {
    s += __shfl_down(s, o);
    q += __shfl_down(q, o);
  }
  float mu = __shfl(s, 0) * (1.0f / 512.0f);
  float ex2 = __shfl(q, 0) * (1.0f / 512.0f);
  float rs = rsqrtf(ex2 - mu * mu + 1e-5f);
  const float4* gp = (const float4*)gamma;
  const float4* bp = (const float4*)beta;
  float4 g0 = gp[lane * 2], g1 = gp[lane * 2 + 1];
  float4 b0 = bp[lane * 2], b1 = bp[lane * 2 + 1];
  float4 o0, o1;
  o0.x = (v0.x - mu) * rs * g0.x + b0.x;
  o0.y = (v0.y - mu) * rs * g0.y + b0.y;
  o0.z = (v0.z - mu) * rs * g0.z + b0.z;
  o0.w = (v0.w - mu) * rs * g0.w + b0.w;
  o1.x = (v1.x - mu) * rs * g1.x + b1.x;
  o1.y = (v1.y - mu) * rs * g1.y + b1.y;
  o1.z = (v1.z - mu) * rs * g1.z + b1.z;
  o1.w = (v1.w - mu) * rs * g1.w + b1.w;
  float4* op = (float4*)(out + (size_t)row * 512);
  op[lane * 2] = o0;
  op[lane * 2 + 1] = o1;
}

// ---------------- W_eff prep f32 (L1, bitwise) -----------------------------
__global__ __launch_bounds__(256) void prep_w_f32(
    const float* __restrict__ bw, const float* __restrict__ sw,
    const float* __restrict__ sc, float* __restrict__ W,
    int in_shift, int total) {
  int idx = blockIdx.x * 256 + threadIdx.x;
  if (idx >= total) return;
  int in = 1 << in_shift;
  int i = idx & (in - 1);
  int o = idx >> in_shift;
  size_t wb = (size_t)o * ((size_t)9 << in_shift) + i;
  float s = sc[idx];
  const float4* swp = (const float4*)(sw + (size_t)idx * 8);
  float4 a = swp[0], b = swp[1];
  W[wb] = bw[idx];
  W[wb + ((size_t)1 << in_shift)] = a.x * s;
  W[wb + ((size_t)2 << in_shift)] = a.y * s;
  W[wb + ((size_t)3 << in_shift)] = a.z * s;
  W[wb + ((size_t)4 << in_shift)] = a.w * s;
  W[wb + ((size_t)5 << in_shift)] = b.x * s;
  W[wb + ((size_t)6 << in_shift)] = b.y * s;
  W[wb + ((size_t)7 << in_shift)] = b.z * s;
  W[wb + ((size_t)8 << in_shift)] = b.w * s;
}

// ---------------- expansion f32 (L1, bitwise) ------------------------------
__global__ __launch_bounds__(256) void expand_f32(
    const float* __restrict__ x, float* __restrict__ X, int in_shift, int total) {
  int idx = blockIdx.x * 256 + threadIdx.x;
  if (idx >= total) return;
  int in = 1 << in_shift;
  int i = idx & (in - 1);
  int b = idx >> in_shift;
  float v = x[idx];
  size_t base = (size_t)b * ((size_t)9 << in_shift) + i;
  float bs[8];
  bspl(v, bs);
  X[base] = silu_f(v);
#pragma unroll
  for (int g = 0; g < 8; ++g)
    X[base + ((size_t)(g + 1) << in_shift)] = bs[g];
}

// ---------------- W_eff prep f16 hi/lo (L2, bitwise = r17) ----------------
__global__ __launch_bounds__(256) void prep_w_f16(
    const float* __restrict__ bw, const float* __restrict__ sw,
    const float* __restrict__ sc, f16* __restrict__ Wh, f16* __restrict__ Wl,
    int in_shift, int total) {
  int idx = blockIdx.x * 256 + threadIdx.x;
  if (idx >= total) return;
  int in = 1 << in_shift;
  int i = idx & (in - 1);
  int o = idx >> in_shift;
  size_t wb = (size_t)o * ((size_t)9 << in_shift) + i;
  float s = sc[idx];
  const float4* swp = (const float4*)(sw + (size_t)idx * 8);
  float4 a = swp[0], b = swp[1];
  float vals[9] = {bw[idx], a.x * s, a.y * s, a.z * s, a.w * s,
                   b.x * s, b.y * s, b.z * s, b.w * s};
#pragma unroll
  for (int c = 0; c < 9; ++c) {
    f16 h, l;
    split_f16(vals[c], &h, &l);
    Wh[wb + ((size_t)c << in_shift)] = h;
    Wl[wb + ((size_t)c << in_shift)] = l;
  }
}

// ---------------- expansion f16 hi/lo (L2, bitwise = r17) -----------------
__global__ __launch_bounds__(256) void expand_f16(
    const float* __restrict__ x, f16* __restrict__ Xh, f16* __restrict__ Xl,
    int in_shift, int total) {
  int idx = blockIdx.x * 256 + threadIdx.x;
  if (idx >= total) return;
  int in = 1 << in_shift;
  int i = idx & (in - 1);
  int b = idx >> in_shift;
  float v = x[idx];
  size_t base = (size_t)b * ((size_t)9 << in_shift) + i;
  float bs[8];
  bspl(v, bs);
  float vals[9];
  vals[0] = silu_f(v);
#pragma unroll
  for (int g = 0; g < 8; ++g) vals[g + 1] = bs[g];
#pragma unroll
  for (int c = 0; c < 9; ++c) {
    f16 h, l;
    split_f16(vals[c], &h, &l);
    Xh[base + ((size_t)c << in_shift)] = h;
    Xl[base + ((size_t)c << in_shift)] = l;
  }
}

// ---------------- W_eff prep bf16 hi/lo (L3, bitwise = r17) ---------------
__global__ __launch_bounds__(256) void prep_w_bf(
    const float* __restrict__ bw, const float* __restrict__ sw,
    const float* __restrict__ sc, u16* __restrict__ Wh, u16* __restrict__ Wl,
    int in_shift, int total) {
  int idx = blockIdx.x * 256 + threadIdx.x;
  if (idx >= total) return;
  int in = 1 << in_shift;
  int i = idx & (in - 1);
  int o = idx >> in_shift;
  size_t wb = (size_t)o * ((size_t)9 << in_shift) + i;
  float s = sc[idx];
  const float4* swp = (const float4*)(sw + (size_t)idx * 8);
  float4 a = swp[0], b = swp[1];
  float vals[9] = {bw[idx], a.x * s, a.y * s, a.z * s, a.w * s,
                   b.x * s, b.y * s, b.z * s, b.w * s};
#pragma unroll
  for (int c = 0; c < 9; ++c) {
    u16 h, l;
    split_bf(vals[c], &h, &l);
    Wh[wb + ((size_t)c << in_shift)] = h;
    Wl[wb + ((size_t)c << in_shift)] = l;
  }
}

// ---------------- expansion bf16 hi/lo (L3, bitwise = r17) ----------------
__global__ __launch_bounds__(256) void expand_bf(
    const float* __restrict__ x, u16* __restrict__ Xh, u16* __restrict__ Xl,
    int in_shift, int total) {
  int idx = blockIdx.x * 256 + threadIdx.x;
  if (idx >= total) return;
  int in = 1 << in_shift;
  int i = idx & (in - 1);
  int b = idx >> in_shift;
  float v = x[idx];
  size_t base = (size_t)b * ((size_t)9 << in_shift) + i;
  float bs[8];
  bspl(v, bs);
  float vals[9];
  vals[0] = silu_f(v);
#pragma unroll
  for (int g = 0; g < 8; ++g) vals[g + 1] = bs[g];
#pragma unroll
  for (int c = 0; c < 9; ++c) {
    u16 h, l;
    split_bf(vals[c], &h, &l);
    Xh[base + ((size_t)c << in_shift)] = h;
    Xl[base + ((size_t)c << in_shift)] = l;
  }
}

// ---------------- f32 tiled GEMM (L1; BN=64, 3 blocks/CU) -----------------
template <bool SILU, int BN>
__global__ __launch_bounds__(256, BN == 64 ? 3 : 2) void gemm_f32(
    const float* __restrict__ A, const float* __restrict__ B,
    float* __restrict__ C, int M, int N, int K, int ldc) {
  constexpr int TN = BN / 16;
  constexpr int BP = BN / 32;
  __shared__ float As[2][32][132];
  __shared__ float Bs[2][32][BN + 4];
  const int tid = threadIdx.x;
  const int bm = blockIdx.y * 128, bn = blockIdx.x * BN;
  const int tx = tid & 15, ty = tid >> 4;
  const int sr = tid >> 3;
  const int sk = (tid & 7) * 4;
  const float* gA = A + (size_t)(bm + sr) * K + sk;
  const float* gB = B + (size_t)(bn + sr) * K + sk;
  float acc[8][TN] = {};
  float acc_t[8][TN] = {};
  float4 av[4], bv[BP];
  const int NT = K >> 5;
#pragma unroll
  for (int p = 0; p < 4; ++p)
    av[p] = *(const float4*)(gA + (size_t)p * 32 * K);
#pragma unroll
  for (int p = 0; p < BP; ++p)
    bv[p] = *(const float4*)(gB + (size_t)p * 32 * K);
#pragma unroll
  for (int p = 0; p < 4; ++p) {
    int m = p * 32 + sr;
    As[0][sk + 0][m] = av[p].x; As[0][sk + 1][m] = av[p].y;
    As[0][sk + 2][m] = av[p].z; As[0][sk + 3][m] = av[p].w;
  }
#pragma unroll
  for (int p = 0; p < BP; ++p) {
    int m = p * 32 + sr;
    Bs[0][sk + 0][m] = bv[p].x; Bs[0][sk + 1][m] = bv[p].y;
    Bs[0][sk + 2][m] = bv[p].z; Bs[0][sk + 3][m] = bv[p].w;
  }
  __syncthreads();
  for (int t = 0; t < NT; ++t) {
    const int cur = t & 1;
    if (t + 1 < NT) {
      const int k0 = (t + 1) << 5;
#pragma unroll
      for (int p = 0; p < 4; ++p)
        av[p] = *(const float4*)(gA + (size_t)p * 32 * K + k0);
#pragma unroll
      for (int p = 0; p < BP; ++p)
        bv[p] = *(const float4*)(gB + (size_t)p * 32 * K + k0);
    }
#pragma unroll 4
    for (int kk = 0; kk < 32; ++kk) {
      float4 a0 = *(const float4*)&As[cur][kk][ty * 8];
      float4 a1 = *(const float4*)&As[cur][kk][ty * 8 + 4];
      float a[8] = {a0.x, a0.y, a0.z, a0.w, a1.x, a1.y, a1.z, a1.w};
      float b[TN];
#pragma unroll
      for (int q = 0; q < TN; q += 4) {
        float4 bq = *(const float4*)&Bs[cur][kk][tx * TN + q];
        b[q] = bq.x; b[q + 1] = bq.y; b[q + 2] = bq.z; b[q + 3] = bq.w;
      }
#pragma unroll
      for (int j = 0; j < 8; ++j)
#pragma unroll
        for (int l = 0; l < TN; ++l)
          acc[j][l] += a[j] * b[l];
    }
#pragma unroll
    for (int j = 0; j < 8; ++j)
#pragma unroll
      for (int l = 0; l < TN; ++l) {
        acc_t[j][l] += acc[j][l];
        acc[j][l] = 0.0f;
      }
    if (t + 1 < NT) {
      const int nxt = cur ^ 1;
#pragma unroll
      for (int p = 0; p < 4; ++p) {
        int m = p * 32 + sr;
        As[nxt][sk + 0][m] = av[p].x; As[nxt][sk + 1][m] = av[p].y;
        As[nxt][sk + 2][m] = av[p].z; As[nxt][sk + 3][m] = av[p].w;
      }
#pragma unroll
      for (int p = 0; p < BP; ++p) {
        int m = p * 32 + sr;
        Bs[nxt][sk + 0][m] = bv[p].x; Bs[nxt][sk + 1][m] = bv[p].y;
        Bs[nxt][sk + 2][m] = bv[p].z; Bs[nxt][sk + 3][m] = bv[p].w;
      }
      __syncthreads();
    }
  }
#pragma unroll
  for (int j = 0; j < 8; ++j) {
    int r = bm + ty * 8 + j;
    float* cp = C + (size_t)r * ldc + bn + tx * TN;
#pragma unroll
    for (int q = 0; q < TN; q += 4) {
      float4 o;
      o.x = acc_t[j][q]; o.y = acc_t[j][q + 1];
      o.z = acc_t[j][q + 2]; o.w = acc_t[j][q + 3];
      if (SILU) {
        o.x = silu_f(o.x); o.y = silu_f(o.y);
        o.z = silu_f(o.z); o.w = silu_f(o.w);
      }
      *(float4*)(cp + q) = o;
    }
  }
}

// ---------------- FUSED 3-product dbuf MFMA GEMMs (bitwise = r17) ---------
__device__ __forceinline__ void gload_lds16(const void* g, void* l) {
  __builtin_amdgcn_global_load_lds(
      (const __attribute__((address_space(1))) void*)g,
      (__attribute__((address_space(3))) void*)l, 16, 0, 0);
}

// f16 unscaled 3-product variant, BN=128 (L2)
template <bool SILU>
__global__ __launch_bounds__(256) void gemm_fused_f16(
    const f16* __restrict__ Ah, const f16* __restrict__ Al,
    const f16* __restrict__ Wh, const f16* __restrict__ Wl,
    float* __restrict__ C, int M, int N, int K, int ldc) {
  __shared__ __align__(16) f16 sAh[2][128 * 32];
  __shared__ __align__(16) f16 sAl[2][128 * 32];
  __shared__ __align__(16) f16 sWh[2][128 * 32];
  __shared__ __align__(16) f16 sWl[2][128 * 32];
  const int tid = threadIdx.x, wave = tid >> 6, lane = tid & 63;
  const int bm = blockIdx.y * 128, bn = blockIdx.x * 128;
  const int rsub = lane >> 2;
  const int csub = (lane & 3) * 8;
  const int wm = wave >> 1, wn = wave & 1;
  const int fr = lane & 15, kg = lane >> 4;
  f32x4 acc[4][4] = {};
  const int NT = K >> 5;

  auto stage = [&](int buf, int k0) {
#pragma unroll
    for (int s = 0; s < 2; ++s) {
      const int rb = (s * 4 + wave) * 16;
      const int doff = rb * 32 + lane * 8;
      gload_lds16(Ah + (size_t)(bm + rb + rsub) * K + k0 + csub, &sAh[buf][doff]);
      gload_lds16(Al + (size_t)(bm + rb + rsub) * K + k0 + csub, &sAl[buf][doff]);
      gload_lds16(Wh + (size_t)(bn + rb + rsub) * K + k0 + csub, &sWh[buf][doff]);
      gload_lds16(Wl + (size_t)(bn + rb + rsub) * K + k0 + csub, &sWl[buf][doff]);
    }
  };

  stage(0, 0);
  __syncthreads();
  int cur = 0;
  for (int t = 0; t < NT; ++t) {
    if (t + 1 < NT) stage(cur ^ 1, (t + 1) << 5);
    f16x8 ah[4], al[4], wh[4], wl[4];
#pragma unroll
    for (int m = 0; m < 4; ++m) {
      int off = (wm * 64 + m * 16 + fr) * 32 + kg * 8;
      ah[m] = *(const f16x8*)&sAh[cur][off];
      al[m] = *(const f16x8*)&sAl[cur][off];
    }
#pragma unroll
    for (int n = 0; n < 4; ++n) {
      int off = (wn * 64 + n * 16 + fr) * 32 + kg * 8;
      wh[n] = *(const f16x8*)&sWh[cur][off];
      wl[n] = *(const f16x8*)&sWl[cur][off];
    }
#pragma unroll
    for (int m = 0; m < 4; ++m)
#pragma unroll
      for (int n = 0; n < 4; ++n) {
        acc[m][n] = __builtin_amdgcn_mfma_f32_16x16x32_f16(ah[m], wh[n], acc[m][n], 0, 0, 0);
        acc[m][n] = __builtin_amdgcn_mfma_f32_16x16x32_f16(al[m], wh[n], acc[m][n], 0, 0, 0);
        acc[m][n] = __builtin_amdgcn_mfma_f32_16x16x32_f16(ah[m], wl[n], acc[m][n], 0, 0, 0);
      }
    __syncthreads();
    cur ^= 1;
  }
#pragma unroll
  for (int m = 0; m < 4; ++m) {
#pragma unroll
    for (int n = 0; n < 4; ++n) {
#pragma unroll
      for (int v = 0; v < 4; ++v) {
        int r = bm + wm * 64 + m * 16 + kg * 4 + v;
        int c = bn + wn * 64 + n * 16 + fr;
        float val = acc[m][n][v];
        if (SILU) val = silu_f(val);
        C[(size_t)r * ldc + c] = val;
      }
    }
  }
}

// bf16 variant, BN=64 (L3)
template <bool SILU>
__global__ __launch_bounds__(256) void gemm_fused_bf64(
    const u16* __restrict__ Ah, const u16* __restrict__ Al,
    const u16* __restrict__ Wh, const u16* __restrict__ Wl,
    float* __restrict__ C, int M, int N, int K, int ldc) {
  __shared__ __align__(16) u16 sAh[2][128 * 32];
  __shared__ __align__(16) u16 sAl[2][128 * 32];
  __shared__ __align__(16) u16 sWh[2][64 * 32];
  __shared__ __align__(16) u16 sWl[2][64 * 32];
  const int tid = threadIdx.x, wave = tid >> 6, lane = tid & 63;
  const int bm = blockIdx.y * 128, bn = blockIdx.x * 64;
  const int rsub = lane >> 2;
  const int csub = (lane & 3) * 8;
  const int wm = wave >> 1, wn = wave & 1;
  const int fr = lane & 15, kg = lane >> 4;
  f32x4 acc[4][2] = {};
  const int NT = K >> 5;

  auto stage = [&](int buf, int k0) {
#pragma unroll
    for (int s = 0; s < 2; ++s) {
      const int rb = (s * 4 + wave) * 16;
      const int doff = rb * 32 + lane * 8;
      gload_lds16(Ah + (size_t)(bm + rb + rsub) * K + k0 + csub, &sAh[buf][doff]);
      gload_lds16(Al + (size_t)(bm + rb + rsub) * K + k0 + csub, &sAl[buf][doff]);
    }
    {
      const int rb = wave * 16;
      const int doff = rb * 32 + lane * 8;
      gload_lds16(Wh + (size_t)(bn + rb + rsub) * K + k0 + csub, &sWh[buf][doff]);
      gload_lds16(Wl + (size_t)(bn + rb + rsub) * K + k0 + csub, &sWl[buf][doff]);
    }
  };

  stage(0, 0);
  __syncthreads();
  int cur = 0;
  for (int t = 0; t < NT; ++t) {
    if (t + 1 < NT) stage(cur ^ 1, (t + 1) << 5);
    short8 ah[4], al[4], wh[2], wl[2];
#pragma unroll
    for (int m = 0; m < 4; ++m) {
      int off = (wm * 64 + m * 16 + fr) * 32 + kg * 8;
      ah[m] = *(const short8*)&sAh[cur][off];
      al[m] = *(const short8*)&sAl[cur][off];
    }
#pragma unroll
    for (int n = 0; n < 2; ++n) {
      int off = (wn * 32 + n * 16 + fr) * 32 + kg * 8;
      wh[n] = *(const short8*)&sWh[cur][off];
      wl[n] = *(const short8*)&sWl[cur][off];
    }
#pragma unroll
    for (int m = 0; m < 4; ++m)
#pragma unroll
      for (int n = 0; n < 2; ++n) {
        acc[m][n] = __builtin_amdgcn_mfma_f32_16x16x32_bf16(ah[m], wh[n], acc[m][n], 0, 0, 0);
        acc[m][n] = __builtin_amdgcn_mfma_f32_16x16x32_bf16(al[m], wh[n], acc[m][n], 0, 0, 0);
        acc[m][n] = __builtin_amdgcn_mfma_f32_16x16x32_bf16(ah[m], wl[n], acc[m][n], 0, 0, 0);
      }
    __syncthreads();
    cur ^= 1;
  }
#pragma unroll
  for (int m = 0; m < 4; ++m) {
#pragma unroll
    for (int n = 0; n < 2; ++n) {
#pragma unroll
      for (int v = 0; v < 4; ++v) {
        int r = bm + wm * 64 + m * 16 + kg * 4 + v;
        int c = bn + wn * 32 + n * 16 + fr;
        float val = acc[m][n][v];
        if (SILU) val = silu_f(val);
        C[(size_t)r * ldc + c] = val;
      }
    }
  }
}

extern "C" void kernel_launch(void* const* d_in, const int* in_sizes, int n_in,
                              void* d_out, int out_size, void* d_ws, size_t ws_size,
                              hipStream_t stream) {
  const float* z   = (const float*)d_in[1];
  const float* lng = (const float*)d_in[2];
  const float* lnb = (const float*)d_in[3];
  const float* bw1 = (const float*)d_in[5];
  const float* sw1 = (const float*)d_in[6];
  const float* sc1 = (const float*)d_in[7];
  const float* bw2 = (const float*)d_in[9];
  const float* sw2 = (const float*)d_in[10];
  const float* sc2 = (const float*)d_in[11];
  const float* bw3 = (const float*)d_in[13];
  const float* sw3 = (const float*)d_in[14];
  const float* sc3 = (const float*)d_in[15];
  float* out = (float*)d_out;

  const int B = 8192, D = 512, H = 1024;
  char* ws = (char*)d_ws;
  size_t off = 0;
  float* ln_out = (float*)(ws + off); off += (size_t)B * D * 4;
  float* hbuf   = (float*)(ws + off); off += (size_t)B * H * 4;  // activated h
  char* Wregion = ws + off;           off += (size_t)H * 9216 * 4;
  size_t rem = ws_size > off ? ws_size - off : 0;
  int CB = 128;
  {
    const int cands[6] = {8192, 4096, 2048, 1024, 512, 256};
    for (int c = 0; c < 6; ++c) {
      if ((size_t)cands[c] * 9216 * 4 <= rem) { CB = cands[c]; break; }
    }
  }
  char* Xregion = ws + off;
  // typed overlays (stream-ordered reuse across layers)
  float* WF = (float*)Wregion;
  float* XF = (float*)Xregion;
  f16* WhF = (f16*)Wregion;
  f16* WlF = WhF + (size_t)H * 9216;
  f16* XhF = (f16*)Xregion;
  f16* XlF = XhF + (size_t)CB * 9216;
  u16* WhB = (u16*)Wregion;
  u16* WlB = WhB + (size_t)H * 9216;
  u16* XhB = (u16*)Xregion;
  u16* XlB = XhB + (size_t)CB * 9216;

  ln_kernel<<<B / 4, 256, 0, stream>>>(z, lng, lnb, ln_out);

  // ---- layer 1: f32 VALU GEMM, BN=64 (83% of f32 peak; accuracy-pinned)
  {
    const int in_shift = 9, K = 9 * D, N = H;
    prep_w_f32<<<(H * D + 255) / 256, 256, 0, stream>>>(bw1, sw1, sc1, WF, in_shift, H * D);
    for (int r0 = 0; r0 < B; r0 += CB) {
      int cb = (B - r0 < CB) ? (B - r0) : CB;
      expand_f32<<<(cb << in_shift) / 256, 256, 0, stream>>>(
          ln_out + (size_t)r0 * D, XF, in_shift, cb << in_shift);
      dim3 grid(N / 64, cb / 128);
      gemm_f32<true, 64><<<grid, 256, 0, stream>>>(XF, WF, hbuf + (size_t)r0 * H, cb, N, K, H);
    }
  }
  // ---- layer 2: f16x2 fused MFMA, silu epilogue
  {
    const int in_shift = 10, K = 9 * H, N = H;
    prep_w_f16<<<(H * H + 255) / 256, 256, 0, stream>>>(
        bw2, sw2, sc2, WhF, WlF, in_shift, H * H);
    for (int r0 = 0; r0 < B; r0 += CB) {
      int cb = (B - r0 < CB) ? (B - r0) : CB;
      expand_f16<<<(cb << in_shift) / 256, 256, 0, stream>>>(
          hbuf + (size_t)r0 * H, XhF, XlF, in_shift, cb << in_shift);
      dim3 grid(N / 128, cb / 128);
      gemm_fused_f16<true><<<grid, 256, 0, stream>>>(
          XhF, XlF, WhF, WlF, hbuf + (size_t)r0 * H, cb, N, K, H);
    }
  }
  // ---- layer 3: bf16x2 fused MFMA, BN=64, no silu
  {
    const int in_shift = 10, K = 9 * H, N = D;
    prep_w_bf<<<(D * H + 255) / 256, 256, 0, stream>>>(bw3, sw3, sc3, WhB, WlB, in_shift, D * H);
    for (int r0 = 0; r0 < B; r0 += CB) {
      int cb = (B - r0 < CB) ? (B - r0) : CB;
      expand_bf<<<(cb << in_shift) / 256, 256, 0, stream>>>(
          hbuf + (size_t)r0 * H, XhB, XlB, in_shift, cb << in_shift);
      dim3 grid(N / 64, cb / 128);
      gemm_fused_bf64<false><<<grid, 256, 0, stream>>>(
          XhB, XlB, WhB, WlB, out + (size_t)r0 * D, cb, N, K, D);
    }
  }
}